// Round 1
// baseline (543.567 us; speedup 1.0000x reference)
//
#include <hip/hip_runtime.h>
#include <math.h>

// Shapes (fixed per setup_inputs): B=2, H=W=48, D=384, CD=384, NH=6, hd=64, KS=7
// pixels NPIX = 2*48*48 = 4608; cond cells = 2*6*6 = 72 (each covers 8x8 pixels)

#define NPIX 4608
#define D 384
#define CD 384
#define C3 1152          // 3*D
#define DMLP 1536        // 4*D
#define NCELL 72

// ws layout (floats):
//  mod   @ 0        : 72*2304 = 165888   (ada1[72][768] | ada2[72][768] | gate1[72][384] | gate2[72][384])
//  h1/h2 @ 165888   : 4608*384 = 1769472
//  qkv   @ 1935360  : 4608*1152 = 5308416   (reused, together with attn slot, as mlp-mid 4608*1536)
//  attn  @ 7243776  : 4608*384 = 1769472
//  total = 9013248 floats = 36.1 MB
#define OFF_MOD   0
#define OFF_H1    165888
#define OFF_QKV   1935360
#define OFF_ATTN  7243776
#define MOD_ADA1  0
#define MOD_ADA2  55296
#define MOD_GATE1 110592
#define MOD_GATE2 138240

__device__ __forceinline__ float wsum(float v) {
    #pragma unroll
    for (int o = 32; o > 0; o >>= 1) v += __shfl_xor(v, o);
    return v;
}
__device__ __forceinline__ float wmax(float v) {
    #pragma unroll
    for (int o = 32; o > 0; o >>= 1) v = fmaxf(v, __shfl_xor(v, o));
    return v;
}

// ---------------------------------------------------------------------------
// Per-cell modulation: for each of 72 cells and 2304 weight rows,
// out = dot(silu(cond[cell]), v_row) * g_row / ||v_row||.
// One wave per (cell,row). 72*2304 = 165888 waves.
// ---------------------------------------------------------------------------
__global__ __launch_bounds__(256) void mod_kernel(
    const float* __restrict__ cond,
    const float* __restrict__ a1v, const float* __restrict__ a1g,
    const float* __restrict__ a2v, const float* __restrict__ a2g,
    const float* __restrict__ g1v, const float* __restrict__ g1g,
    const float* __restrict__ g2v, const float* __restrict__ g2g,
    float* __restrict__ mod)
{
    int wid  = (blockIdx.x * blockDim.x + threadIdx.x) >> 6;
    int lane = threadIdx.x & 63;
    int cell = wid / 2304;
    int row  = wid % 2304;

    const float* V; float g; float* dst; int r;
    if (row < 768)        { r = row;        V = a1v; g = a1g[r]; dst = mod + MOD_ADA1  + cell * 768 + r; }
    else if (row < 1536)  { r = row - 768;  V = a2v; g = a2g[r]; dst = mod + MOD_ADA2  + cell * 768 + r; }
    else if (row < 1920)  { r = row - 1536; V = g1v; g = g1g[r]; dst = mod + MOD_GATE1 + cell * 384 + r; }
    else                  { r = row - 1920; V = g2v; g = g2g[r]; dst = mod + MOD_GATE2 + cell * 384 + r; }

    const float* vrow = V + r * CD;
    const float* crow = cond + cell * CD;
    float dot = 0.f, nrm = 0.f;
    #pragma unroll
    for (int j = 0; j < 6; j++) {
        int k = lane + 64 * j;
        float c  = crow[k];
        float sc = c / (1.f + expf(-c));   // silu
        float v  = vrow[k];
        dot += sc * v;
        nrm += v * v;
    }
    dot = wsum(dot);
    nrm = wsum(nrm);
    if (lane == 0) *dst = dot * g / sqrtf(nrm);
}

// ---------------------------------------------------------------------------
// AdaLN: per pixel, LayerNorm over D then xn*(1+a)+b with per-cell a,b.
// One wave per pixel.
// ---------------------------------------------------------------------------
__global__ __launch_bounds__(256) void adaln_kernel(
    const float* __restrict__ x,
    const float* __restrict__ gamma, const float* __restrict__ beta,
    const float* __restrict__ mod_ab,   // [72][768] base
    float* __restrict__ out)
{
    int p    = (blockIdx.x * blockDim.x + threadIdx.x) >> 6;
    int lane = threadIdx.x & 63;
    int b  = p / 2304;
    int hh = (p / 48) % 48;
    int ww = p % 48;
    int cell = b * 36 + (hh >> 3) * 6 + (ww >> 3);

    const float* xr = x + p * D;
    float v[6]; float s = 0.f, ss = 0.f;
    #pragma unroll
    for (int j = 0; j < 6; j++) {
        v[j] = xr[lane + 64 * j];
        s  += v[j];
        ss += v[j] * v[j];
    }
    s = wsum(s); ss = wsum(ss);
    float mu  = s * (1.f / 384.f);
    float var = ss * (1.f / 384.f) - mu * mu;
    float rs  = 1.f / sqrtf(var + 1e-6f);

    const float* ab = mod_ab + cell * 768;
    float* orow = out + p * D;
    #pragma unroll
    for (int j = 0; j < 6; j++) {
        int d = lane + 64 * j;
        float xn = (v[j] - mu) * rs * gamma[d] + beta[d];
        orow[d] = xn * (1.f + ab[d]) + ab[384 + d];
    }
}

// ---------------------------------------------------------------------------
// Tiled fp32 GEMM: C[M,N] = A[M,K] @ B[N,K]^T + bias, with fused epilogues.
// 64x64 tile, BK=16, 256 threads, 4x4 micro-tile.
// EPI 0: none; 1: gelu(tanh); 2: resid + val*gate[cell,col]  (N must be 384)
// ---------------------------------------------------------------------------
template <int EPI>
__global__ __launch_bounds__(256) void gemm_bt(
    const float* __restrict__ A, const float* __restrict__ B,
    const float* __restrict__ bias, float* __restrict__ C,
    int M, int N, int K,
    const float* __restrict__ gate, const float* __restrict__ resid)
{
    __shared__ float As[16][68];
    __shared__ float Bs[16][68];
    int tid = threadIdx.x;
    int tx = tid & 15, ty = tid >> 4;
    int m0 = blockIdx.y * 64, n0 = blockIdx.x * 64;

    int lm = tid >> 2;            // 0..63
    int lk = (tid & 3) * 4;       // 0,4,8,12
    const float* Aptr = A + (size_t)(m0 + lm) * K + lk;
    const float* Bptr = B + (size_t)(n0 + lm) * K + lk;

    float acc[4][4] = {};
    for (int kt = 0; kt < K; kt += 16) {
        float4 av = *(const float4*)(Aptr + kt);
        float4 bv = *(const float4*)(Bptr + kt);
        As[lk + 0][lm] = av.x; As[lk + 1][lm] = av.y;
        As[lk + 2][lm] = av.z; As[lk + 3][lm] = av.w;
        Bs[lk + 0][lm] = bv.x; Bs[lk + 1][lm] = bv.y;
        Bs[lk + 2][lm] = bv.z; Bs[lk + 3][lm] = bv.w;
        __syncthreads();
        #pragma unroll
        for (int kk = 0; kk < 16; kk++) {
            float4 a4 = *(const float4*)(&As[kk][ty * 4]);
            float4 b4 = *(const float4*)(&Bs[kk][tx * 4]);
            float a[4] = {a4.x, a4.y, a4.z, a4.w};
            float b[4] = {b4.x, b4.y, b4.z, b4.w};
            #pragma unroll
            for (int i = 0; i < 4; i++)
                #pragma unroll
                for (int j = 0; j < 4; j++)
                    acc[i][j] = fmaf(a[i], b[j], acc[i][j]);
        }
        __syncthreads();
    }

    #pragma unroll
    for (int i = 0; i < 4; i++) {
        int row = m0 + ty * 4 + i;
        int cell = 0;
        if (EPI == 2) {
            int b  = row / 2304;
            int hh = (row / 48) % 48;
            int ww = row % 48;
            cell = b * 36 + (hh >> 3) * 6 + (ww >> 3);
        }
        #pragma unroll
        for (int j = 0; j < 4; j++) {
            int col = n0 + tx * 4 + j;
            float val = acc[i][j] + bias[col];
            if (EPI == 1) {
                float t = val;
                float c = 0.7978845608028654f * (t + 0.044715f * t * t * t);
                val = 0.5f * t * (1.f + tanhf(c));
            }
            if (EPI == 2) {
                val = resid[(size_t)row * N + col] + val * gate[cell * 384 + col];
            }
            C[(size_t)row * N + col] = val;
        }
    }
}

// ---------------------------------------------------------------------------
// 7x7 clamped-window neighborhood attention, hd=64 -> one wave per (pixel,head).
// lane = head dim. Logits via butterfly reduce; softmax distributed across
// lanes 0..48; PV via shuffle-broadcast of attention weights.
// ---------------------------------------------------------------------------
__global__ __launch_bounds__(256) void natten_kernel(
    const float* __restrict__ qkv, float* __restrict__ out)
{
    int wid  = (blockIdx.x * blockDim.x + threadIdx.x) >> 6;
    int lane = threadIdx.x & 63;
    int head = wid % 6;
    int p    = wid / 6;
    int b  = p / 2304;
    int hh = (p / 48) % 48;
    int ww = p % 48;
    int sh = hh - 3; sh = sh < 0 ? 0 : (sh > 41 ? 41 : sh);
    int sw = ww - 3; sw = sw < 0 ? 0 : (sw > 41 ? 41 : sw);
    int pb = b * 2304;

    float q = qkv[(size_t)p * C3 + head * 64 + lane] * 0.125f;  // 1/sqrt(64)

    float mylogit = -INFINITY;
    #pragma unroll 7
    for (int n = 0; n < 49; n++) {
        int np = pb + (sh + n / 7) * 48 + (sw + n % 7);
        float kv = qkv[(size_t)np * C3 + 384 + head * 64 + lane];
        float d = wsum(q * kv);
        if (lane == n) mylogit = d;
    }
    float m = wmax(mylogit);
    float e = (lane < 49) ? expf(mylogit - m) : 0.f;
    float s = wsum(e);
    float w = e / s;

    float acc = 0.f;
    #pragma unroll 7
    for (int n = 0; n < 49; n++) {
        int np = pb + (sh + n / 7) * 48 + (sw + n % 7);
        float v = qkv[(size_t)np * C3 + 768 + head * 64 + lane];
        float a = __shfl(w, n);
        acc = fmaf(a, v, acc);
    }
    out[(size_t)p * D + head * 64 + lane] = acc;
}

// ---------------------------------------------------------------------------
extern "C" void kernel_launch(void* const* d_in, const int* in_sizes, int n_in,
                              void* d_out, int out_size, void* d_ws, size_t ws_size,
                              hipStream_t stream)
{
    (void)in_sizes; (void)n_in; (void)out_size; (void)ws_size;
    const float* x      = (const float*)d_in[0];
    const float* cond   = (const float*)d_in[1];
    const float* ln1_g  = (const float*)d_in[2];
    const float* ln1_b  = (const float*)d_in[3];
    const float* ada1_v = (const float*)d_in[4];
    const float* ada1_g = (const float*)d_in[5];
    const float* ln2_g  = (const float*)d_in[6];
    const float* ln2_b  = (const float*)d_in[7];
    const float* ada2_v = (const float*)d_in[8];
    const float* ada2_g = (const float*)d_in[9];
    const float* gate1_v = (const float*)d_in[10];
    const float* gate1_g = (const float*)d_in[11];
    const float* gate2_v = (const float*)d_in[12];
    const float* gate2_g = (const float*)d_in[13];
    const float* w_qkv  = (const float*)d_in[14];
    const float* b_qkv  = (const float*)d_in[15];
    const float* w_out  = (const float*)d_in[16];
    const float* b_out  = (const float*)d_in[17];
    const float* w_mlp1 = (const float*)d_in[18];
    const float* b_mlp1 = (const float*)d_in[19];
    const float* w_mlp2 = (const float*)d_in[20];
    const float* b_mlp2 = (const float*)d_in[21];

    float* ws   = (float*)d_ws;
    float* mod  = ws + OFF_MOD;
    float* h1   = ws + OFF_H1;    // reused as h2
    float* qkvb = ws + OFF_QKV;   // reused (with attn slot) as mlp mid
    float* attn = ws + OFF_ATTN;
    float* mid  = qkvb;
    float* x2   = (float*)d_out;  // x2 lives in d_out; final result overwrites it

    // 1. per-cell modulation vectors (includes weight-norm + silu)
    mod_kernel<<<(NCELL * 2304) / 4, 256, 0, stream>>>(
        cond, ada1_v, ada1_g, ada2_v, ada2_g, gate1_v, gate1_g, gate2_v, gate2_g, mod);

    // 2. h1 = adaln1(x)
    adaln_kernel<<<NPIX / 4, 256, 0, stream>>>(x, ln1_g, ln1_b, mod + MOD_ADA1, h1);

    // 3. qkv = h1 @ w_qkv^T + b_qkv
    gemm_bt<0><<<dim3(C3 / 64, NPIX / 64), 256, 0, stream>>>(
        h1, w_qkv, b_qkv, qkvb, NPIX, C3, D, nullptr, nullptr);

    // 4. neighborhood attention
    natten_kernel<<<(NPIX * 6) / 4, 256, 0, stream>>>(qkvb, attn);

    // 5. x2 = x + (attn @ w_out^T + b_out) * gate1   -> d_out
    gemm_bt<2><<<dim3(D / 64, NPIX / 64), 256, 0, stream>>>(
        attn, w_out, b_out, x2, NPIX, D, D, mod + MOD_GATE1, x);

    // 6. h2 = adaln2(x2)
    adaln_kernel<<<NPIX / 4, 256, 0, stream>>>(x2, ln2_g, ln2_b, mod + MOD_ADA2, h1);

    // 7. mid = gelu(h2 @ w_mlp1^T + b_mlp1)
    gemm_bt<1><<<dim3(DMLP / 64, NPIX / 64), 256, 0, stream>>>(
        h1, w_mlp1, b_mlp1, mid, NPIX, DMLP, D, nullptr, nullptr);

    // 8. out = x2 + (mid @ w_mlp2^T + b_mlp2) * gate2   -> d_out (in-place read+write)
    gemm_bt<2><<<dim3(D / 64, NPIX / 64), 256, 0, stream>>>(
        mid, w_mlp2, b_mlp2, x2, NPIX, D, DMLP, mod + MOD_GATE2, x2);
}

// Round 3
// 468.706 us; speedup vs baseline: 1.1597x; 1.1597x over previous
//
#include <hip/hip_runtime.h>
#include <hip/hip_bf16.h>
#include <math.h>

// Shapes fixed: B=2, H=W=48, D=384, CD=384, NH=6, hd=64, KS=7
#define NPIX 4608
#define D 384
#define CD 384
#define C3 1152
#define DMLP 1536
#define NCELL 72

typedef unsigned short u16;
typedef __attribute__((ext_vector_type(8))) short bf16x8;
typedef __attribute__((ext_vector_type(4))) float f32x4;

// ---------------- workspace layout (bytes) ----------------
// mod f32 [165888] | big f32 (qkv 21.2MB / partials 28.3MB) | h hi/lo | attn hi/lo
// | mid hi/lo | w hi/lo (concat 4 matrices)
#define OFF_MOD   0
#define OFF_BIG   663552
#define OFF_HHI   28975104
#define OFF_HLO   32514048
#define OFF_AHI   36052992
#define OFF_ALO   39591936
#define OFF_MHI   43130880
#define OFF_MLO   57286656
#define OFF_WHI   71442432
#define OFF_WLO   74981376
// mod sub-offsets (floats)
#define MOD_ADA1  0
#define MOD_ADA2  55296
#define MOD_GATE1 110592
#define MOD_GATE2 138240
// weight concat offsets (elements)
#define WOFF_QKV  0
#define WOFF_OUT  442368
#define WOFF_M1   589824
#define WOFF_M2   1179648

#define GLOAD16(g, l) __builtin_amdgcn_global_load_lds( \
    (const __attribute__((address_space(1))) unsigned int*)(g), \
    (__attribute__((address_space(3))) unsigned int*)(l), 16, 0, 0)

__device__ __forceinline__ float wsum(float v) {
    #pragma unroll
    for (int o = 32; o > 0; o >>= 1) v += __shfl_xor(v, o);
    return v;
}
__device__ __forceinline__ float wmax(float v) {
    #pragma unroll
    for (int o = 32; o > 0; o >>= 1) v = fmaxf(v, __shfl_xor(v, o));
    return v;
}
__device__ __forceinline__ void split_bf16(float x, u16& h, u16& l) {
    __hip_bfloat16 bh = __float2bfloat16(x);
    float fh = __bfloat162float(bh);
    __hip_bfloat16 bl = __float2bfloat16(x - fh);
    h = *(u16*)&bh; l = *(u16*)&bl;
}

// ---------------------------------------------------------------------------
// Per-cell modulation (weight-norm + silu + matvec): 72 cells x 2304 rows
// ---------------------------------------------------------------------------
__global__ __launch_bounds__(256) void mod_kernel(
    const float* __restrict__ cond,
    const float* __restrict__ a1v, const float* __restrict__ a1g,
    const float* __restrict__ a2v, const float* __restrict__ a2g,
    const float* __restrict__ g1v, const float* __restrict__ g1g,
    const float* __restrict__ g2v, const float* __restrict__ g2g,
    float* __restrict__ mod)
{
    int wid  = (blockIdx.x * blockDim.x + threadIdx.x) >> 6;
    int lane = threadIdx.x & 63;
    int cell = wid / 2304;
    int row  = wid % 2304;

    const float* V; float g; float* dst; int r;
    if (row < 768)        { r = row;        V = a1v; g = a1g[r]; dst = mod + MOD_ADA1  + cell * 768 + r; }
    else if (row < 1536)  { r = row - 768;  V = a2v; g = a2g[r]; dst = mod + MOD_ADA2  + cell * 768 + r; }
    else if (row < 1920)  { r = row - 1536; V = g1v; g = g1g[r]; dst = mod + MOD_GATE1 + cell * 384 + r; }
    else                  { r = row - 1920; V = g2v; g = g2g[r]; dst = mod + MOD_GATE2 + cell * 384 + r; }

    const float* vrow = V + r * CD;
    const float* crow = cond + cell * CD;
    float dot = 0.f, nrm = 0.f;
    #pragma unroll
    for (int j = 0; j < 6; j++) {
        int k = lane + 64 * j;
        float c  = crow[k];
        float sc = c / (1.f + __expf(-c));
        float v  = vrow[k];
        dot += sc * v;
        nrm += v * v;
    }
    dot = wsum(dot);
    nrm = wsum(nrm);
    if (lane == 0) *dst = dot * g / sqrtf(nrm);
}

// ---------------------------------------------------------------------------
// Weight conversion: fp32 -> bf16 hi/lo, 4 matrices concatenated
// ---------------------------------------------------------------------------
__global__ __launch_bounds__(256) void wconv_kernel(
    const float* __restrict__ wq, const float* __restrict__ wo,
    const float* __restrict__ w1, const float* __restrict__ w2,
    u16* __restrict__ whi, u16* __restrict__ wlo)
{
    int i4 = blockIdx.x * 256 + threadIdx.x;   // 442368 float4s total
    const float* src; int l4;
    if (i4 < 110592)        { src = wq; l4 = i4; }
    else if (i4 < 147456)   { src = wo; l4 = i4 - 110592; }
    else if (i4 < 294912)   { src = w1; l4 = i4 - 147456; }
    else                    { src = w2; l4 = i4 - 294912; }
    float4 v = ((const float4*)src)[l4];
    int o = i4 * 4;
    split_bf16(v.x, whi[o+0], wlo[o+0]);
    split_bf16(v.y, whi[o+1], wlo[o+1]);
    split_bf16(v.z, whi[o+2], wlo[o+2]);
    split_bf16(v.w, whi[o+3], wlo[o+3]);
}

// ---------------------------------------------------------------------------
// AdaLN: LayerNorm + per-cell (1+a)*xn + b, output split to bf16 hi/lo
// ---------------------------------------------------------------------------
__global__ __launch_bounds__(256) void adaln_kernel(
    const float* __restrict__ x,
    const float* __restrict__ gamma, const float* __restrict__ beta,
    const float* __restrict__ mod_ab,
    u16* __restrict__ ohi, u16* __restrict__ olo)
{
    int p    = (blockIdx.x * blockDim.x + threadIdx.x) >> 6;
    int lane = threadIdx.x & 63;
    int b  = p / 2304;
    int hh = (p / 48) % 48;
    int ww = p % 48;
    int cell = b * 36 + (hh >> 3) * 6 + (ww >> 3);

    const float* xr = x + (size_t)p * D;
    float v[6]; float s = 0.f, ss = 0.f;
    #pragma unroll
    for (int j = 0; j < 6; j++) {
        v[j] = xr[lane + 64 * j];
        s  += v[j];
        ss += v[j] * v[j];
    }
    s = wsum(s); ss = wsum(ss);
    float mu  = s * (1.f / 384.f);
    float var = ss * (1.f / 384.f) - mu * mu;
    float rs  = 1.f / sqrtf(var + 1e-6f);

    const float* ab = mod_ab + cell * 768;
    #pragma unroll
    for (int j = 0; j < 6; j++) {
        int d = lane + 64 * j;
        float xn = (v[j] - mu) * rs * gamma[d] + beta[d];
        float o  = xn * (1.f + ab[d]) + ab[384 + d];
        split_bf16(o, ohi[(size_t)p * D + d], olo[(size_t)p * D + d]);
    }
}

// ---------------------------------------------------------------------------
// MFMA GEMM: C[M=4608,N] = A[M,K] @ B[N,K]^T  (split-bf16 3-term emulation)
// 128x128 tile, BK=32, 4 waves 2x2 (64x64 each).
// EPI 0: +bias -> f32; 1: +bias,gelu -> bf16 hi/lo; 2: split-K partial -> f32
// ---------------------------------------------------------------------------
template <int EPI>
__global__ __launch_bounds__(256) void gemm_mfma(
    const u16* __restrict__ Ah, const u16* __restrict__ Al,
    const u16* __restrict__ Bh, const u16* __restrict__ Bl,
    const float* __restrict__ bias,
    float* __restrict__ Cf, u16* __restrict__ Ch, u16* __restrict__ Cl,
    int N, int K, int kPerSplit)
{
    __shared__ u16 lds[16384];   // Ahi[0:4096) Alo[4096:8192) Bhi[8192:12288) Blo[12288:16384)
    const int tid  = threadIdx.x;
    const int lane = tid & 63;
    const int wid  = tid >> 6;
    const int m0 = blockIdx.y * 128;
    const int n0 = blockIdx.x * 128;
    const int kbeg = (EPI == 2) ? blockIdx.z * kPerSplit : 0;
    const int nk   = ((EPI == 2) ? kPerSplit : K) >> 5;
    const int wr = wid >> 1, wc = wid & 1;

    f32x4 acc[4][4] = {};

    // staging: waves 0/1 -> A halves, waves 2/3 -> B halves
    const bool isB = wid >= 2;
    const int half = wid & 1;
    const u16* srcH = isB ? (Bh + (size_t)(n0 + half * 64 + lane) * K)
                          : (Ah + (size_t)(m0 + half * 64 + lane) * K);
    const u16* srcL = isB ? (Bl + (size_t)(n0 + half * 64 + lane) * K)
                          : (Al + (size_t)(m0 + half * 64 + lane) * K);
    u16* ldsH = &lds[(isB ? 8192 : 0) + half * 64 * 8];
    u16* ldsL = ldsH + 4096;

    const int ks = lane >> 4;     // kslot 0..3
    const int fr = lane & 15;     // row/col within fragment

    for (int kt = 0; kt < nk; kt++) {
        const int k0 = kbeg + (kt << 5);
        #pragma unroll
        for (int s = 0; s < 4; s++) {
            GLOAD16(srcH + k0 + s * 8, ldsH + s * 128 * 8);
            GLOAD16(srcL + k0 + s * 8, ldsL + s * 128 * 8);
        }
        __syncthreads();

        bf16x8 ah[4], al[4], bh[4], bl[4];
        #pragma unroll
        for (int m = 0; m < 4; m++) {
            int ai = (ks * 128 + wr * 64 + m * 16 + fr) * 8;
            ah[m] = *(const bf16x8*)&lds[ai];
            al[m] = *(const bf16x8*)&lds[4096 + ai];
        }
        #pragma unroll
        for (int n = 0; n < 4; n++) {
            int bi = (ks * 128 + wc * 64 + n * 16 + fr) * 8;
            bh[n] = *(const bf16x8*)&lds[8192 + bi];
            bl[n] = *(const bf16x8*)&lds[12288 + bi];
        }
        #pragma unroll
        for (int m = 0; m < 4; m++)
            #pragma unroll
            for (int n = 0; n < 4; n++) {
                acc[m][n] = __builtin_amdgcn_mfma_f32_16x16x32_bf16(ah[m], bh[n], acc[m][n], 0, 0, 0);
                acc[m][n] = __builtin_amdgcn_mfma_f32_16x16x32_bf16(ah[m], bl[n], acc[m][n], 0, 0, 0);
                acc[m][n] = __builtin_amdgcn_mfma_f32_16x16x32_bf16(al[m], bh[n], acc[m][n], 0, 0, 0);
            }
        __syncthreads();
    }

    // epilogue: C/D layout col=lane&15, row=(lane>>4)*4+j  (m89-verified)
    const int r4 = ks * 4;
    #pragma unroll
    for (int m = 0; m < 4; m++) {
        #pragma unroll
        for (int n = 0; n < 4; n++) {
            #pragma unroll
            for (int j = 0; j < 4; j++) {
                int row = m0 + wr * 64 + m * 16 + r4 + j;
                int col = n0 + wc * 64 + n * 16 + fr;
                float v = acc[m][n][j];
                if (EPI == 0) {
                    Cf[(size_t)row * N + col] = v + bias[col];
                } else if (EPI == 1) {
                    float t = v + bias[col];
                    float c = 0.7978845608028654f * (t + 0.044715f * t * t * t);
                    float e = __expf(2.f * c);
                    float th = (e - 1.f) / (e + 1.f);
                    float g = 0.5f * t * (1.f + th);
                    size_t idx = (size_t)row * N + col;
                    split_bf16(g, Ch[idx], Cl[idx]);
                } else {
                    Cf[((size_t)blockIdx.z * NPIX + row) * N + col] = v;
                }
            }
        }
    }
}

// ---------------------------------------------------------------------------
// Split-K reduce + bias + gate + residual (N=384)
// ---------------------------------------------------------------------------
__global__ __launch_bounds__(256) void reduce_gate(
    const float* __restrict__ part, const float* __restrict__ bias,
    const float* __restrict__ gate, const float* __restrict__ resid,
    float* __restrict__ out)
{
    int i4 = blockIdx.x * 256 + threadIdx.x;   // 442368 float4s
    int row = i4 / 96, c4 = i4 % 96;
    int b  = row / 2304;
    int hh = (row / 48) % 48;
    int ww = row % 48;
    int cell = b * 36 + (hh >> 3) * 6 + (ww >> 3);

    const float4* P = (const float4*)part;
    float4 p0 = P[i4], p1 = P[i4 + 442368], p2 = P[i4 + 2 * 442368], p3 = P[i4 + 3 * 442368];
    float4 bb = ((const float4*)bias)[c4];
    float4 gg = ((const float4*)(gate + cell * 384))[c4];
    float4 rr = ((const float4*)resid)[i4];
    float4 o;
    o.x = rr.x + (p0.x + p1.x + p2.x + p3.x + bb.x) * gg.x;
    o.y = rr.y + (p0.y + p1.y + p2.y + p3.y + bb.y) * gg.y;
    o.z = rr.z + (p0.z + p1.z + p2.z + p3.z + bb.z) * gg.z;
    o.w = rr.w + (p0.w + p1.w + p2.w + p3.w + bb.w) * gg.w;
    ((float4*)out)[i4] = o;
}

// ---------------------------------------------------------------------------
// 7x7 neighborhood attention, one wave per (pixel,head); output bf16 hi/lo
// ---------------------------------------------------------------------------
__global__ __launch_bounds__(256) void natten_kernel(
    const float* __restrict__ qkv, u16* __restrict__ ohi, u16* __restrict__ olo)
{
    int wid  = (blockIdx.x * blockDim.x + threadIdx.x) >> 6;
    int lane = threadIdx.x & 63;
    int head = wid % 6;
    int p    = wid / 6;
    int b  = p / 2304;
    int hh = (p / 48) % 48;
    int ww = p % 48;
    int sh = hh - 3; sh = sh < 0 ? 0 : (sh > 41 ? 41 : sh);
    int sw = ww - 3; sw = sw < 0 ? 0 : (sw > 41 ? 41 : sw);
    int pb = b * 2304;

    float q = qkv[(size_t)p * C3 + head * 64 + lane] * 0.125f;

    float mylogit = -INFINITY;
    #pragma unroll 7
    for (int n = 0; n < 49; n++) {
        int np = pb + (sh + n / 7) * 48 + (sw + n % 7);
        float kv = qkv[(size_t)np * C3 + 384 + head * 64 + lane];
        float d = wsum(q * kv);
        if (lane == n) mylogit = d;
    }
    float m = wmax(mylogit);
    float e = (lane < 49) ? __expf(mylogit - m) : 0.f;
    float s = wsum(e);
    float w = e / s;

    float acc = 0.f;
    #pragma unroll 7
    for (int n = 0; n < 49; n++) {
        int np = pb + (sh + n / 7) * 48 + (sw + n % 7);
        float v = qkv[(size_t)np * C3 + 768 + head * 64 + lane];
        float a = __shfl(w, n);
        acc = fmaf(a, v, acc);
    }
    size_t oi = (size_t)p * D + head * 64 + lane;
    split_bf16(acc, ohi[oi], olo[oi]);
}

// ---------------------------------------------------------------------------
extern "C" void kernel_launch(void* const* d_in, const int* in_sizes, int n_in,
                              void* d_out, int out_size, void* d_ws, size_t ws_size,
                              hipStream_t stream)
{
    (void)in_sizes; (void)n_in; (void)out_size; (void)ws_size;
    const float* x      = (const float*)d_in[0];
    const float* cond   = (const float*)d_in[1];
    const float* ln1_g  = (const float*)d_in[2];
    const float* ln1_b  = (const float*)d_in[3];
    const float* ada1_v = (const float*)d_in[4];
    const float* ada1_g = (const float*)d_in[5];
    const float* ln2_g  = (const float*)d_in[6];
    const float* ln2_b  = (const float*)d_in[7];
    const float* ada2_v = (const float*)d_in[8];
    const float* ada2_g = (const float*)d_in[9];
    const float* gate1_v = (const float*)d_in[10];
    const float* gate1_g = (const float*)d_in[11];
    const float* gate2_v = (const float*)d_in[12];
    const float* gate2_g = (const float*)d_in[13];
    const float* w_qkv  = (const float*)d_in[14];
    const float* b_qkv  = (const float*)d_in[15];
    const float* w_out  = (const float*)d_in[16];
    const float* b_out  = (const float*)d_in[17];
    const float* w_mlp1 = (const float*)d_in[18];
    const float* b_mlp1 = (const float*)d_in[19];
    const float* w_mlp2 = (const float*)d_in[20];
    const float* b_mlp2 = (const float*)d_in[21];

    char* ws = (char*)d_ws;
    float* mod  = (float*)(ws + OFF_MOD);
    float* big  = (float*)(ws + OFF_BIG);    // qkv f32, later split-K partials
    u16* h_hi   = (u16*)(ws + OFF_HHI);
    u16* h_lo   = (u16*)(ws + OFF_HLO);
    u16* a_hi   = (u16*)(ws + OFF_AHI);
    u16* a_lo   = (u16*)(ws + OFF_ALO);
    u16* m_hi   = (u16*)(ws + OFF_MHI);
    u16* m_lo   = (u16*)(ws + OFF_MLO);
    u16* w_hi   = (u16*)(ws + OFF_WHI);
    u16* w_lo   = (u16*)(ws + OFF_WLO);
    float* x2   = (float*)d_out;

    // 1. per-cell modulation vectors
    mod_kernel<<<(NCELL * 2304) / 4, 256, 0, stream>>>(
        cond, ada1_v, ada1_g, ada2_v, ada2_g, gate1_v, gate1_g, gate2_v, gate2_g, mod);

    // 2. weights -> bf16 hi/lo
    wconv_kernel<<<1728, 256, 0, stream>>>(w_qkv, w_out, w_mlp1, w_mlp2, w_hi, w_lo);

    // 3. h = adaln1(x) -> hi/lo
    adaln_kernel<<<NPIX / 4, 256, 0, stream>>>(x, ln1_g, ln1_b, mod + MOD_ADA1, h_hi, h_lo);

    // 4. qkv = h @ w_qkv^T + b_qkv  (f32, into big)
    gemm_mfma<0><<<dim3(C3 / 128, NPIX / 128), 256, 0, stream>>>(
        h_hi, h_lo, w_hi + WOFF_QKV, w_lo + WOFF_QKV, b_qkv,
        big, nullptr, nullptr, C3, D, 0);

    // 5. neighborhood attention -> hi/lo
    natten_kernel<<<(NPIX * 6) / 4, 256, 0, stream>>>(big, a_hi, a_lo);

    // 6. out-proj split-K=4 partials (into big; qkv dead now)
    gemm_mfma<2><<<dim3(D / 128, NPIX / 128, 4), 256, 0, stream>>>(
        a_hi, a_lo, w_hi + WOFF_OUT, w_lo + WOFF_OUT, nullptr,
        big, nullptr, nullptr, D, D, 96);

    // 7. x2 = x + (sum + b_out) * gate1  -> d_out
    reduce_gate<<<1728, 256, 0, stream>>>(big, b_out, mod + MOD_GATE1, x, x2);

    // 8. h = adaln2(x2) -> hi/lo (reuse h buffers)
    adaln_kernel<<<NPIX / 4, 256, 0, stream>>>(x2, ln2_g, ln2_b, mod + MOD_ADA2, h_hi, h_lo);

    // 9. mid = gelu(h @ w_mlp1^T + b_mlp1) -> bf16 hi/lo
    gemm_mfma<1><<<dim3(DMLP / 128, NPIX / 128), 256, 0, stream>>>(
        h_hi, h_lo, w_hi + WOFF_M1, w_lo + WOFF_M1, b_mlp1,
        nullptr, m_hi, m_lo, DMLP, D, 0);

    // 10. mlp2 split-K=4 partials (K=1536 -> 4x384)
    gemm_mfma<2><<<dim3(D / 128, NPIX / 128, 4), 256, 0, stream>>>(
        m_hi, m_lo, w_hi + WOFF_M2, w_lo + WOFF_M2, nullptr,
        big, nullptr, nullptr, D, DMLP, 384);

    // 11. out = x2 + (sum + b_mlp2) * gate2 -> d_out (in-place elementwise)
    reduce_gate<<<1728, 256, 0, stream>>>(big, b_mlp2, mod + MOD_GATE2, x2, x2);
}

// Round 4
// 410.627 us; speedup vs baseline: 1.3238x; 1.1414x over previous
//
#include <hip/hip_runtime.h>
#include <hip/hip_bf16.h>
#include <math.h>

// Shapes fixed: B=2, H=W=48, D=384, CD=384, NH=6, hd=64, KS=7
#define NPIX 4608
#define D 384
#define CD 384
#define C3 1152
#define DMLP 1536
#define NCELL 72

typedef unsigned short u16;
typedef __attribute__((ext_vector_type(8))) short bf16x8;
typedef __attribute__((ext_vector_type(4))) float f32x4;

// ---------------- workspace layout (bytes) ----------------
#define OFF_MOD   0
#define OFF_BIG   663552
#define OFF_HHI   28975104
#define OFF_HLO   32514048
#define OFF_AHI   36052992
#define OFF_ALO   39591936
#define OFF_MHI   43130880
#define OFF_MLO   57286656
#define OFF_WHI   71442432
#define OFF_WLO   74981376
// mod sub-offsets (floats)
#define MOD_ADA1  0
#define MOD_ADA2  55296
#define MOD_GATE1 110592
#define MOD_GATE2 138240
// weight concat offsets (elements)
#define WOFF_QKV  0
#define WOFF_OUT  442368
#define WOFF_M1   589824
#define WOFF_M2   1179648

#define GLOAD16(g, l) __builtin_amdgcn_global_load_lds( \
    (const __attribute__((address_space(1))) unsigned int*)(g), \
    (__attribute__((address_space(3))) unsigned int*)(l), 16, 0, 0)

__device__ __forceinline__ float wsum(float v) {
    #pragma unroll
    for (int o = 32; o > 0; o >>= 1) v += __shfl_xor(v, o);
    return v;
}
__device__ __forceinline__ void split_bf16(float x, u16& h, u16& l) {
    __hip_bfloat16 bh = __float2bfloat16(x);
    float fh = __bfloat162float(bh);
    __hip_bfloat16 bl = __float2bfloat16(x - fh);
    h = *(u16*)&bh; l = *(u16*)&bl;
}

// ---------------------------------------------------------------------------
// Per-cell modulation (weight-norm + silu + matvec): 72 cells x 2304 rows
// ---------------------------------------------------------------------------
__global__ __launch_bounds__(256) void mod_kernel(
    const float* __restrict__ cond,
    const float* __restrict__ a1v, const float* __restrict__ a1g,
    const float* __restrict__ a2v, const float* __restrict__ a2g,
    const float* __restrict__ g1v, const float* __restrict__ g1g,
    const float* __restrict__ g2v, const float* __restrict__ g2g,
    float* __restrict__ mod)
{
    int wid  = (blockIdx.x * blockDim.x + threadIdx.x) >> 6;
    int lane = threadIdx.x & 63;
    int cell = wid / 2304;
    int row  = wid % 2304;

    const float* V; float g; float* dst; int r;
    if (row < 768)        { r = row;        V = a1v; g = a1g[r]; dst = mod + MOD_ADA1  + cell * 768 + r; }
    else if (row < 1536)  { r = row - 768;  V = a2v; g = a2g[r]; dst = mod + MOD_ADA2  + cell * 768 + r; }
    else if (row < 1920)  { r = row - 1536; V = g1v; g = g1g[r]; dst = mod + MOD_GATE1 + cell * 384 + r; }
    else                  { r = row - 1920; V = g2v; g = g2g[r]; dst = mod + MOD_GATE2 + cell * 384 + r; }

    const float* vrow = V + r * CD;
    const float* crow = cond + cell * CD;
    float dot = 0.f, nrm = 0.f;
    #pragma unroll
    for (int j = 0; j < 6; j++) {
        int k = lane + 64 * j;
        float c  = crow[k];
        float sc = c / (1.f + __expf(-c));
        float v  = vrow[k];
        dot += sc * v;
        nrm += v * v;
    }
    dot = wsum(dot);
    nrm = wsum(nrm);
    if (lane == 0) *dst = dot * g / sqrtf(nrm);
}

// ---------------------------------------------------------------------------
// Weight conversion: fp32 -> bf16 hi/lo, 4 matrices concatenated
// ---------------------------------------------------------------------------
__global__ __launch_bounds__(256) void wconv_kernel(
    const float* __restrict__ wq, const float* __restrict__ wo,
    const float* __restrict__ w1, const float* __restrict__ w2,
    u16* __restrict__ whi, u16* __restrict__ wlo)
{
    int i4 = blockIdx.x * 256 + threadIdx.x;   // 442368 float4s total
    const float* src; int l4;
    if (i4 < 110592)        { src = wq; l4 = i4; }
    else if (i4 < 147456)   { src = wo; l4 = i4 - 110592; }
    else if (i4 < 294912)   { src = w1; l4 = i4 - 147456; }
    else                    { src = w2; l4 = i4 - 294912; }
    float4 v = ((const float4*)src)[l4];
    int o = i4 * 4;
    split_bf16(v.x, whi[o+0], wlo[o+0]);
    split_bf16(v.y, whi[o+1], wlo[o+1]);
    split_bf16(v.z, whi[o+2], wlo[o+2]);
    split_bf16(v.w, whi[o+3], wlo[o+3]);
}

// ---------------------------------------------------------------------------
// AdaLN: LayerNorm + per-cell (1+a)*xn + b, output split to bf16 hi/lo
// ---------------------------------------------------------------------------
__global__ __launch_bounds__(256) void adaln_kernel(
    const float* __restrict__ x,
    const float* __restrict__ gamma, const float* __restrict__ beta,
    const float* __restrict__ mod_ab,
    u16* __restrict__ ohi, u16* __restrict__ olo)
{
    int p    = (blockIdx.x * blockDim.x + threadIdx.x) >> 6;
    int lane = threadIdx.x & 63;
    int b  = p / 2304;
    int hh = (p / 48) % 48;
    int ww = p % 48;
    int cell = b * 36 + (hh >> 3) * 6 + (ww >> 3);

    const float* xr = x + (size_t)p * D;
    float v[6]; float s = 0.f, ss = 0.f;
    #pragma unroll
    for (int j = 0; j < 6; j++) {
        v[j] = xr[lane + 64 * j];
        s  += v[j];
        ss += v[j] * v[j];
    }
    s = wsum(s); ss = wsum(ss);
    float mu  = s * (1.f / 384.f);
    float var = ss * (1.f / 384.f) - mu * mu;
    float rs  = 1.f / sqrtf(var + 1e-6f);

    const float* ab = mod_ab + cell * 768;
    #pragma unroll
    for (int j = 0; j < 6; j++) {
        int d = lane + 64 * j;
        float xn = (v[j] - mu) * rs * gamma[d] + beta[d];
        float o  = xn * (1.f + ab[d]) + ab[384 + d];
        split_bf16(o, ohi[(size_t)p * D + d], olo[(size_t)p * D + d]);
    }
}

// ---------------------------------------------------------------------------
// MFMA GEMM: C[M=4608,N] = A[M,K] @ B[N,K]^T  (split-bf16 3-term emulation)
// ---------------------------------------------------------------------------
template <int EPI>
__global__ __launch_bounds__(256) void gemm_mfma(
    const u16* __restrict__ Ah, const u16* __restrict__ Al,
    const u16* __restrict__ Bh, const u16* __restrict__ Bl,
    const float* __restrict__ bias,
    float* __restrict__ Cf, u16* __restrict__ Ch, u16* __restrict__ Cl,
    int N, int K, int kPerSplit)
{
    __shared__ u16 lds[16384];   // Ahi[0:4096) Alo[4096:8192) Bhi[8192:12288) Blo[12288:16384)
    const int tid  = threadIdx.x;
    const int lane = tid & 63;
    const int wid  = tid >> 6;
    const int m0 = blockIdx.y * 128;
    const int n0 = blockIdx.x * 128;
    const int kbeg = (EPI == 2) ? blockIdx.z * kPerSplit : 0;
    const int nk   = ((EPI == 2) ? kPerSplit : K) >> 5;
    const int wr = wid >> 1, wc = wid & 1;

    f32x4 acc[4][4] = {};

    const bool isB = wid >= 2;
    const int half = wid & 1;
    const u16* srcH = isB ? (Bh + (size_t)(n0 + half * 64 + lane) * K)
                          : (Ah + (size_t)(m0 + half * 64 + lane) * K);
    const u16* srcL = isB ? (Bl + (size_t)(n0 + half * 64 + lane) * K)
                          : (Al + (size_t)(m0 + half * 64 + lane) * K);
    u16* ldsH = &lds[(isB ? 8192 : 0) + half * 64 * 8];
    u16* ldsL = ldsH + 4096;

    const int ks = lane >> 4;     // kslot 0..3
    const int fr = lane & 15;     // row/col within fragment

    for (int kt = 0; kt < nk; kt++) {
        const int k0 = kbeg + (kt << 5);
        #pragma unroll
        for (int s = 0; s < 4; s++) {
            GLOAD16(srcH + k0 + s * 8, ldsH + s * 128 * 8);
            GLOAD16(srcL + k0 + s * 8, ldsL + s * 128 * 8);
        }
        __syncthreads();

        bf16x8 ah[4], al[4], bh[4], bl[4];
        #pragma unroll
        for (int m = 0; m < 4; m++) {
            int ai = (ks * 128 + wr * 64 + m * 16 + fr) * 8;
            ah[m] = *(const bf16x8*)&lds[ai];
            al[m] = *(const bf16x8*)&lds[4096 + ai];
        }
        #pragma unroll
        for (int n = 0; n < 4; n++) {
            int bi = (ks * 128 + wc * 64 + n * 16 + fr) * 8;
            bh[n] = *(const bf16x8*)&lds[8192 + bi];
            bl[n] = *(const bf16x8*)&lds[12288 + bi];
        }
        #pragma unroll
        for (int m = 0; m < 4; m++)
            #pragma unroll
            for (int n = 0; n < 4; n++) {
                acc[m][n] = __builtin_amdgcn_mfma_f32_16x16x32_bf16(ah[m], bh[n], acc[m][n], 0, 0, 0);
                acc[m][n] = __builtin_amdgcn_mfma_f32_16x16x32_bf16(ah[m], bl[n], acc[m][n], 0, 0, 0);
                acc[m][n] = __builtin_amdgcn_mfma_f32_16x16x32_bf16(al[m], bh[n], acc[m][n], 0, 0, 0);
            }
        __syncthreads();
    }

    const int r4 = ks * 4;
    #pragma unroll
    for (int m = 0; m < 4; m++) {
        #pragma unroll
        for (int n = 0; n < 4; n++) {
            #pragma unroll
            for (int j = 0; j < 4; j++) {
                int row = m0 + wr * 64 + m * 16 + r4 + j;
                int col = n0 + wc * 64 + n * 16 + fr;
                float v = acc[m][n][j];
                if (EPI == 0) {
                    Cf[(size_t)row * N + col] = v + bias[col];
                } else if (EPI == 1) {
                    float t = v + bias[col];
                    float c = 0.7978845608028654f * (t + 0.044715f * t * t * t);
                    float e = __expf(2.f * c);
                    float th = (e - 1.f) / (e + 1.f);
                    float g = 0.5f * t * (1.f + th);
                    size_t idx = (size_t)row * N + col;
                    split_bf16(g, Ch[idx], Cl[idx]);
                } else {
                    Cf[((size_t)blockIdx.z * NPIX + row) * N + col] = v;
                }
            }
        }
    }
}

// ---------------------------------------------------------------------------
// Split-K reduce + bias + gate + residual (N=384)
// ---------------------------------------------------------------------------
__global__ __launch_bounds__(256) void reduce_gate(
    const float* __restrict__ part, const float* __restrict__ bias,
    const float* __restrict__ gate, const float* __restrict__ resid,
    float* __restrict__ out)
{
    int i4 = blockIdx.x * 256 + threadIdx.x;   // 442368 float4s
    int row = i4 / 96, c4 = i4 % 96;
    int b  = row / 2304;
    int hh = (row / 48) % 48;
    int ww = row % 48;
    int cell = b * 36 + (hh >> 3) * 6 + (ww >> 3);

    const float4* P = (const float4*)part;
    float4 p0 = P[i4], p1 = P[i4 + 442368], p2 = P[i4 + 2 * 442368], p3 = P[i4 + 3 * 442368];
    float4 bb = ((const float4*)bias)[c4];
    float4 gg = ((const float4*)(gate + cell * 384))[c4];
    float4 rr = ((const float4*)resid)[i4];
    float4 o;
    o.x = rr.x + (p0.x + p1.x + p2.x + p3.x + bb.x) * gg.x;
    o.y = rr.y + (p0.y + p1.y + p2.y + p3.y + bb.y) * gg.y;
    o.z = rr.z + (p0.z + p1.z + p2.z + p3.z + bb.z) * gg.z;
    o.w = rr.w + (p0.w + p1.w + p2.w + p3.w + bb.w) * gg.w;
    ((float4*)out)[i4] = o;
}

// ---------------------------------------------------------------------------
// 7x7 neighborhood attention, one wave per (pixel,head).
// Lane decomposition: n_sub = lane>>3 (neighbor sub-index), d_sub = lane&7
// (owns dims 8*d_sub..8*d_sub+7). 7 passes of 8 neighbors.
// QK: 2x float4 K-load + 8 FMA + 3 shfl_xor (reduce over d_sub) per pass.
// Softmax distributed: lane keeps logits L[p] for neighbors 8p+n_sub;
// max/sum reduced in-lane over p, then 3 shfl_xor over n_sub. w[p] is then
// exactly the per-lane weight needed in PV pass p (no gather shuffles).
// PV: 2x float4 V-load + 8 FMA per pass; final 8-float butterfly over n_sub.
// Total ~51 shuffles/wave vs 355 in the serial-wsum version.
// ---------------------------------------------------------------------------
__global__ __launch_bounds__(256) void natten_kernel(
    const float* __restrict__ qkv, u16* __restrict__ ohi, u16* __restrict__ olo)
{
    int wid  = (blockIdx.x * blockDim.x + threadIdx.x) >> 6;
    int lane = threadIdx.x & 63;
    int head = wid % 6;
    int p    = wid / 6;
    int b  = p / 2304;
    int hh = (p / 48) % 48;
    int ww = p % 48;
    int sh = hh - 3; sh = sh < 0 ? 0 : (sh > 41 ? 41 : sh);
    int sw = ww - 3; sw = sw < 0 ? 0 : (sw > 41 ? 41 : sw);
    int pb = b * 2304;

    const int n_sub = lane >> 3;
    const int d_sub = lane & 7;
    const int dof = head * 64 + d_sub * 8;

    // q: this lane's 8 dims, pre-scaled
    const float* qp = qkv + (size_t)p * C3 + dof;
    float4 q0 = *(const float4*)qp;
    float4 q1 = *(const float4*)(qp + 4);
    q0.x *= 0.125f; q0.y *= 0.125f; q0.z *= 0.125f; q0.w *= 0.125f;
    q1.x *= 0.125f; q1.y *= 0.125f; q1.z *= 0.125f; q1.w *= 0.125f;

    // QK passes
    float L[7];
    #pragma unroll
    for (int t = 0; t < 7; t++) {
        int n = t * 8 + n_sub;            // 0..55
        int nn = n > 48 ? 48 : n;         // clamp for safe load
        int nr = nn / 7, nc = nn - nr * 7;
        const float* kp = qkv + (size_t)(pb + (sh + nr) * 48 + (sw + nc)) * C3 + 384 + dof;
        float4 k0 = *(const float4*)kp;
        float4 k1 = *(const float4*)(kp + 4);
        float d = q0.x * k0.x + q0.y * k0.y + q0.z * k0.z + q0.w * k0.w
                + q1.x * k1.x + q1.y * k1.y + q1.z * k1.z + q1.w * k1.w;
        d += __shfl_xor(d, 1);
        d += __shfl_xor(d, 2);
        d += __shfl_xor(d, 4);
        L[t] = (n < 49) ? d : -INFINITY;
    }

    // distributed softmax
    float m = L[0];
    #pragma unroll
    for (int t = 1; t < 7; t++) m = fmaxf(m, L[t]);
    m = fmaxf(m, __shfl_xor(m, 8));
    m = fmaxf(m, __shfl_xor(m, 16));
    m = fmaxf(m, __shfl_xor(m, 32));

    float w[7]; float s = 0.f;
    #pragma unroll
    for (int t = 0; t < 7; t++) {
        w[t] = (L[t] == -INFINITY) ? 0.f : __expf(L[t] - m);
        s += w[t];
    }
    s += __shfl_xor(s, 8);
    s += __shfl_xor(s, 16);
    s += __shfl_xor(s, 32);
    float inv = 1.f / s;
    #pragma unroll
    for (int t = 0; t < 7; t++) w[t] *= inv;

    // PV passes
    float a0x = 0.f, a0y = 0.f, a0z = 0.f, a0w = 0.f;
    float a1x = 0.f, a1y = 0.f, a1z = 0.f, a1w = 0.f;
    #pragma unroll
    for (int t = 0; t < 7; t++) {
        int n = t * 8 + n_sub;
        int nn = n > 48 ? 48 : n;
        int nr = nn / 7, nc = nn - nr * 7;
        const float* vp = qkv + (size_t)(pb + (sh + nr) * 48 + (sw + nc)) * C3 + 768 + dof;
        float4 v0 = *(const float4*)vp;
        float4 v1 = *(const float4*)(vp + 4);
        float wn = w[t];
        a0x = fmaf(wn, v0.x, a0x); a0y = fmaf(wn, v0.y, a0y);
        a0z = fmaf(wn, v0.z, a0z); a0w = fmaf(wn, v0.w, a0w);
        a1x = fmaf(wn, v1.x, a1x); a1y = fmaf(wn, v1.y, a1y);
        a1z = fmaf(wn, v1.z, a1z); a1w = fmaf(wn, v1.w, a1w);
    }
    // reduce over n_sub (strides 8,16,32) for each of the 8 accumulators
    #pragma unroll
    for (int o = 8; o <= 32; o <<= 1) {
        a0x += __shfl_xor(a0x, o); a0y += __shfl_xor(a0y, o);
        a0z += __shfl_xor(a0z, o); a0w += __shfl_xor(a0w, o);
        a1x += __shfl_xor(a1x, o); a1y += __shfl_xor(a1y, o);
        a1z += __shfl_xor(a1z, o); a1w += __shfl_xor(a1w, o);
    }

    // lanes 0..7 (n_sub==0) write their 8 dims as one 16B hi + one 16B lo store
    if (lane < 8) {
        float av[8] = {a0x, a0y, a0z, a0w, a1x, a1y, a1z, a1w};
        u16 hi8[8], lo8[8];
        #pragma unroll
        for (int i = 0; i < 8; i++) split_bf16(av[i], hi8[i], lo8[i]);
        size_t oi = (size_t)p * D + head * 64 + lane * 8;
        *(uint4*)(ohi + oi) = *(uint4*)hi8;
        *(uint4*)(olo + oi) = *(uint4*)lo8;
    }
}

// ---------------------------------------------------------------------------
extern "C" void kernel_launch(void* const* d_in, const int* in_sizes, int n_in,
                              void* d_out, int out_size, void* d_ws, size_t ws_size,
                              hipStream_t stream)
{
    (void)in_sizes; (void)n_in; (void)out_size; (void)ws_size;
    const float* x      = (const float*)d_in[0];
    const float* cond   = (const float*)d_in[1];
    const float* ln1_g  = (const float*)d_in[2];
    const float* ln1_b  = (const float*)d_in[3];
    const float* ada1_v = (const float*)d_in[4];
    const float* ada1_g = (const float*)d_in[5];
    const float* ln2_g  = (const float*)d_in[6];
    const float* ln2_b  = (const float*)d_in[7];
    const float* ada2_v = (const float*)d_in[8];
    const float* ada2_g = (const float*)d_in[9];
    const float* gate1_v = (const float*)d_in[10];
    const float* gate1_g = (const float*)d_in[11];
    const float* gate2_v = (const float*)d_in[12];
    const float* gate2_g = (const float*)d_in[13];
    const float* w_qkv  = (const float*)d_in[14];
    const float* b_qkv  = (const float*)d_in[15];
    const float* w_out  = (const float*)d_in[16];
    const float* b_out  = (const float*)d_in[17];
    const float* w_mlp1 = (const float*)d_in[18];
    const float* b_mlp1 = (const float*)d_in[19];
    const float* w_mlp2 = (const float*)d_in[20];
    const float* b_mlp2 = (const float*)d_in[21];

    char* ws = (char*)d_ws;
    float* mod  = (float*)(ws + OFF_MOD);
    float* big  = (float*)(ws + OFF_BIG);
    u16* h_hi   = (u16*)(ws + OFF_HHI);
    u16* h_lo   = (u16*)(ws + OFF_HLO);
    u16* a_hi   = (u16*)(ws + OFF_AHI);
    u16* a_lo   = (u16*)(ws + OFF_ALO);
    u16* m_hi   = (u16*)(ws + OFF_MHI);
    u16* m_lo   = (u16*)(ws + OFF_MLO);
    u16* w_hi   = (u16*)(ws + OFF_WHI);
    u16* w_lo   = (u16*)(ws + OFF_WLO);
    float* x2   = (float*)d_out;

    mod_kernel<<<(NCELL * 2304) / 4, 256, 0, stream>>>(
        cond, ada1_v, ada1_g, ada2_v, ada2_g, gate1_v, gate1_g, gate2_v, gate2_g, mod);

    wconv_kernel<<<1728, 256, 0, stream>>>(w_qkv, w_out, w_mlp1, w_mlp2, w_hi, w_lo);

    adaln_kernel<<<NPIX / 4, 256, 0, stream>>>(x, ln1_g, ln1_b, mod + MOD_ADA1, h_hi, h_lo);

    gemm_mfma<0><<<dim3(C3 / 128, NPIX / 128), 256, 0, stream>>>(
        h_hi, h_lo, w_hi + WOFF_QKV, w_lo + WOFF_QKV, b_qkv,
        big, nullptr, nullptr, C3, D, 0);

    natten_kernel<<<(NPIX * 6) / 4, 256, 0, stream>>>(big, a_hi, a_lo);

    gemm_mfma<2><<<dim3(D / 128, NPIX / 128, 4), 256, 0, stream>>>(
        a_hi, a_lo, w_hi + WOFF_OUT, w_lo + WOFF_OUT, nullptr,
        big, nullptr, nullptr, D, D, 96);

    reduce_gate<<<1728, 256, 0, stream>>>(big, b_out, mod + MOD_GATE1, x, x2);

    adaln_kernel<<<NPIX / 4, 256, 0, stream>>>(x2, ln2_g, ln2_b, mod + MOD_ADA2, h_hi, h_lo);

    gemm_mfma<1><<<dim3(DMLP / 128, NPIX / 128), 256, 0, stream>>>(
        h_hi, h_lo, w_hi + WOFF_M1, w_lo + WOFF_M1, b_mlp1,
        nullptr, m_hi, m_lo, DMLP, D, 0);

    gemm_mfma<2><<<dim3(D / 128, NPIX / 128, 4), 256, 0, stream>>>(
        m_hi, m_lo, w_hi + WOFF_M2, w_lo + WOFF_M2, nullptr,
        big, nullptr, nullptr, D, DMLP, 384);

    reduce_gate<<<1728, 256, 0, stream>>>(big, b_mlp2, mod + MOD_GATE2, x2, x2);
}

// Round 5
// 358.288 us; speedup vs baseline: 1.5171x; 1.1461x over previous
//
#include <hip/hip_runtime.h>
#include <hip/hip_bf16.h>
#include <math.h>

// Shapes fixed: B=2, H=W=48, D=384, CD=384, NH=6, hd=64, KS=7
#define NPIX 4608
#define D 384
#define CD 384
#define C3 1152
#define DMLP 1536
#define NCELL 72

typedef unsigned short u16;
typedef __attribute__((ext_vector_type(8))) short bf16x8;
typedef __attribute__((ext_vector_type(4))) float f32x4;

// ---------------- workspace layout (bytes) ----------------
#define OFF_MOD   0
#define OFF_BIG   663552
#define OFF_HHI   28975104
#define OFF_HLO   32514048
#define OFF_AHI   36052992
#define OFF_ALO   39591936
#define OFF_MHI   43130880
#define OFF_MLO   57286656
#define OFF_WHI   71442432
#define OFF_WLO   74981376
// mod sub-offsets (floats)
#define MOD_ADA1  0
#define MOD_ADA2  55296
#define MOD_GATE1 110592
#define MOD_GATE2 138240
// weight concat offsets (elements)
#define WOFF_QKV  0
#define WOFF_OUT  442368
#define WOFF_M1   589824
#define WOFF_M2   1179648

#define GLOAD16(g, l) __builtin_amdgcn_global_load_lds( \
    (const __attribute__((address_space(1))) unsigned int*)(g), \
    (__attribute__((address_space(3))) unsigned int*)(l), 16, 0, 0)

__device__ __forceinline__ float wsum(float v) {
    #pragma unroll
    for (int o = 32; o > 0; o >>= 1) v += __shfl_xor(v, o);
    return v;
}
__device__ __forceinline__ void split_bf16(float x, u16& h, u16& l) {
    __hip_bfloat16 bh = __float2bfloat16(x);
    float fh = __bfloat162float(bh);
    __hip_bfloat16 bl = __float2bfloat16(x - fh);
    h = *(u16*)&bh; l = *(u16*)&bl;
}

// ---------------------------------------------------------------------------
// Per-cell modulation (weight-norm + silu + matvec): 72 cells x 2304 rows
// ---------------------------------------------------------------------------
__global__ __launch_bounds__(256) void mod_kernel(
    const float* __restrict__ cond,
    const float* __restrict__ a1v, const float* __restrict__ a1g,
    const float* __restrict__ a2v, const float* __restrict__ a2g,
    const float* __restrict__ g1v, const float* __restrict__ g1g,
    const float* __restrict__ g2v, const float* __restrict__ g2g,
    float* __restrict__ mod)
{
    int wid  = (blockIdx.x * blockDim.x + threadIdx.x) >> 6;
    int lane = threadIdx.x & 63;
    int cell = wid / 2304;
    int row  = wid % 2304;

    const float* V; float g; float* dst; int r;
    if (row < 768)        { r = row;        V = a1v; g = a1g[r]; dst = mod + MOD_ADA1  + cell * 768 + r; }
    else if (row < 1536)  { r = row - 768;  V = a2v; g = a2g[r]; dst = mod + MOD_ADA2  + cell * 768 + r; }
    else if (row < 1920)  { r = row - 1536; V = g1v; g = g1g[r]; dst = mod + MOD_GATE1 + cell * 384 + r; }
    else                  { r = row - 1920; V = g2v; g = g2g[r]; dst = mod + MOD_GATE2 + cell * 384 + r; }

    const float* vrow = V + r * CD;
    const float* crow = cond + cell * CD;
    float dot = 0.f, nrm = 0.f;
    #pragma unroll
    for (int j = 0; j < 6; j++) {
        int k = lane + 64 * j;
        float c  = crow[k];
        float sc = c / (1.f + __expf(-c));
        float v  = vrow[k];
        dot += sc * v;
        nrm += v * v;
    }
    dot = wsum(dot);
    nrm = wsum(nrm);
    if (lane == 0) *dst = dot * g / sqrtf(nrm);
}

// ---------------------------------------------------------------------------
// Weight conversion: fp32 -> bf16 hi/lo, 4 matrices concatenated
// ---------------------------------------------------------------------------
__global__ __launch_bounds__(256) void wconv_kernel(
    const float* __restrict__ wq, const float* __restrict__ wo,
    const float* __restrict__ w1, const float* __restrict__ w2,
    u16* __restrict__ whi, u16* __restrict__ wlo)
{
    int i4 = blockIdx.x * 256 + threadIdx.x;   // 442368 float4s total
    const float* src; int l4;
    if (i4 < 110592)        { src = wq; l4 = i4; }
    else if (i4 < 147456)   { src = wo; l4 = i4 - 110592; }
    else if (i4 < 294912)   { src = w1; l4 = i4 - 147456; }
    else                    { src = w2; l4 = i4 - 294912; }
    float4 v = ((const float4*)src)[l4];
    int o = i4 * 4;
    split_bf16(v.x, whi[o+0], wlo[o+0]);
    split_bf16(v.y, whi[o+1], wlo[o+1]);
    split_bf16(v.z, whi[o+2], wlo[o+2]);
    split_bf16(v.w, whi[o+3], wlo[o+3]);
}

// ---------------------------------------------------------------------------
// AdaLN: LayerNorm + per-cell (1+a)*xn + b, output split to bf16 hi/lo
// ---------------------------------------------------------------------------
__global__ __launch_bounds__(256) void adaln_kernel(
    const float* __restrict__ x,
    const float* __restrict__ gamma, const float* __restrict__ beta,
    const float* __restrict__ mod_ab,
    u16* __restrict__ ohi, u16* __restrict__ olo)
{
    int p    = (blockIdx.x * blockDim.x + threadIdx.x) >> 6;
    int lane = threadIdx.x & 63;
    int b  = p / 2304;
    int hh = (p / 48) % 48;
    int ww = p % 48;
    int cell = b * 36 + (hh >> 3) * 6 + (ww >> 3);

    const float* xr = x + (size_t)p * D;
    float v[6]; float s = 0.f, ss = 0.f;
    #pragma unroll
    for (int j = 0; j < 6; j++) {
        v[j] = xr[lane + 64 * j];
        s  += v[j];
        ss += v[j] * v[j];
    }
    s = wsum(s); ss = wsum(ss);
    float mu  = s * (1.f / 384.f);
    float var = ss * (1.f / 384.f) - mu * mu;
    float rs  = 1.f / sqrtf(var + 1e-6f);

    const float* ab = mod_ab + cell * 768;
    #pragma unroll
    for (int j = 0; j < 6; j++) {
        int d = lane + 64 * j;
        float xn = (v[j] - mu) * rs * gamma[d] + beta[d];
        float o  = xn * (1.f + ab[d]) + ab[384 + d];
        split_bf16(o, ohi[(size_t)p * D + d], olo[(size_t)p * D + d]);
    }
}

// ---------------------------------------------------------------------------
// MFMA GEMM, split-bf16 3-term: C[4608,N] = A @ B^T
// BM=128, BN=64, BK=32, 4 waves (2x2, 64x32 per wave), double-buffered LDS,
// 2-phase pipeline (stage k+1 before compute k), bijective XCD swizzle.
// LDS per buffer (u16): Ahi[0,4096) Alo[4096,8192) Bhi[8192,10240) Blo[10240,12288)
// region layout [kslot][row][8]; staged as 6 flat 16B chunks per thread.
// EPI 0: +bias -> f32; 1: +bias,gelu -> bf16 hi/lo; 2: split-K partial -> f32
// ---------------------------------------------------------------------------
template <int EPI, int NS>
__global__ __launch_bounds__(256) void gemm_mfma(
    const u16* __restrict__ Ah, const u16* __restrict__ Al,
    const u16* __restrict__ Bh, const u16* __restrict__ Bl,
    const float* __restrict__ bias,
    float* __restrict__ Cf, u16* __restrict__ Ch, u16* __restrict__ Cl,
    int N, int K)
{
    __shared__ u16 lds[24576];   // 2 x 12288 (48 KB)
    const int tid  = threadIdx.x;
    const int lane = tid & 63;
    const int wid  = tid >> 6;

    // bijective XCD swizzle (m204)
    const int nwg = gridDim.x;
    const int q = nwg >> 3, r = nwg & 7;
    const int xcd = blockIdx.x & 7, loc = blockIdx.x >> 3;
    const int wgid = (xcd < r ? xcd * (q + 1) : r * (q + 1) + (xcd - r) * q) + loc;

    const int nx = N >> 6;                 // column blocks
    const int per = nx * 36;               // blocks per K-split (M/128 = 36)
    const int bz  = wgid / per;
    const int id2 = wgid - bz * per;
    const int by  = id2 / nx;
    const int bx  = id2 - by * nx;

    const int m0 = by * 128;
    const int n0 = bx * 64;
    const int kPer = K / NS;
    const int kbeg = bz * kPer;
    const int nt = kPer >> 5;

    const int wr = wid >> 1, wc = wid & 1;

    // staging: 6 chunks of 16B per thread, chunk c = tid + 256*s
    const u16* gsrc[6];
    int loff[6];
    #pragma unroll
    for (int s = 0; s < 6; s++) {
        int c = tid + (s << 8);
        const u16* base; int ks, row;
        if (c < 512)        { ks = c >> 7;           row = c & 127; base = Ah + (size_t)(m0 + row) * K; }
        else if (c < 1024)  { int cc = c - 512;  ks = cc >> 7; row = cc & 127; base = Al + (size_t)(m0 + row) * K; }
        else if (c < 1280)  { int cc = c - 1024; ks = cc >> 6; row = cc & 63;  base = Bh + (size_t)(n0 + row) * K; }
        else                { int cc = c - 1280; ks = cc >> 6; row = cc & 63;  base = Bl + (size_t)(n0 + row) * K; }
        gsrc[s] = base + ks * 8;
        loff[s] = c * 8;
    }

    f32x4 acc[4][2] = {};
    const int ks = lane >> 4;     // kslot 0..3
    const int fr = lane & 15;

    // prologue: stage tile 0 into buffer 0
    #pragma unroll
    for (int s = 0; s < 6; s++) GLOAD16(gsrc[s] + kbeg, &lds[loff[s]]);
    __syncthreads();

    int cur = 0;
    for (int kt = 0; kt < nt; kt++) {
        if (kt + 1 < nt) {
            int k0 = kbeg + ((kt + 1) << 5);
            int dbo = (cur ^ 1) * 12288;
            #pragma unroll
            for (int s = 0; s < 6; s++) GLOAD16(gsrc[s] + k0, &lds[dbo + loff[s]]);
        }
        const int b0 = cur * 12288;
        bf16x8 ah[4], al[4], bh[2], bl[2];
        #pragma unroll
        for (int m = 0; m < 4; m++) {
            int ai = b0 + (ks * 128 + wr * 64 + m * 16 + fr) * 8;
            ah[m] = *(const bf16x8*)&lds[ai];
            al[m] = *(const bf16x8*)&lds[4096 + ai];
        }
        #pragma unroll
        for (int n = 0; n < 2; n++) {
            int bi = b0 + (ks * 64 + wc * 32 + n * 16 + fr) * 8;
            bh[n] = *(const bf16x8*)&lds[8192 + bi];
            bl[n] = *(const bf16x8*)&lds[10240 + bi];
        }
        #pragma unroll
        for (int m = 0; m < 4; m++)
            #pragma unroll
            for (int n = 0; n < 2; n++) {
                acc[m][n] = __builtin_amdgcn_mfma_f32_16x16x32_bf16(ah[m], bh[n], acc[m][n], 0, 0, 0);
                acc[m][n] = __builtin_amdgcn_mfma_f32_16x16x32_bf16(ah[m], bl[n], acc[m][n], 0, 0, 0);
                acc[m][n] = __builtin_amdgcn_mfma_f32_16x16x32_bf16(al[m], bh[n], acc[m][n], 0, 0, 0);
            }
        __syncthreads();
        cur ^= 1;
    }

    // epilogue: C/D layout col=lane&15, row=(lane>>4)*4+j (m89-verified)
    const int r4 = ks * 4;
    #pragma unroll
    for (int m = 0; m < 4; m++) {
        #pragma unroll
        for (int n = 0; n < 2; n++) {
            #pragma unroll
            for (int j = 0; j < 4; j++) {
                int row = m0 + wr * 64 + m * 16 + r4 + j;
                int col = n0 + wc * 32 + n * 16 + fr;
                float v = acc[m][n][j];
                if (EPI == 0) {
                    Cf[(size_t)row * N + col] = v + bias[col];
                } else if (EPI == 1) {
                    float t = v + bias[col];
                    float c = 0.7978845608028654f * (t + 0.044715f * t * t * t);
                    float e = __expf(2.f * c);
                    float th = (e - 1.f) / (e + 1.f);
                    float g = 0.5f * t * (1.f + th);
                    size_t idx = (size_t)row * N + col;
                    split_bf16(g, Ch[idx], Cl[idx]);
                } else {
                    Cf[((size_t)bz * NPIX + row) * N + col] = v;
                }
            }
        }
    }
}

// ---------------------------------------------------------------------------
// Split-K reduce + bias + gate + residual (N=384, 4 partials)
// ---------------------------------------------------------------------------
__global__ __launch_bounds__(256) void reduce_gate(
    const float* __restrict__ part, const float* __restrict__ bias,
    const float* __restrict__ gate, const float* __restrict__ resid,
    float* __restrict__ out)
{
    int i4 = blockIdx.x * 256 + threadIdx.x;   // 442368 float4s
    int row = i4 / 96, c4 = i4 % 96;
    int b  = row / 2304;
    int hh = (row / 48) % 48;
    int ww = row % 48;
    int cell = b * 36 + (hh >> 3) * 6 + (ww >> 3);

    const float4* P = (const float4*)part;
    float4 p0 = P[i4], p1 = P[i4 + 442368], p2 = P[i4 + 2 * 442368], p3 = P[i4 + 3 * 442368];
    float4 bb = ((const float4*)bias)[c4];
    float4 gg = ((const float4*)(gate + cell * 384))[c4];
    float4 rr = ((const float4*)resid)[i4];
    float4 o;
    o.x = rr.x + (p0.x + p1.x + p2.x + p3.x + bb.x) * gg.x;
    o.y = rr.y + (p0.y + p1.y + p2.y + p3.y + bb.y) * gg.y;
    o.z = rr.z + (p0.z + p1.z + p2.z + p3.z + bb.z) * gg.z;
    o.w = rr.w + (p0.w + p1.w + p2.w + p3.w + bb.w) * gg.w;
    ((float4*)out)[i4] = o;
}

// ---------------------------------------------------------------------------
// 7x7 neighborhood attention, one wave per (pixel,head), 8x8 lane decomp.
// ---------------------------------------------------------------------------
__global__ __launch_bounds__(256) void natten_kernel(
    const float* __restrict__ qkv, u16* __restrict__ ohi, u16* __restrict__ olo)
{
    int wid  = (blockIdx.x * blockDim.x + threadIdx.x) >> 6;
    int lane = threadIdx.x & 63;
    int head = wid % 6;
    int p    = wid / 6;
    int b  = p / 2304;
    int hh = (p / 48) % 48;
    int ww = p % 48;
    int sh = hh - 3; sh = sh < 0 ? 0 : (sh > 41 ? 41 : sh);
    int sw = ww - 3; sw = sw < 0 ? 0 : (sw > 41 ? 41 : sw);
    int pb = b * 2304;

    const int n_sub = lane >> 3;
    const int d_sub = lane & 7;
    const int dof = head * 64 + d_sub * 8;

    const float* qp = qkv + (size_t)p * C3 + dof;
    float4 q0 = *(const float4*)qp;
    float4 q1 = *(const float4*)(qp + 4);
    q0.x *= 0.125f; q0.y *= 0.125f; q0.z *= 0.125f; q0.w *= 0.125f;
    q1.x *= 0.125f; q1.y *= 0.125f; q1.z *= 0.125f; q1.w *= 0.125f;

    float L[7];
    #pragma unroll
    for (int t = 0; t < 7; t++) {
        int n = t * 8 + n_sub;
        int nn = n > 48 ? 48 : n;
        int nr = nn / 7, nc = nn - nr * 7;
        const float* kp = qkv + (size_t)(pb + (sh + nr) * 48 + (sw + nc)) * C3 + 384 + dof;
        float4 k0 = *(const float4*)kp;
        float4 k1 = *(const float4*)(kp + 4);
        float d = q0.x * k0.x + q0.y * k0.y + q0.z * k0.z + q0.w * k0.w
                + q1.x * k1.x + q1.y * k1.y + q1.z * k1.z + q1.w * k1.w;
        d += __shfl_xor(d, 1);
        d += __shfl_xor(d, 2);
        d += __shfl_xor(d, 4);
        L[t] = (n < 49) ? d : -INFINITY;
    }

    float m = L[0];
    #pragma unroll
    for (int t = 1; t < 7; t++) m = fmaxf(m, L[t]);
    m = fmaxf(m, __shfl_xor(m, 8));
    m = fmaxf(m, __shfl_xor(m, 16));
    m = fmaxf(m, __shfl_xor(m, 32));

    float w[7]; float s = 0.f;
    #pragma unroll
    for (int t = 0; t < 7; t++) {
        w[t] = (L[t] == -INFINITY) ? 0.f : __expf(L[t] - m);
        s += w[t];
    }
    s += __shfl_xor(s, 8);
    s += __shfl_xor(s, 16);
    s += __shfl_xor(s, 32);
    float inv = 1.f / s;
    #pragma unroll
    for (int t = 0; t < 7; t++) w[t] *= inv;

    float a0x = 0.f, a0y = 0.f, a0z = 0.f, a0w = 0.f;
    float a1x = 0.f, a1y = 0.f, a1z = 0.f, a1w = 0.f;
    #pragma unroll
    for (int t = 0; t < 7; t++) {
        int n = t * 8 + n_sub;
        int nn = n > 48 ? 48 : n;
        int nr = nn / 7, nc = nn - nr * 7;
        const float* vp = qkv + (size_t)(pb + (sh + nr) * 48 + (sw + nc)) * C3 + 768 + dof;
        float4 v0 = *(const float4*)vp;
        float4 v1 = *(const float4*)(vp + 4);
        float wn = w[t];
        a0x = fmaf(wn, v0.x, a0x); a0y = fmaf(wn, v0.y, a0y);
        a0z = fmaf(wn, v0.z, a0z); a0w = fmaf(wn, v0.w, a0w);
        a1x = fmaf(wn, v1.x, a1x); a1y = fmaf(wn, v1.y, a1y);
        a1z = fmaf(wn, v1.z, a1z); a1w = fmaf(wn, v1.w, a1w);
    }
    #pragma unroll
    for (int o = 8; o <= 32; o <<= 1) {
        a0x += __shfl_xor(a0x, o); a0y += __shfl_xor(a0y, o);
        a0z += __shfl_xor(a0z, o); a0w += __shfl_xor(a0w, o);
        a1x += __shfl_xor(a1x, o); a1y += __shfl_xor(a1y, o);
        a1z += __shfl_xor(a1z, o); a1w += __shfl_xor(a1w, o);
    }

    if (lane < 8) {
        float av[8] = {a0x, a0y, a0z, a0w, a1x, a1y, a1z, a1w};
        u16 hi8[8], lo8[8];
        #pragma unroll
        for (int i = 0; i < 8; i++) split_bf16(av[i], hi8[i], lo8[i]);
        size_t oi = (size_t)p * D + head * 64 + lane * 8;
        *(uint4*)(ohi + oi) = *(uint4*)hi8;
        *(uint4*)(olo + oi) = *(uint4*)lo8;
    }
}

// ---------------------------------------------------------------------------
extern "C" void kernel_launch(void* const* d_in, const int* in_sizes, int n_in,
                              void* d_out, int out_size, void* d_ws, size_t ws_size,
                              hipStream_t stream)
{
    (void)in_sizes; (void)n_in; (void)out_size; (void)ws_size;
    const float* x      = (const float*)d_in[0];
    const float* cond   = (const float*)d_in[1];
    const float* ln1_g  = (const float*)d_in[2];
    const float* ln1_b  = (const float*)d_in[3];
    const float* ada1_v = (const float*)d_in[4];
    const float* ada1_g = (const float*)d_in[5];
    const float* ln2_g  = (const float*)d_in[6];
    const float* ln2_b  = (const float*)d_in[7];
    const float* ada2_v = (const float*)d_in[8];
    const float* ada2_g = (const float*)d_in[9];
    const float* gate1_v = (const float*)d_in[10];
    const float* gate1_g = (const float*)d_in[11];
    const float* gate2_v = (const float*)d_in[12];
    const float* gate2_g = (const float*)d_in[13];
    const float* w_qkv  = (const float*)d_in[14];
    const float* b_qkv  = (const float*)d_in[15];
    const float* w_out  = (const float*)d_in[16];
    const float* b_out  = (const float*)d_in[17];
    const float* w_mlp1 = (const float*)d_in[18];
    const float* b_mlp1 = (const float*)d_in[19];
    const float* w_mlp2 = (const float*)d_in[20];
    const float* b_mlp2 = (const float*)d_in[21];

    char* ws = (char*)d_ws;
    float* mod  = (float*)(ws + OFF_MOD);
    float* big  = (float*)(ws + OFF_BIG);
    u16* h_hi   = (u16*)(ws + OFF_HHI);
    u16* h_lo   = (u16*)(ws + OFF_HLO);
    u16* a_hi   = (u16*)(ws + OFF_AHI);
    u16* a_lo   = (u16*)(ws + OFF_ALO);
    u16* m_hi   = (u16*)(ws + OFF_MHI);
    u16* m_lo   = (u16*)(ws + OFF_MLO);
    u16* w_hi   = (u16*)(ws + OFF_WHI);
    u16* w_lo   = (u16*)(ws + OFF_WLO);
    float* x2   = (float*)d_out;

    mod_kernel<<<(NCELL * 2304) / 4, 256, 0, stream>>>(
        cond, ada1_v, ada1_g, ada2_v, ada2_g, gate1_v, gate1_g, gate2_v, gate2_g, mod);

    wconv_kernel<<<1728, 256, 0, stream>>>(w_qkv, w_out, w_mlp1, w_mlp2, w_hi, w_lo);

    adaln_kernel<<<NPIX / 4, 256, 0, stream>>>(x, ln1_g, ln1_b, mod + MOD_ADA1, h_hi, h_lo);

    // qkv: N=1152 -> 18x36 = 648 blocks
    gemm_mfma<0, 1><<<648, 256, 0, stream>>>(
        h_hi, h_lo, w_hi + WOFF_QKV, w_lo + WOFF_QKV, b_qkv,
        big, nullptr, nullptr, C3, D);

    natten_kernel<<<(NPIX * 6) / 4, 256, 0, stream>>>(big, a_hi, a_lo);

    // out-proj split-K=4: 6x36x4 = 864 blocks
    gemm_mfma<2, 4><<<864, 256, 0, stream>>>(
        a_hi, a_lo, w_hi + WOFF_OUT, w_lo + WOFF_OUT, nullptr,
        big, nullptr, nullptr, D, D);

    reduce_gate<<<1728, 256, 0, stream>>>(big, b_out, mod + MOD_GATE1, x, x2);

    adaln_kernel<<<NPIX / 4, 256, 0, stream>>>(x2, ln2_g, ln2_b, mod + MOD_ADA2, h_hi, h_lo);

    // mlp1: N=1536 -> 24x36 = 864 blocks
    gemm_mfma<1, 1><<<864, 256, 0, stream>>>(
        h_hi, h_lo, w_hi + WOFF_M1, w_lo + WOFF_M1, b_mlp1,
        nullptr, m_hi, m_lo, DMLP, D);

    // mlp2 split-K=4 (K=1536): 6x36x4 = 864 blocks
    gemm_mfma<2, 4><<<864, 256, 0, stream>>>(
        m_hi, m_lo, w_hi + WOFF_M2, w_lo + WOFF_M2, nullptr,
        big, nullptr, nullptr, D, DMLP);

    reduce_gate<<<1728, 256, 0, stream>>>(big, b_mlp2, mod + MOD_GATE2, x2, x2);
}

// Round 6
// 331.755 us; speedup vs baseline: 1.6385x; 1.0800x over previous
//
#include <hip/hip_runtime.h>
#include <hip/hip_bf16.h>
#include <math.h>

// Shapes fixed: B=2, H=W=48, D=384, CD=384, NH=6, hd=64, KS=7
#define NPIX 4608
#define D 384
#define CD 384
#define C3 1152
#define DMLP 1536
#define NCELL 72

typedef unsigned short u16;
typedef __attribute__((ext_vector_type(8))) short bf16x8;
typedef __attribute__((ext_vector_type(4))) float f32x4;

// ---------------- workspace layout (bytes) ----------------
// mod f32 [72][2304] | big (qkv f32 21.2MB / partials 28.3MB / early: modV+sc+invn)
// | h hi/lo | attn hi/lo | mid hi/lo | w hi/lo
#define OFF_MOD   0
#define OFF_BIG   663552
#define OFF_HHI   28975104
#define OFF_HLO   32514048
#define OFF_AHI   36052992
#define OFF_ALO   39591936
#define OFF_MHI   43130880
#define OFF_MLO   57286656
#define OFF_WHI   71442432
#define OFF_WLO   74981376
// early-phase temporaries inside BIG (dead before qkv GEMM writes big):
#define BIGOFF_MODV_HI  0         // 2304*384 u16 = 1769472 B
#define BIGOFF_MODV_LO  1769472
#define BIGOFF_SC_HI    3538944   // 128*384 u16 = 98304 B
#define BIGOFF_SC_LO    3637248
#define BIGOFF_INVN     3735552   // 2304 f32
// mod row-major [72][2304]: per cell, [0,384)=a1, [384,768)=b1,
// [768,1152)=a2, [1152,1536)=b2, [1536,1920)=gate1, [1920,2304)=gate2
// weight concat offsets (elements) in w_hi/w_lo
#define WOFF_QKV  0
#define WOFF_OUT  442368
#define WOFF_M1   589824
#define WOFF_M2   1179648

#define GLOAD16(g, l) __builtin_amdgcn_global_load_lds( \
    (const __attribute__((address_space(1))) unsigned int*)(g), \
    (__attribute__((address_space(3))) unsigned int*)(l), 16, 0, 0)

__device__ __forceinline__ float wsum(float v) {
    #pragma unroll
    for (int o = 32; o > 0; o >>= 1) v += __shfl_xor(v, o);
    return v;
}
__device__ __forceinline__ void split_bf16(float x, u16& h, u16& l) {
    __hip_bfloat16 bh = __float2bfloat16(x);
    float fh = __bfloat162float(bh);
    __hip_bfloat16 bl = __float2bfloat16(x - fh);
    h = *(u16*)&bh; l = *(u16*)&bl;
}

// ---------------------------------------------------------------------------
// Weight conversion: fp32 -> bf16 hi/lo. 4 main weights (w_hi/w_lo) plus the
// 4 modulation V matrices concatenated [a1|a2|g1|g2] (modV hi/lo in big).
// ---------------------------------------------------------------------------
__global__ __launch_bounds__(256) void wconv_kernel(
    const float* __restrict__ wq, const float* __restrict__ wo,
    const float* __restrict__ w1, const float* __restrict__ w2,
    const float* __restrict__ a1v, const float* __restrict__ a2v,
    const float* __restrict__ g1v, const float* __restrict__ g2v,
    u16* __restrict__ whi, u16* __restrict__ wlo,
    u16* __restrict__ mvhi, u16* __restrict__ mvlo)
{
    int i4 = blockIdx.x * 256 + threadIdx.x;   // 663552 float4s total
    const float* src; int l4; u16 *dh, *dl; int o;
    if (i4 < 442368) {
        if (i4 < 110592)        { src = wq; l4 = i4; }
        else if (i4 < 147456)   { src = wo; l4 = i4 - 110592; }
        else if (i4 < 294912)   { src = w1; l4 = i4 - 147456; }
        else                    { src = w2; l4 = i4 - 294912; }
        dh = whi; dl = wlo; o = i4 * 4;
    } else {
        int j4 = i4 - 442368;   // 0..221183
        if (j4 < 73728)         { src = a1v; l4 = j4; }
        else if (j4 < 147456)   { src = a2v; l4 = j4 - 73728; }
        else if (j4 < 184320)   { src = g1v; l4 = j4 - 147456; }
        else                    { src = g2v; l4 = j4 - 184320; }
        dh = mvhi; dl = mvlo; o = j4 * 4;
    }
    float4 v = ((const float4*)src)[l4];
    split_bf16(v.x, dh[o+0], dl[o+0]);
    split_bf16(v.y, dh[o+1], dl[o+1]);
    split_bf16(v.z, dh[o+2], dl[o+2]);
    split_bf16(v.w, dh[o+3], dl[o+3]);
}

// ---------------------------------------------------------------------------
// modprep: wid<2304 -> inv_norm[row] = g/||v_row||; else silu(cond) -> sc
// (padded to 128 cells, zero beyond 72). 2432 waves -> 608 blocks.
// ---------------------------------------------------------------------------
__global__ __launch_bounds__(256) void modprep_kernel(
    const float* __restrict__ cond,
    const float* __restrict__ a1v, const float* __restrict__ a1g,
    const float* __restrict__ a2v, const float* __restrict__ a2g,
    const float* __restrict__ g1v, const float* __restrict__ g1g,
    const float* __restrict__ g2v, const float* __restrict__ g2g,
    float* __restrict__ invn, u16* __restrict__ schi, u16* __restrict__ sclo)
{
    int wid  = (blockIdx.x * blockDim.x + threadIdx.x) >> 6;
    int lane = threadIdx.x & 63;
    if (wid < 2304) {
        const float* V; float g; int r;
        if (wid < 768)        { r = wid;        V = a1v; g = a1g[r]; }
        else if (wid < 1536)  { r = wid - 768;  V = a2v; g = a2g[r]; }
        else if (wid < 1920)  { r = wid - 1536; V = g1v; g = g1g[r]; }
        else                  { r = wid - 1920; V = g2v; g = g2g[r]; }
        const float* vrow = V + r * CD;
        float nrm = 0.f;
        #pragma unroll
        for (int j = 0; j < 6; j++) {
            float v = vrow[lane + 64 * j];
            nrm += v * v;
        }
        nrm = wsum(nrm);
        if (lane == 0) invn[wid] = g / sqrtf(nrm);
    } else {
        int cell = wid - 2304;   // 0..127
        #pragma unroll
        for (int j = 0; j < 6; j++) {
            int k = lane + 64 * j;
            float val = 0.f;
            if (cell < NCELL) {
                float c = cond[cell * CD + k];
                val = c / (1.f + __expf(-c));
            }
            split_bf16(val, schi[cell * CD + k], sclo[cell * CD + k]);
        }
    }
}

// ---------------------------------------------------------------------------
// mod GEMM: mod[72,2304] = sc[128,384] @ modV[2304,384]^T, x inv_norm[col].
// Same structure as gemm_mfma: BM=128 (single M tile), BN=64, BK=32,
// double-buffered, 36 blocks.
// ---------------------------------------------------------------------------
__global__ __launch_bounds__(256) void modgemm_mfma(
    const u16* __restrict__ Ah, const u16* __restrict__ Al,
    const u16* __restrict__ Bh, const u16* __restrict__ Bl,
    const float* __restrict__ invn, float* __restrict__ mod)
{
    __shared__ u16 lds[24576];
    const int tid  = threadIdx.x;
    const int lane = tid & 63;
    const int wid  = tid >> 6;
    const int n0 = blockIdx.x * 64;
    const int K = 384, nt = 12;
    const int wr = wid >> 1, wc = wid & 1;

    const u16* gsrc[6];
    int loff[6];
    #pragma unroll
    for (int s = 0; s < 6; s++) {
        int c = tid + (s << 8);
        const u16* base; int ks, row;
        if (c < 512)        { ks = c >> 7;           row = c & 127; base = Ah + (size_t)row * K; }
        else if (c < 1024)  { int cc = c - 512;  ks = cc >> 7; row = cc & 127; base = Al + (size_t)row * K; }
        else if (c < 1280)  { int cc = c - 1024; ks = cc >> 6; row = cc & 63;  base = Bh + (size_t)(n0 + row) * K; }
        else                { int cc = c - 1280; ks = cc >> 6; row = cc & 63;  base = Bl + (size_t)(n0 + row) * K; }
        gsrc[s] = base + ks * 8;
        loff[s] = c * 8;
    }

    f32x4 acc[4][2] = {};
    const int ks = lane >> 4;
    const int fr = lane & 15;

    #pragma unroll
    for (int s = 0; s < 6; s++) GLOAD16(gsrc[s], &lds[loff[s]]);
    __syncthreads();

    int cur = 0;
    for (int kt = 0; kt < nt; kt++) {
        if (kt + 1 < nt) {
            int k0 = (kt + 1) << 5;
            int dbo = (cur ^ 1) * 12288;
            #pragma unroll
            for (int s = 0; s < 6; s++) GLOAD16(gsrc[s] + k0, &lds[dbo + loff[s]]);
        }
        const int b0 = cur * 12288;
        bf16x8 ah[4], al[4], bh[2], bl[2];
        #pragma unroll
        for (int m = 0; m < 4; m++) {
            int ai = b0 + (ks * 128 + wr * 64 + m * 16 + fr) * 8;
            ah[m] = *(const bf16x8*)&lds[ai];
            al[m] = *(const bf16x8*)&lds[4096 + ai];
        }
        #pragma unroll
        for (int n = 0; n < 2; n++) {
            int bi = b0 + (ks * 64 + wc * 32 + n * 16 + fr) * 8;
            bh[n] = *(const bf16x8*)&lds[8192 + bi];
            bl[n] = *(const bf16x8*)&lds[10240 + bi];
        }
        #pragma unroll
        for (int m = 0; m < 4; m++)
            #pragma unroll
            for (int n = 0; n < 2; n++) {
                acc[m][n] = __builtin_amdgcn_mfma_f32_16x16x32_bf16(ah[m], bh[n], acc[m][n], 0, 0, 0);
                acc[m][n] = __builtin_amdgcn_mfma_f32_16x16x32_bf16(ah[m], bl[n], acc[m][n], 0, 0, 0);
                acc[m][n] = __builtin_amdgcn_mfma_f32_16x16x32_bf16(al[m], bh[n], acc[m][n], 0, 0, 0);
            }
        __syncthreads();
        cur ^= 1;
    }

    const int r4 = ks * 4;
    #pragma unroll
    for (int m = 0; m < 4; m++) {
        #pragma unroll
        for (int n = 0; n < 2; n++) {
            #pragma unroll
            for (int j = 0; j < 4; j++) {
                int row = wr * 64 + m * 16 + r4 + j;
                int col = n0 + wc * 32 + n * 16 + fr;
                if (row < NCELL)
                    mod[(size_t)row * 2304 + col] = acc[m][n][j] * invn[col];
            }
        }
    }
}

// ---------------------------------------------------------------------------
// AdaLN: LayerNorm + per-cell (1+a)*xn + b; mod row-major [72][2304],
// mod_ab points at the a-block base (a at [d], b at [384+d]).
// ---------------------------------------------------------------------------
__global__ __launch_bounds__(256) void adaln_kernel(
    const float* __restrict__ x,
    const float* __restrict__ gamma, const float* __restrict__ beta,
    const float* __restrict__ mod_ab,
    u16* __restrict__ ohi, u16* __restrict__ olo)
{
    int p    = (blockIdx.x * blockDim.x + threadIdx.x) >> 6;
    int lane = threadIdx.x & 63;
    int b  = p / 2304;
    int hh = (p / 48) % 48;
    int ww = p % 48;
    int cell = b * 36 + (hh >> 3) * 6 + (ww >> 3);

    const float* xr = x + (size_t)p * D;
    float v[6]; float s = 0.f, ss = 0.f;
    #pragma unroll
    for (int j = 0; j < 6; j++) {
        v[j] = xr[lane + 64 * j];
        s  += v[j];
        ss += v[j] * v[j];
    }
    s = wsum(s); ss = wsum(ss);
    float mu  = s * (1.f / 384.f);
    float var = ss * (1.f / 384.f) - mu * mu;
    float rs  = 1.f / sqrtf(var + 1e-6f);

    const float* ab = mod_ab + (size_t)cell * 2304;
    #pragma unroll
    for (int j = 0; j < 6; j++) {
        int d = lane + 64 * j;
        float xn = (v[j] - mu) * rs * gamma[d] + beta[d];
        float o  = xn * (1.f + ab[d]) + ab[384 + d];
        split_bf16(o, ohi[(size_t)p * D + d], olo[(size_t)p * D + d]);
    }
}

// ---------------------------------------------------------------------------
// MFMA GEMM, split-bf16 3-term: C[4608,N] = A @ B^T
// BM=128, BN=64, BK=32, 4 waves (2x2, 64x32 per wave), double-buffered LDS,
// 2-phase pipeline, bijective XCD swizzle.
// EPI 0: +bias -> f32; 1: +bias,gelu -> bf16 hi/lo; 2: split-K partial -> f32
// ---------------------------------------------------------------------------
template <int EPI, int NS>
__global__ __launch_bounds__(256) void gemm_mfma(
    const u16* __restrict__ Ah, const u16* __restrict__ Al,
    const u16* __restrict__ Bh, const u16* __restrict__ Bl,
    const float* __restrict__ bias,
    float* __restrict__ Cf, u16* __restrict__ Ch, u16* __restrict__ Cl,
    int N, int K)
{
    __shared__ u16 lds[24576];   // 2 x 12288 (48 KB)
    const int tid  = threadIdx.x;
    const int lane = tid & 63;
    const int wid  = tid >> 6;

    // bijective XCD swizzle (m204)
    const int nwg = gridDim.x;
    const int q = nwg >> 3, r = nwg & 7;
    const int xcd = blockIdx.x & 7, loc = blockIdx.x >> 3;
    const int wgid = (xcd < r ? xcd * (q + 1) : r * (q + 1) + (xcd - r) * q) + loc;

    const int nx = N >> 6;                 // column blocks
    const int per = nx * 36;               // blocks per K-split (M/128 = 36)
    const int bz  = wgid / per;
    const int id2 = wgid - bz * per;
    const int by  = id2 / nx;
    const int bx  = id2 - by * nx;

    const int m0 = by * 128;
    const int n0 = bx * 64;
    const int kPer = K / NS;
    const int kbeg = bz * kPer;
    const int nt = kPer >> 5;

    const int wr = wid >> 1, wc = wid & 1;

    // staging: 6 chunks of 16B per thread
    const u16* gsrc[6];
    int loff[6];
    #pragma unroll
    for (int s = 0; s < 6; s++) {
        int c = tid + (s << 8);
        const u16* base; int ks, row;
        if (c < 512)        { ks = c >> 7;           row = c & 127; base = Ah + (size_t)(m0 + row) * K; }
        else if (c < 1024)  { int cc = c - 512;  ks = cc >> 7; row = cc & 127; base = Al + (size_t)(m0 + row) * K; }
        else if (c < 1280)  { int cc = c - 1024; ks = cc >> 6; row = cc & 63;  base = Bh + (size_t)(n0 + row) * K; }
        else                { int cc = c - 1280; ks = cc >> 6; row = cc & 63;  base = Bl + (size_t)(n0 + row) * K; }
        gsrc[s] = base + ks * 8;
        loff[s] = c * 8;
    }

    f32x4 acc[4][2] = {};
    const int ks = lane >> 4;
    const int fr = lane & 15;

    #pragma unroll
    for (int s = 0; s < 6; s++) GLOAD16(gsrc[s] + kbeg, &lds[loff[s]]);
    __syncthreads();

    int cur = 0;
    for (int kt = 0; kt < nt; kt++) {
        if (kt + 1 < nt) {
            int k0 = kbeg + ((kt + 1) << 5);
            int dbo = (cur ^ 1) * 12288;
            #pragma unroll
            for (int s = 0; s < 6; s++) GLOAD16(gsrc[s] + k0, &lds[dbo + loff[s]]);
        }
        const int b0 = cur * 12288;
        bf16x8 ah[4], al[4], bh[2], bl[2];
        #pragma unroll
        for (int m = 0; m < 4; m++) {
            int ai = b0 + (ks * 128 + wr * 64 + m * 16 + fr) * 8;
            ah[m] = *(const bf16x8*)&lds[ai];
            al[m] = *(const bf16x8*)&lds[4096 + ai];
        }
        #pragma unroll
        for (int n = 0; n < 2; n++) {
            int bi = b0 + (ks * 64 + wc * 32 + n * 16 + fr) * 8;
            bh[n] = *(const bf16x8*)&lds[8192 + bi];
            bl[n] = *(const bf16x8*)&lds[10240 + bi];
        }
        #pragma unroll
        for (int m = 0; m < 4; m++)
            #pragma unroll
            for (int n = 0; n < 2; n++) {
                acc[m][n] = __builtin_amdgcn_mfma_f32_16x16x32_bf16(ah[m], bh[n], acc[m][n], 0, 0, 0);
                acc[m][n] = __builtin_amdgcn_mfma_f32_16x16x32_bf16(ah[m], bl[n], acc[m][n], 0, 0, 0);
                acc[m][n] = __builtin_amdgcn_mfma_f32_16x16x32_bf16(al[m], bh[n], acc[m][n], 0, 0, 0);
            }
        __syncthreads();
        cur ^= 1;
    }

    const int r4 = ks * 4;
    #pragma unroll
    for (int m = 0; m < 4; m++) {
        #pragma unroll
        for (int n = 0; n < 2; n++) {
            #pragma unroll
            for (int j = 0; j < 4; j++) {
                int row = m0 + wr * 64 + m * 16 + r4 + j;
                int col = n0 + wc * 32 + n * 16 + fr;
                float v = acc[m][n][j];
                if (EPI == 0) {
                    Cf[(size_t)row * N + col] = v + bias[col];
                } else if (EPI == 1) {
                    float t = v + bias[col];
                    float c = 0.7978845608028654f * (t + 0.044715f * t * t * t);
                    float e = __expf(2.f * c);
                    float th = (e - 1.f) / (e + 1.f);
                    float g = 0.5f * t * (1.f + th);
                    size_t idx = (size_t)row * N + col;
                    split_bf16(g, Ch[idx], Cl[idx]);
                } else {
                    Cf[((size_t)bz * NPIX + row) * N + col] = v;
                }
            }
        }
    }
}

// ---------------------------------------------------------------------------
// Split-K reduce + bias + gate + residual (N=384, 4 partials).
// gate points at the per-cell gate block base; cell stride 2304.
// ---------------------------------------------------------------------------
__global__ __launch_bounds__(256) void reduce_gate(
    const float* __restrict__ part, const float* __restrict__ bias,
    const float* __restrict__ gate, const float* __restrict__ resid,
    float* __restrict__ out)
{
    int i4 = blockIdx.x * 256 + threadIdx.x;   // 442368 float4s
    int row = i4 / 96, c4 = i4 % 96;
    int b  = row / 2304;
    int hh = (row / 48) % 48;
    int ww = row % 48;
    int cell = b * 36 + (hh >> 3) * 6 + (ww >> 3);

    const float4* P = (const float4*)part;
    float4 p0 = P[i4], p1 = P[i4 + 442368], p2 = P[i4 + 2 * 442368], p3 = P[i4 + 3 * 442368];
    float4 bb = ((const float4*)bias)[c4];
    float4 gg = ((const float4*)(gate + (size_t)cell * 2304))[c4];
    float4 rr = ((const float4*)resid)[i4];
    float4 o;
    o.x = rr.x + (p0.x + p1.x + p2.x + p3.x + bb.x) * gg.x;
    o.y = rr.y + (p0.y + p1.y + p2.y + p3.y + bb.y) * gg.y;
    o.z = rr.z + (p0.z + p1.z + p2.z + p3.z + bb.z) * gg.z;
    o.w = rr.w + (p0.w + p1.w + p2.w + p3.w + bb.w) * gg.w;
    ((float4*)out)[i4] = o;
}

// ---------------------------------------------------------------------------
// 7x7 neighborhood attention, one wave per (pixel,head), 8x8 lane decomp.
// ---------------------------------------------------------------------------
__global__ __launch_bounds__(256) void natten_kernel(
    const float* __restrict__ qkv, u16* __restrict__ ohi, u16* __restrict__ olo)
{
    int wid  = (blockIdx.x * blockDim.x + threadIdx.x) >> 6;
    int lane = threadIdx.x & 63;
    int head = wid % 6;
    int p    = wid / 6;
    int b  = p / 2304;
    int hh = (p / 48) % 48;
    int ww = p % 48;
    int sh = hh - 3; sh = sh < 0 ? 0 : (sh > 41 ? 41 : sh);
    int sw = ww - 3; sw = sw < 0 ? 0 : (sw > 41 ? 41 : sw);
    int pb = b * 2304;

    const int n_sub = lane >> 3;
    const int d_sub = lane & 7;
    const int dof = head * 64 + d_sub * 8;

    const float* qp = qkv + (size_t)p * C3 + dof;
    float4 q0 = *(const float4*)qp;
    float4 q1 = *(const float4*)(qp + 4);
    q0.x *= 0.125f; q0.y *= 0.125f; q0.z *= 0.125f; q0.w *= 0.125f;
    q1.x *= 0.125f; q1.y *= 0.125f; q1.z *= 0.125f; q1.w *= 0.125f;

    float L[7];
    #pragma unroll
    for (int t = 0; t < 7; t++) {
        int n = t * 8 + n_sub;
        int nn = n > 48 ? 48 : n;
        int nr = nn / 7, nc = nn - nr * 7;
        const float* kp = qkv + (size_t)(pb + (sh + nr) * 48 + (sw + nc)) * C3 + 384 + dof;
        float4 k0 = *(const float4*)kp;
        float4 k1 = *(const float4*)(kp + 4);
        float d = q0.x * k0.x + q0.y * k0.y + q0.z * k0.z + q0.w * k0.w
                + q1.x * k1.x + q1.y * k1.y + q1.z * k1.z + q1.w * k1.w;
        d += __shfl_xor(d, 1);
        d += __shfl_xor(d, 2);
        d += __shfl_xor(d, 4);
        L[t] = (n < 49) ? d : -INFINITY;
    }

    float m = L[0];
    #pragma unroll
    for (int t = 1; t < 7; t++) m = fmaxf(m, L[t]);
    m = fmaxf(m, __shfl_xor(m, 8));
    m = fmaxf(m, __shfl_xor(m, 16));
    m = fmaxf(m, __shfl_xor(m, 32));

    float w[7]; float s = 0.f;
    #pragma unroll
    for (int t = 0; t < 7; t++) {
        w[t] = (L[t] == -INFINITY) ? 0.f : __expf(L[t] - m);
        s += w[t];
    }
    s += __shfl_xor(s, 8);
    s += __shfl_xor(s, 16);
    s += __shfl_xor(s, 32);
    float inv = 1.f / s;
    #pragma unroll
    for (int t = 0; t < 7; t++) w[t] *= inv;

    float a0x = 0.f, a0y = 0.f, a0z = 0.f, a0w = 0.f;
    float a1x = 0.f, a1y = 0.f, a1z = 0.f, a1w = 0.f;
    #pragma unroll
    for (int t = 0; t < 7; t++) {
        int n = t * 8 + n_sub;
        int nn = n > 48 ? 48 : n;
        int nr = nn / 7, nc = nn - nr * 7;
        const float* vp = qkv + (size_t)(pb + (sh + nr) * 48 + (sw + nc)) * C3 + 768 + dof;
        float4 v0 = *(const float4*)vp;
        float4 v1 = *(const float4*)(vp + 4);
        float wn = w[t];
        a0x = fmaf(wn, v0.x, a0x); a0y = fmaf(wn, v0.y, a0y);
        a0z = fmaf(wn, v0.z, a0z); a0w = fmaf(wn, v0.w, a0w);
        a1x = fmaf(wn, v1.x, a1x); a1y = fmaf(wn, v1.y, a1y);
        a1z = fmaf(wn, v1.z, a1z); a1w = fmaf(wn, v1.w, a1w);
    }
    #pragma unroll
    for (int o = 8; o <= 32; o <<= 1) {
        a0x += __shfl_xor(a0x, o); a0y += __shfl_xor(a0y, o);
        a0z += __shfl_xor(a0z, o); a0w += __shfl_xor(a0w, o);
        a1x += __shfl_xor(a1x, o); a1y += __shfl_xor(a1y, o);
        a1z += __shfl_xor(a1z, o); a1w += __shfl_xor(a1w, o);
    }

    if (lane < 8) {
        float av[8] = {a0x, a0y, a0z, a0w, a1x, a1y, a1z, a1w};
        u16 hi8[8], lo8[8];
        #pragma unroll
        for (int i = 0; i < 8; i++) split_bf16(av[i], hi8[i], lo8[i]);
        size_t oi = (size_t)p * D + head * 64 + lane * 8;
        *(uint4*)(ohi + oi) = *(uint4*)hi8;
        *(uint4*)(olo + oi) = *(uint4*)lo8;
    }
}

// ---------------------------------------------------------------------------
extern "C" void kernel_launch(void* const* d_in, const int* in_sizes, int n_in,
                              void* d_out, int out_size, void* d_ws, size_t ws_size,
                              hipStream_t stream)
{
    (void)in_sizes; (void)n_in; (void)out_size; (void)ws_size;
    const float* x      = (const float*)d_in[0];
    const float* cond   = (const float*)d_in[1];
    const float* ln1_g  = (const float*)d_in[2];
    const float* ln1_b  = (const float*)d_in[3];
    const float* ada1_v = (const float*)d_in[4];
    const float* ada1_g = (const float*)d_in[5];
    const float* ln2_g  = (const float*)d_in[6];
    const float* ln2_b  = (const float*)d_in[7];
    const float* ada2_v = (const float*)d_in[8];
    const float* ada2_g = (const float*)d_in[9];
    const float* gate1_v = (const float*)d_in[10];
    const float* gate1_g = (const float*)d_in[11];
    const float* gate2_v = (const float*)d_in[12];
    const float* gate2_g = (const float*)d_in[13];
    const float* w_qkv  = (const float*)d_in[14];
    const float* b_qkv  = (const float*)d_in[15];
    const float* w_out  = (const float*)d_in[16];
    const float* b_out  = (const float*)d_in[17];
    const float* w_mlp1 = (const float*)d_in[18];
    const float* b_mlp1 = (const float*)d_in[19];
    const float* w_mlp2 = (const float*)d_in[20];
    const float* b_mlp2 = (const float*)d_in[21];

    char* ws = (char*)d_ws;
    float* mod  = (float*)(ws + OFF_MOD);        // [72][2304]
    float* big  = (float*)(ws + OFF_BIG);
    u16* h_hi   = (u16*)(ws + OFF_HHI);
    u16* h_lo   = (u16*)(ws + OFF_HLO);
    u16* a_hi   = (u16*)(ws + OFF_AHI);
    u16* a_lo   = (u16*)(ws + OFF_ALO);
    u16* m_hi   = (u16*)(ws + OFF_MHI);
    u16* m_lo   = (u16*)(ws + OFF_MLO);
    u16* w_hi   = (u16*)(ws + OFF_WHI);
    u16* w_lo   = (u16*)(ws + OFF_WLO);
    // early temporaries inside big
    char* bigc  = ws + OFF_BIG;
    u16* mv_hi  = (u16*)(bigc + BIGOFF_MODV_HI);
    u16* mv_lo  = (u16*)(bigc + BIGOFF_MODV_LO);
    u16* sc_hi  = (u16*)(bigc + BIGOFF_SC_HI);
    u16* sc_lo  = (u16*)(bigc + BIGOFF_SC_LO);
    float* invn = (float*)(bigc + BIGOFF_INVN);
    float* x2   = (float*)d_out;

    // 1. weights + modulation V -> bf16 hi/lo
    wconv_kernel<<<2592, 256, 0, stream>>>(
        w_qkv, w_out, w_mlp1, w_mlp2, ada1_v, ada2_v, gate1_v, gate2_v,
        w_hi, w_lo, mv_hi, mv_lo);

    // 2. inv-norms + silu(cond) (padded to 128 cells)
    modprep_kernel<<<608, 256, 0, stream>>>(
        cond, ada1_v, ada1_g, ada2_v, ada2_g, gate1_v, gate1_g, gate2_v, gate2_g,
        invn, sc_hi, sc_lo);

    // 3. mod[72,2304] = sc @ modV^T * invn
    modgemm_mfma<<<36, 256, 0, stream>>>(sc_hi, sc_lo, mv_hi, mv_lo, invn, mod);

    // 4. h = adaln1(x)
    adaln_kernel<<<NPIX / 4, 256, 0, stream>>>(x, ln1_g, ln1_b, mod, h_hi, h_lo);

    // 5. qkv (overwrites big; mod temporaries dead)
    gemm_mfma<0, 1><<<648, 256, 0, stream>>>(
        h_hi, h_lo, w_hi + WOFF_QKV, w_lo + WOFF_QKV, b_qkv,
        big, nullptr, nullptr, C3, D);

    // 6. neighborhood attention
    natten_kernel<<<(NPIX * 6) / 4, 256, 0, stream>>>(big, a_hi, a_lo);

    // 7. out-proj split-K=4
    gemm_mfma<2, 4><<<864, 256, 0, stream>>>(
        a_hi, a_lo, w_hi + WOFF_OUT, w_lo + WOFF_OUT, nullptr,
        big, nullptr, nullptr, D, D);

    // 8. x2 = x + (sum + b_out) * gate1
    reduce_gate<<<1728, 256, 0, stream>>>(big, b_out, mod + 1536, x, x2);

    // 9. h = adaln2(x2)
    adaln_kernel<<<NPIX / 4, 256, 0, stream>>>(x2, ln2_g, ln2_b, mod + 768, h_hi, h_lo);

    // 10. mid = gelu(h @ w_mlp1^T + b_mlp1)
    gemm_mfma<1, 1><<<864, 256, 0, stream>>>(
        h_hi, h_lo, w_hi + WOFF_M1, w_lo + WOFF_M1, b_mlp1,
        nullptr, m_hi, m_lo, DMLP, D);

    // 11. mlp2 split-K=4 (K=1536)
    gemm_mfma<2, 4><<<864, 256, 0, stream>>>(
        m_hi, m_lo, w_hi + WOFF_M2, w_lo + WOFF_M2, nullptr,
        big, nullptr, nullptr, D, DMLP);

    // 12. out = x2 + (sum + b_mlp2) * gate2
    reduce_gate<<<1728, 256, 0, stream>>>(big, b_mlp2, mod + 1920, x2, x2);
}

// Round 7
// 331.360 us; speedup vs baseline: 1.6404x; 1.0012x over previous
//
#include <hip/hip_runtime.h>
#include <hip/hip_bf16.h>
#include <math.h>

// Shapes fixed: B=2, H=W=48, D=384, CD=384, NH=6, hd=64, KS=7
#define NPIX 4608
#define D 384
#define CD 384
#define C3 1152
#define DMLP 1536
#define NCELL 72

typedef unsigned short u16;
typedef __attribute__((ext_vector_type(8))) short bf16x8;
typedef __attribute__((ext_vector_type(4))) float f32x4;

// ---------------- workspace layout (bytes) ----------------
#define OFF_MOD   0
#define OFF_BIG   663552
#define OFF_HHI   28975104
#define OFF_HLO   32514048
#define OFF_AHI   36052992
#define OFF_ALO   39591936
#define OFF_MHI   43130880
#define OFF_MLO   57286656
#define OFF_WHI   71442432
#define OFF_WLO   74981376
// early-phase temporaries inside BIG (dead before qkv GEMM writes big):
#define BIGOFF_MODV_HI  0
#define BIGOFF_MODV_LO  1769472
#define BIGOFF_SC_HI    3538944
#define BIGOFF_SC_LO    3637248
#define BIGOFF_INVN     3735552
// mod row-major [72][2304]: a1[0,384) b1[384,768) a2[768,1152) b2[1152,1536)
// gate1[1536,1920) gate2[1920,2304)
#define WOFF_QKV  0
#define WOFF_OUT  442368
#define WOFF_M1   589824
#define WOFF_M2   1179648

#define GLOAD16(g, l) __builtin_amdgcn_global_load_lds( \
    (const __attribute__((address_space(1))) unsigned int*)(g), \
    (__attribute__((address_space(3))) unsigned int*)(l), 16, 0, 0)

__device__ __forceinline__ float wsum(float v) {
    #pragma unroll
    for (int o = 32; o > 0; o >>= 1) v += __shfl_xor(v, o);
    return v;
}
__device__ __forceinline__ void split_bf16(float x, u16& h, u16& l) {
    __hip_bfloat16 bh = __float2bfloat16(x);
    float fh = __bfloat162float(bh);
    __hip_bfloat16 bl = __float2bfloat16(x - fh);
    h = *(u16*)&bh; l = *(u16*)&bl;
}

// ---------------------------------------------------------------------------
// Weight conversion: fp32 -> bf16 hi/lo (4 main weights + 4 modulation V)
// ---------------------------------------------------------------------------
__global__ __launch_bounds__(256) void wconv_kernel(
    const float* __restrict__ wq, const float* __restrict__ wo,
    const float* __restrict__ w1, const float* __restrict__ w2,
    const float* __restrict__ a1v, const float* __restrict__ a2v,
    const float* __restrict__ g1v, const float* __restrict__ g2v,
    u16* __restrict__ whi, u16* __restrict__ wlo,
    u16* __restrict__ mvhi, u16* __restrict__ mvlo)
{
    int i4 = blockIdx.x * 256 + threadIdx.x;   // 663552 float4s total
    const float* src; int l4; u16 *dh, *dl; int o;
    if (i4 < 442368) {
        if (i4 < 110592)        { src = wq; l4 = i4; }
        else if (i4 < 147456)   { src = wo; l4 = i4 - 110592; }
        else if (i4 < 294912)   { src = w1; l4 = i4 - 147456; }
        else                    { src = w2; l4 = i4 - 294912; }
        dh = whi; dl = wlo; o = i4 * 4;
    } else {
        int j4 = i4 - 442368;
        if (j4 < 73728)         { src = a1v; l4 = j4; }
        else if (j4 < 147456)   { src = a2v; l4 = j4 - 73728; }
        else if (j4 < 184320)   { src = g1v; l4 = j4 - 147456; }
        else                    { src = g2v; l4 = j4 - 184320; }
        dh = mvhi; dl = mvlo; o = j4 * 4;
    }
    float4 v = ((const float4*)src)[l4];
    split_bf16(v.x, dh[o+0], dl[o+0]);
    split_bf16(v.y, dh[o+1], dl[o+1]);
    split_bf16(v.z, dh[o+2], dl[o+2]);
    split_bf16(v.w, dh[o+3], dl[o+3]);
}

// ---------------------------------------------------------------------------
// modprep: wid<2304 -> inv_norm[row] = g/||v_row||; else silu(cond) -> sc
// ---------------------------------------------------------------------------
__global__ __launch_bounds__(256) void modprep_kernel(
    const float* __restrict__ cond,
    const float* __restrict__ a1v, const float* __restrict__ a1g,
    const float* __restrict__ a2v, const float* __restrict__ a2g,
    const float* __restrict__ g1v, const float* __restrict__ g1g,
    const float* __restrict__ g2v, const float* __restrict__ g2g,
    float* __restrict__ invn, u16* __restrict__ schi, u16* __restrict__ sclo)
{
    int wid  = (blockIdx.x * blockDim.x + threadIdx.x) >> 6;
    int lane = threadIdx.x & 63;
    if (wid < 2304) {
        const float* V; float g; int r;
        if (wid < 768)        { r = wid;        V = a1v; g = a1g[r]; }
        else if (wid < 1536)  { r = wid - 768;  V = a2v; g = a2g[r]; }
        else if (wid < 1920)  { r = wid - 1536; V = g1v; g = g1g[r]; }
        else                  { r = wid - 1920; V = g2v; g = g2g[r]; }
        const float* vrow = V + r * CD;
        float nrm = 0.f;
        #pragma unroll
        for (int j = 0; j < 6; j++) {
            float v = vrow[lane + 64 * j];
            nrm += v * v;
        }
        nrm = wsum(nrm);
        if (lane == 0) invn[wid] = g / sqrtf(nrm);
    } else {
        int cell = wid - 2304;
        #pragma unroll
        for (int j = 0; j < 6; j++) {
            int k = lane + 64 * j;
            float val = 0.f;
            if (cell < NCELL) {
                float c = cond[cell * CD + k];
                val = c / (1.f + __expf(-c));
            }
            split_bf16(val, schi[cell * CD + k], sclo[cell * CD + k]);
        }
    }
}

// ---------------------------------------------------------------------------
// mod GEMM: mod[72,2304] = sc[128,384] @ modV[2304,384]^T, x inv_norm[col]
// ---------------------------------------------------------------------------
__global__ __launch_bounds__(256) void modgemm_mfma(
    const u16* __restrict__ Ah, const u16* __restrict__ Al,
    const u16* __restrict__ Bh, const u16* __restrict__ Bl,
    const float* __restrict__ invn, float* __restrict__ mod)
{
    __shared__ u16 lds[24576];
    const int tid  = threadIdx.x;
    const int lane = tid & 63;
    const int wid  = tid >> 6;
    const int n0 = blockIdx.x * 64;
    const int K = 384, nt = 12;
    const int wr = wid >> 1, wc = wid & 1;

    const u16* gsrc[6];
    int loff[6];
    #pragma unroll
    for (int s = 0; s < 6; s++) {
        int c = tid + (s << 8);
        const u16* base; int ks, row;
        if (c < 512)        { ks = c >> 7;           row = c & 127; base = Ah + (size_t)row * K; }
        else if (c < 1024)  { int cc = c - 512;  ks = cc >> 7; row = cc & 127; base = Al + (size_t)row * K; }
        else if (c < 1280)  { int cc = c - 1024; ks = cc >> 6; row = cc & 63;  base = Bh + (size_t)(n0 + row) * K; }
        else                { int cc = c - 1280; ks = cc >> 6; row = cc & 63;  base = Bl + (size_t)(n0 + row) * K; }
        gsrc[s] = base + ks * 8;
        loff[s] = c * 8;
    }

    f32x4 acc[4][2] = {};
    const int ks = lane >> 4;
    const int fr = lane & 15;

    #pragma unroll
    for (int s = 0; s < 6; s++) GLOAD16(gsrc[s], &lds[loff[s]]);
    __syncthreads();

    int cur = 0;
    for (int kt = 0; kt < nt; kt++) {
        if (kt + 1 < nt) {
            int k0 = (kt + 1) << 5;
            int dbo = (cur ^ 1) * 12288;
            #pragma unroll
            for (int s = 0; s < 6; s++) GLOAD16(gsrc[s] + k0, &lds[dbo + loff[s]]);
        }
        const int b0 = cur * 12288;
        bf16x8 ah[4], al[4], bh[2], bl[2];
        #pragma unroll
        for (int m = 0; m < 4; m++) {
            int ai = b0 + (ks * 128 + wr * 64 + m * 16 + fr) * 8;
            ah[m] = *(const bf16x8*)&lds[ai];
            al[m] = *(const bf16x8*)&lds[4096 + ai];
        }
        #pragma unroll
        for (int n = 0; n < 2; n++) {
            int bi = b0 + (ks * 64 + wc * 32 + n * 16 + fr) * 8;
            bh[n] = *(const bf16x8*)&lds[8192 + bi];
            bl[n] = *(const bf16x8*)&lds[10240 + bi];
        }
        #pragma unroll
        for (int m = 0; m < 4; m++)
            #pragma unroll
            for (int n = 0; n < 2; n++) {
                acc[m][n] = __builtin_amdgcn_mfma_f32_16x16x32_bf16(ah[m], bh[n], acc[m][n], 0, 0, 0);
                acc[m][n] = __builtin_amdgcn_mfma_f32_16x16x32_bf16(ah[m], bl[n], acc[m][n], 0, 0, 0);
                acc[m][n] = __builtin_amdgcn_mfma_f32_16x16x32_bf16(al[m], bh[n], acc[m][n], 0, 0, 0);
            }
        __syncthreads();
        cur ^= 1;
    }

    const int r4 = ks * 4;
    #pragma unroll
    for (int m = 0; m < 4; m++) {
        #pragma unroll
        for (int n = 0; n < 2; n++) {
            #pragma unroll
            for (int j = 0; j < 4; j++) {
                int row = wr * 64 + m * 16 + r4 + j;
                int col = n0 + wc * 32 + n * 16 + fr;
                if (row < NCELL)
                    mod[(size_t)row * 2304 + col] = acc[m][n][j] * invn[col];
            }
        }
    }
}

// ---------------------------------------------------------------------------
// AdaLN: LayerNorm + per-cell (1+a)*xn + b; mod row-major [72][2304]
// ---------------------------------------------------------------------------
__global__ __launch_bounds__(256) void adaln_kernel(
    const float* __restrict__ x,
    const float* __restrict__ gamma, const float* __restrict__ beta,
    const float* __restrict__ mod_ab,
    u16* __restrict__ ohi, u16* __restrict__ olo)
{
    int p    = (blockIdx.x * blockDim.x + threadIdx.x) >> 6;
    int lane = threadIdx.x & 63;
    int b  = p / 2304;
    int hh = (p / 48) % 48;
    int ww = p % 48;
    int cell = b * 36 + (hh >> 3) * 6 + (ww >> 3);

    const float* xr = x + (size_t)p * D;
    float v[6]; float s = 0.f, ss = 0.f;
    #pragma unroll
    for (int j = 0; j < 6; j++) {
        v[j] = xr[lane + 64 * j];
        s  += v[j];
        ss += v[j] * v[j];
    }
    s = wsum(s); ss = wsum(ss);
    float mu  = s * (1.f / 384.f);
    float var = ss * (1.f / 384.f) - mu * mu;
    float rs  = 1.f / sqrtf(var + 1e-6f);

    const float* ab = mod_ab + (size_t)cell * 2304;
    #pragma unroll
    for (int j = 0; j < 6; j++) {
        int d = lane + 64 * j;
        float xn = (v[j] - mu) * rs * gamma[d] + beta[d];
        float o  = xn * (1.f + ab[d]) + ab[384 + d];
        split_bf16(o, ohi[(size_t)p * D + d], olo[(size_t)p * D + d]);
    }
}

// ---------------------------------------------------------------------------
// MFMA GEMM, split-bf16 3-term: C[4608,N] = A @ B^T
// BM=128, BN=64, BK=32, 4 waves, double-buffered, XCD swizzle.
// ---------------------------------------------------------------------------
template <int EPI, int NS>
__global__ __launch_bounds__(256) void gemm_mfma(
    const u16* __restrict__ Ah, const u16* __restrict__ Al,
    const u16* __restrict__ Bh, const u16* __restrict__ Bl,
    const float* __restrict__ bias,
    float* __restrict__ Cf, u16* __restrict__ Ch, u16* __restrict__ Cl,
    int N, int K)
{
    __shared__ u16 lds[24576];
    const int tid  = threadIdx.x;
    const int lane = tid & 63;
    const int wid  = tid >> 6;

    const int nwg = gridDim.x;
    const int q = nwg >> 3, r = nwg & 7;
    const int xcd = blockIdx.x & 7, loc = blockIdx.x >> 3;
    const int wgid = (xcd < r ? xcd * (q + 1) : r * (q + 1) + (xcd - r) * q) + loc;

    const int nx = N >> 6;
    const int per = nx * 36;
    const int bz  = wgid / per;
    const int id2 = wgid - bz * per;
    const int by  = id2 / nx;
    const int bx  = id2 - by * nx;

    const int m0 = by * 128;
    const int n0 = bx * 64;
    const int kPer = K / NS;
    const int kbeg = bz * kPer;
    const int nt = kPer >> 5;

    const int wr = wid >> 1, wc = wid & 1;

    const u16* gsrc[6];
    int loff[6];
    #pragma unroll
    for (int s = 0; s < 6; s++) {
        int c = tid + (s << 8);
        const u16* base; int ks, row;
        if (c < 512)        { ks = c >> 7;           row = c & 127; base = Ah + (size_t)(m0 + row) * K; }
        else if (c < 1024)  { int cc = c - 512;  ks = cc >> 7; row = cc & 127; base = Al + (size_t)(m0 + row) * K; }
        else if (c < 1280)  { int cc = c - 1024; ks = cc >> 6; row = cc & 63;  base = Bh + (size_t)(n0 + row) * K; }
        else                { int cc = c - 1280; ks = cc >> 6; row = cc & 63;  base = Bl + (size_t)(n0 + row) * K; }
        gsrc[s] = base + ks * 8;
        loff[s] = c * 8;
    }

    f32x4 acc[4][2] = {};
    const int ks = lane >> 4;
    const int fr = lane & 15;

    #pragma unroll
    for (int s = 0; s < 6; s++) GLOAD16(gsrc[s] + kbeg, &lds[loff[s]]);
    __syncthreads();

    int cur = 0;
    for (int kt = 0; kt < nt; kt++) {
        if (kt + 1 < nt) {
            int k0 = kbeg + ((kt + 1) << 5);
            int dbo = (cur ^ 1) * 12288;
            #pragma unroll
            for (int s = 0; s < 6; s++) GLOAD16(gsrc[s] + k0, &lds[dbo + loff[s]]);
        }
        const int b0 = cur * 12288;
        bf16x8 ah[4], al[4], bh[2], bl[2];
        #pragma unroll
        for (int m = 0; m < 4; m++) {
            int ai = b0 + (ks * 128 + wr * 64 + m * 16 + fr) * 8;
            ah[m] = *(const bf16x8*)&lds[ai];
            al[m] = *(const bf16x8*)&lds[4096 + ai];
        }
        #pragma unroll
        for (int n = 0; n < 2; n++) {
            int bi = b0 + (ks * 64 + wc * 32 + n * 16 + fr) * 8;
            bh[n] = *(const bf16x8*)&lds[8192 + bi];
            bl[n] = *(const bf16x8*)&lds[10240 + bi];
        }
        #pragma unroll
        for (int m = 0; m < 4; m++)
            #pragma unroll
            for (int n = 0; n < 2; n++) {
                acc[m][n] = __builtin_amdgcn_mfma_f32_16x16x32_bf16(ah[m], bh[n], acc[m][n], 0, 0, 0);
                acc[m][n] = __builtin_amdgcn_mfma_f32_16x16x32_bf16(ah[m], bl[n], acc[m][n], 0, 0, 0);
                acc[m][n] = __builtin_amdgcn_mfma_f32_16x16x32_bf16(al[m], bh[n], acc[m][n], 0, 0, 0);
            }
        __syncthreads();
        cur ^= 1;
    }

    const int r4 = ks * 4;
    #pragma unroll
    for (int m = 0; m < 4; m++) {
        #pragma unroll
        for (int n = 0; n < 2; n++) {
            #pragma unroll
            for (int j = 0; j < 4; j++) {
                int row = m0 + wr * 64 + m * 16 + r4 + j;
                int col = n0 + wc * 32 + n * 16 + fr;
                float v = acc[m][n][j];
                if (EPI == 0) {
                    Cf[(size_t)row * N + col] = v + bias[col];
                } else if (EPI == 1) {
                    float t = v + bias[col];
                    float c = 0.7978845608028654f * (t + 0.044715f * t * t * t);
                    float e = __expf(2.f * c);
                    float th = (e - 1.f) / (e + 1.f);
                    float g = 0.5f * t * (1.f + th);
                    size_t idx = (size_t)row * N + col;
                    split_bf16(g, Ch[idx], Cl[idx]);
                } else {
                    Cf[((size_t)bz * NPIX + row) * N + col] = v;
                }
            }
        }
    }
}

// ---------------------------------------------------------------------------
// Split-K reduce + bias + gate + residual (N=384, 4 partials)
// ---------------------------------------------------------------------------
__global__ __launch_bounds__(256) void reduce_gate(
    const float* __restrict__ part, const float* __restrict__ bias,
    const float* __restrict__ gate, const float* __restrict__ resid,
    float* __restrict__ out)
{
    int i4 = blockIdx.x * 256 + threadIdx.x;
    int row = i4 / 96, c4 = i4 % 96;
    int b  = row / 2304;
    int hh = (row / 48) % 48;
    int ww = row % 48;
    int cell = b * 36 + (hh >> 3) * 6 + (ww >> 3);

    const float4* P = (const float4*)part;
    float4 p0 = P[i4], p1 = P[i4 + 442368], p2 = P[i4 + 2 * 442368], p3 = P[i4 + 3 * 442368];
    float4 bb = ((const float4*)bias)[c4];
    float4 gg = ((const float4*)(gate + (size_t)cell * 2304))[c4];
    float4 rr = ((const float4*)resid)[i4];
    float4 o;
    o.x = rr.x + (p0.x + p1.x + p2.x + p3.x + bb.x) * gg.x;
    o.y = rr.y + (p0.y + p1.y + p2.y + p3.y + bb.y) * gg.y;
    o.z = rr.z + (p0.z + p1.z + p2.z + p3.z + bb.z) * gg.z;
    o.w = rr.w + (p0.w + p1.w + p2.w + p3.w + bb.w) * gg.w;
    ((float4*)out)[i4] = o;
}

// ---------------------------------------------------------------------------
// 7x7 neighborhood attention, one wave per (pixel,head), 8x8 lane decomp.
// Batched loads: all 14 K float4s issued before the dot phase, all 14 V
// float4s issued before softmax (overlap), pinned with sched_barrier(0).
// ---------------------------------------------------------------------------
__global__ __launch_bounds__(256) void natten_kernel(
    const float* __restrict__ qkv, u16* __restrict__ ohi, u16* __restrict__ olo)
{
    int wid  = (blockIdx.x * blockDim.x + threadIdx.x) >> 6;
    int lane = threadIdx.x & 63;
    int head = wid % 6;
    int p    = wid / 6;
    int b  = p / 2304;
    int hh = (p / 48) % 48;
    int ww = p % 48;
    int sh = hh - 3; sh = sh < 0 ? 0 : (sh > 41 ? 41 : sh);
    int sw = ww - 3; sw = sw < 0 ? 0 : (sw > 41 ? 41 : sw);
    int pb = b * 2304;

    const int n_sub = lane >> 3;
    const int d_sub = lane & 7;
    const int dof = head * 64 + d_sub * 8;

    // per-pass neighbor pixel offsets (reused for K and V)
    int npo[7];
    #pragma unroll
    for (int t = 0; t < 7; t++) {
        int n = t * 8 + n_sub;
        int nn = n > 48 ? 48 : n;
        int nr = nn / 7, nc = nn - nr * 7;
        npo[t] = pb + (sh + nr) * 48 + (sw + nc);
    }

    const float* qp = qkv + (size_t)p * C3 + dof;
    float4 q0 = *(const float4*)qp;
    float4 q1 = *(const float4*)(qp + 4);
    q0.x *= 0.125f; q0.y *= 0.125f; q0.z *= 0.125f; q0.w *= 0.125f;
    q1.x *= 0.125f; q1.y *= 0.125f; q1.z *= 0.125f; q1.w *= 0.125f;

    // ---- batch-issue all K loads ----
    float4 kk0[7], kk1[7];
    #pragma unroll
    for (int t = 0; t < 7; t++) {
        const float* kp = qkv + (size_t)npo[t] * C3 + 384 + dof;
        kk0[t] = *(const float4*)kp;
        kk1[t] = *(const float4*)(kp + 4);
    }
    __builtin_amdgcn_sched_barrier(0);

    // ---- QK dots + 3-level butterfly over d_sub ----
    float L[7];
    #pragma unroll
    for (int t = 0; t < 7; t++) {
        float d = q0.x * kk0[t].x + q0.y * kk0[t].y + q0.z * kk0[t].z + q0.w * kk0[t].w
                + q1.x * kk1[t].x + q1.y * kk1[t].y + q1.z * kk1[t].z + q1.w * kk1[t].w;
        d += __shfl_xor(d, 1);
        d += __shfl_xor(d, 2);
        d += __shfl_xor(d, 4);
        L[t] = (t * 8 + n_sub < 49) ? d : -INFINITY;
    }

    // ---- batch-issue all V loads (overlap softmax) ----
    float4 vv0[7], vv1[7];
    #pragma unroll
    for (int t = 0; t < 7; t++) {
        const float* vp = qkv + (size_t)npo[t] * C3 + 768 + dof;
        vv0[t] = *(const float4*)vp;
        vv1[t] = *(const float4*)(vp + 4);
    }
    __builtin_amdgcn_sched_barrier(0);

    // ---- distributed softmax ----
    float m = L[0];
    #pragma unroll
    for (int t = 1; t < 7; t++) m = fmaxf(m, L[t]);
    m = fmaxf(m, __shfl_xor(m, 8));
    m = fmaxf(m, __shfl_xor(m, 16));
    m = fmaxf(m, __shfl_xor(m, 32));

    float w[7]; float s = 0.f;
    #pragma unroll
    for (int t = 0; t < 7; t++) {
        w[t] = (L[t] == -INFINITY) ? 0.f : __expf(L[t] - m);
        s += w[t];
    }
    s += __shfl_xor(s, 8);
    s += __shfl_xor(s, 16);
    s += __shfl_xor(s, 32);
    float inv = 1.f / s;
    #pragma unroll
    for (int t = 0; t < 7; t++) w[t] *= inv;

    // ---- PV ----
    float a0x = 0.f, a0y = 0.f, a0z = 0.f, a0w = 0.f;
    float a1x = 0.f, a1y = 0.f, a1z = 0.f, a1w = 0.f;
    #pragma unroll
    for (int t = 0; t < 7; t++) {
        float wn = w[t];
        a0x = fmaf(wn, vv0[t].x, a0x); a0y = fmaf(wn, vv0[t].y, a0y);
        a0z = fmaf(wn, vv0[t].z, a0z); a0w = fmaf(wn, vv0[t].w, a0w);
        a1x = fmaf(wn, vv1[t].x, a1x); a1y = fmaf(wn, vv1[t].y, a1y);
        a1z = fmaf(wn, vv1[t].z, a1z); a1w = fmaf(wn, vv1[t].w, a1w);
    }
    #pragma unroll
    for (int o = 8; o <= 32; o <<= 1) {
        a0x += __shfl_xor(a0x, o); a0y += __shfl_xor(a0y, o);
        a0z += __shfl_xor(a0z, o); a0w += __shfl_xor(a0w, o);
        a1x += __shfl_xor(a1x, o); a1y += __shfl_xor(a1y, o);
        a1z += __shfl_xor(a1z, o); a1w += __shfl_xor(a1w, o);
    }

    if (lane < 8) {
        float av[8] = {a0x, a0y, a0z, a0w, a1x, a1y, a1z, a1w};
        u16 hi8[8], lo8[8];
        #pragma unroll
        for (int i = 0; i < 8; i++) split_bf16(av[i], hi8[i], lo8[i]);
        size_t oi = (size_t)p * D + head * 64 + lane * 8;
        *(uint4*)(ohi + oi) = *(uint4*)hi8;
        *(uint4*)(olo + oi) = *(uint4*)lo8;
    }
}

// ---------------------------------------------------------------------------
extern "C" void kernel_launch(void* const* d_in, const int* in_sizes, int n_in,
                              void* d_out, int out_size, void* d_ws, size_t ws_size,
                              hipStream_t stream)
{
    (void)in_sizes; (void)n_in; (void)out_size; (void)ws_size;
    const float* x      = (const float*)d_in[0];
    const float* cond   = (const float*)d_in[1];
    const float* ln1_g  = (const float*)d_in[2];
    const float* ln1_b  = (const float*)d_in[3];
    const float* ada1_v = (const float*)d_in[4];
    const float* ada1_g = (const float*)d_in[5];
    const float* ln2_g  = (const float*)d_in[6];
    const float* ln2_b  = (const float*)d_in[7];
    const float* ada2_v = (const float*)d_in[8];
    const float* ada2_g = (const float*)d_in[9];
    const float* gate1_v = (const float*)d_in[10];
    const float* gate1_g = (const float*)d_in[11];
    const float* gate2_v = (const float*)d_in[12];
    const float* gate2_g = (const float*)d_in[13];
    const float* w_qkv  = (const float*)d_in[14];
    const float* b_qkv  = (const float*)d_in[15];
    const float* w_out  = (const float*)d_in[16];
    const float* b_out  = (const float*)d_in[17];
    const float* w_mlp1 = (const float*)d_in[18];
    const float* b_mlp1 = (const float*)d_in[19];
    const float* w_mlp2 = (const float*)d_in[20];
    const float* b_mlp2 = (const float*)d_in[21];

    char* ws = (char*)d_ws;
    float* mod  = (float*)(ws + OFF_MOD);
    float* big  = (float*)(ws + OFF_BIG);
    u16* h_hi   = (u16*)(ws + OFF_HHI);
    u16* h_lo   = (u16*)(ws + OFF_HLO);
    u16* a_hi   = (u16*)(ws + OFF_AHI);
    u16* a_lo   = (u16*)(ws + OFF_ALO);
    u16* m_hi   = (u16*)(ws + OFF_MHI);
    u16* m_lo   = (u16*)(ws + OFF_MLO);
    u16* w_hi   = (u16*)(ws + OFF_WHI);
    u16* w_lo   = (u16*)(ws + OFF_WLO);
    char* bigc  = ws + OFF_BIG;
    u16* mv_hi  = (u16*)(bigc + BIGOFF_MODV_HI);
    u16* mv_lo  = (u16*)(bigc + BIGOFF_MODV_LO);
    u16* sc_hi  = (u16*)(bigc + BIGOFF_SC_HI);
    u16* sc_lo  = (u16*)(bigc + BIGOFF_SC_LO);
    float* invn = (float*)(bigc + BIGOFF_INVN);
    float* x2   = (float*)d_out;

    wconv_kernel<<<2592, 256, 0, stream>>>(
        w_qkv, w_out, w_mlp1, w_mlp2, ada1_v, ada2_v, gate1_v, gate2_v,
        w_hi, w_lo, mv_hi, mv_lo);

    modprep_kernel<<<608, 256, 0, stream>>>(
        cond, ada1_v, ada1_g, ada2_v, ada2_g, gate1_v, gate1_g, gate2_v, gate2_g,
        invn, sc_hi, sc_lo);

    modgemm_mfma<<<36, 256, 0, stream>>>(sc_hi, sc_lo, mv_hi, mv_lo, invn, mod);

    adaln_kernel<<<NPIX / 4, 256, 0, stream>>>(x, ln1_g, ln1_b, mod, h_hi, h_lo);

    gemm_mfma<0, 1><<<648, 256, 0, stream>>>(
        h_hi, h_lo, w_hi + WOFF_QKV, w_lo + WOFF_QKV, b_qkv,
        big, nullptr, nullptr, C3, D);

    natten_kernel<<<(NPIX * 6) / 4, 256, 0, stream>>>(big, a_hi, a_lo);

    gemm_mfma<2, 4><<<864, 256, 0, stream>>>(
        a_hi, a_lo, w_hi + WOFF_OUT, w_lo + WOFF_OUT, nullptr,
        big, nullptr, nullptr, D, D);

    reduce_gate<<<1728, 256, 0, stream>>>(big, b_out, mod + 1536, x, x2);

    adaln_kernel<<<NPIX / 4, 256, 0, stream>>>(x2, ln2_g, ln2_b, mod + 768, h_hi, h_lo);

    gemm_mfma<1, 1><<<864, 256, 0, stream>>>(
        h_hi, h_lo, w_hi + WOFF_M1, w_lo + WOFF_M1, b_mlp1,
        nullptr, m_hi, m_lo, DMLP, D);

    gemm_mfma<2, 4><<<864, 256, 0, stream>>>(
        m_hi, m_lo, w_hi + WOFF_M2, w_lo + WOFF_M2, nullptr,
        big, nullptr, nullptr, D, DMLP);

    reduce_gate<<<1728, 256, 0, stream>>>(big, b_mlp2, mod + 1920, x2, x2);
}

// Round 10
// 325.676 us; speedup vs baseline: 1.6690x; 1.0175x over previous
//
#include <hip/hip_runtime.h>
#include <hip/hip_bf16.h>
#include <math.h>

// Shapes fixed: B=2, H=W=48, D=384, CD=384, NH=6, hd=64, KS=7
#define NPIX 4608
#define D 384
#define CD 384
#define C3 1152
#define DMLP 1536
#define NCELL 72

typedef unsigned short u16;
typedef __attribute__((ext_vector_type(8))) short bf16x8;
typedef __attribute__((ext_vector_type(4))) float f32x4;

// ---------------- workspace layout (bytes) ----------------
#define OFF_MOD   0
#define OFF_BIG   663552
#define OFF_HHI   28975104
#define OFF_HLO   32514048
#define OFF_AHI   36052992
#define OFF_ALO   39591936
#define OFF_MHI   43130880
#define OFF_MLO   57286656
#define OFF_WHI   71442432
#define OFF_WLO   74981376
// early-phase temporaries inside BIG (dead before qkv GEMM writes big):
#define BIGOFF_MODV_HI  0
#define BIGOFF_MODV_LO  1769472
#define BIGOFF_SC_HI    3538944
#define BIGOFF_SC_LO    3637248
#define BIGOFF_INVN     3735552
// mod row-major [72][2304]: a1[0,384) b1[384,768) a2[768,1152) b2[1152,1536)
// gate1[1536,1920) gate2[1920,2304)
#define WOFF_QKV  0
#define WOFF_OUT  442368
#define WOFF_M1   589824
#define WOFF_M2   1179648

#define GLOAD16(g, l) __builtin_amdgcn_global_load_lds( \
    (const __attribute__((address_space(1))) unsigned int*)(g), \
    (__attribute__((address_space(3))) unsigned int*)(l), 16, 0, 0)

__device__ __forceinline__ float wsum(float v) {
    #pragma unroll
    for (int o = 32; o > 0; o >>= 1) v += __shfl_xor(v, o);
    return v;
}
__device__ __forceinline__ void split_bf16(float x, u16& h, u16& l) {
    __hip_bfloat16 bh = __float2bfloat16(x);
    float fh = __bfloat162float(bh);
    __hip_bfloat16 bl = __float2bfloat16(x - fh);
    h = *(u16*)&bh; l = *(u16*)&bl;
}

// ---------------------------------------------------------------------------
// Weight conversion: fp32 -> bf16 hi/lo (4 main weights + 4 modulation V)
// ---------------------------------------------------------------------------
__global__ __launch_bounds__(256) void wconv_kernel(
    const float* __restrict__ wq, const float* __restrict__ wo,
    const float* __restrict__ w1, const float* __restrict__ w2,
    const float* __restrict__ a1v, const float* __restrict__ a2v,
    const float* __restrict__ g1v, const float* __restrict__ g2v,
    u16* __restrict__ whi, u16* __restrict__ wlo,
    u16* __restrict__ mvhi, u16* __restrict__ mvlo)
{
    int i4 = blockIdx.x * 256 + threadIdx.x;   // 663552 float4s total
    const float* src; int l4; u16 *dh, *dl; int o;
    if (i4 < 442368) {
        if (i4 < 110592)        { src = wq; l4 = i4; }
        else if (i4 < 147456)   { src = wo; l4 = i4 - 110592; }
        else if (i4 < 294912)   { src = w1; l4 = i4 - 147456; }
        else                    { src = w2; l4 = i4 - 294912; }
        dh = whi; dl = wlo; o = i4 * 4;
    } else {
        int j4 = i4 - 442368;
        if (j4 < 73728)         { src = a1v; l4 = j4; }
        else if (j4 < 147456)   { src = a2v; l4 = j4 - 73728; }
        else if (j4 < 184320)   { src = g1v; l4 = j4 - 147456; }
        else                    { src = g2v; l4 = j4 - 184320; }
        dh = mvhi; dl = mvlo; o = j4 * 4;
    }
    float4 v = ((const float4*)src)[l4];
    split_bf16(v.x, dh[o+0], dl[o+0]);
    split_bf16(v.y, dh[o+1], dl[o+1]);
    split_bf16(v.z, dh[o+2], dl[o+2]);
    split_bf16(v.w, dh[o+3], dl[o+3]);
}

// ---------------------------------------------------------------------------
// modprep: wid<2304 -> inv_norm[row] = g/||v_row||; else silu(cond) -> sc
// ---------------------------------------------------------------------------
__global__ __launch_bounds__(256) void modprep_kernel(
    const float* __restrict__ cond,
    const float* __restrict__ a1v, const float* __restrict__ a1g,
    const float* __restrict__ a2v, const float* __restrict__ a2g,
    const float* __restrict__ g1v, const float* __restrict__ g1g,
    const float* __restrict__ g2v, const float* __restrict__ g2g,
    float* __restrict__ invn, u16* __restrict__ schi, u16* __restrict__ sclo)
{
    int wid  = (blockIdx.x * blockDim.x + threadIdx.x) >> 6;
    int lane = threadIdx.x & 63;
    if (wid < 2304) {
        const float* V; float g; int r;
        if (wid < 768)        { r = wid;        V = a1v; g = a1g[r]; }
        else if (wid < 1536)  { r = wid - 768;  V = a2v; g = a2g[r]; }
        else if (wid < 1920)  { r = wid - 1536; V = g1v; g = g1g[r]; }
        else                  { r = wid - 1920; V = g2v; g = g2g[r]; }
        const float* vrow = V + r * CD;
        float nrm = 0.f;
        #pragma unroll
        for (int j = 0; j < 6; j++) {
            float v = vrow[lane + 64 * j];
            nrm += v * v;
        }
        nrm = wsum(nrm);
        if (lane == 0) invn[wid] = g / sqrtf(nrm);
    } else {
        int cell = wid - 2304;
        #pragma unroll
        for (int j = 0; j < 6; j++) {
            int k = lane + 64 * j;
            float val = 0.f;
            if (cell < NCELL) {
                float c = cond[cell * CD + k];
                val = c / (1.f + __expf(-c));
            }
            split_bf16(val, schi[cell * CD + k], sclo[cell * CD + k]);
        }
    }
}

// ---------------------------------------------------------------------------
// mod GEMM: mod[72,2304] = sc[128,384] @ modV[2304,384]^T, x inv_norm[col]
// ---------------------------------------------------------------------------
__global__ __launch_bounds__(256) void modgemm_mfma(
    const u16* __restrict__ Ah, const u16* __restrict__ Al,
    const u16* __restrict__ Bh, const u16* __restrict__ Bl,
    const float* __restrict__ invn, float* __restrict__ mod)
{
    __shared__ u16 lds[24576];
    const int tid  = threadIdx.x;
    const int lane = tid & 63;
    const int wid  = tid >> 6;
    const int n0 = blockIdx.x * 64;
    const int K = 384, nt = 12;
    const int wr = wid >> 1, wc = wid & 1;

    const u16* gsrc[6];
    int loff[6];
    #pragma unroll
    for (int s = 0; s < 6; s++) {
        int c = tid + (s << 8);
        const u16* base; int ks, row;
        if (c < 512)        { ks = c >> 7;           row = c & 127; base = Ah + (size_t)row * K; }
        else if (c < 1024)  { int cc = c - 512;  ks = cc >> 7; row = cc & 127; base = Al + (size_t)row * K; }
        else if (c < 1280)  { int cc = c - 1024; ks = cc >> 6; row = cc & 63;  base = Bh + (size_t)(n0 + row) * K; }
        else                { int cc = c - 1280; ks = cc >> 6; row = cc & 63;  base = Bl + (size_t)(n0 + row) * K; }
        gsrc[s] = base + ks * 8;
        loff[s] = c * 8;
    }

    f32x4 acc[4][2] = {};
    const int ks = lane >> 4;
    const int fr = lane & 15;

    #pragma unroll
    for (int s = 0; s < 6; s++) GLOAD16(gsrc[s], &lds[loff[s]]);
    __syncthreads();

    int cur = 0;
    for (int kt = 0; kt < nt; kt++) {
        if (kt + 1 < nt) {
            int k0 = (kt + 1) << 5;
            int dbo = (cur ^ 1) * 12288;
            #pragma unroll
            for (int s = 0; s < 6; s++) GLOAD16(gsrc[s] + k0, &lds[dbo + loff[s]]);
        }
        const int b0 = cur * 12288;
        bf16x8 ah[4], al[4], bh[2], bl[2];
        #pragma unroll
        for (int m = 0; m < 4; m++) {
            int ai = b0 + (ks * 128 + wr * 64 + m * 16 + fr) * 8;
            ah[m] = *(const bf16x8*)&lds[ai];
            al[m] = *(const bf16x8*)&lds[4096 + ai];
        }
        #pragma unroll
        for (int n = 0; n < 2; n++) {
            int bi = b0 + (ks * 64 + wc * 32 + n * 16 + fr) * 8;
            bh[n] = *(const bf16x8*)&lds[8192 + bi];
            bl[n] = *(const bf16x8*)&lds[10240 + bi];
        }
        #pragma unroll
        for (int m = 0; m < 4; m++)
            #pragma unroll
            for (int n = 0; n < 2; n++) {
                acc[m][n] = __builtin_amdgcn_mfma_f32_16x16x32_bf16(ah[m], bh[n], acc[m][n], 0, 0, 0);
                acc[m][n] = __builtin_amdgcn_mfma_f32_16x16x32_bf16(ah[m], bl[n], acc[m][n], 0, 0, 0);
                acc[m][n] = __builtin_amdgcn_mfma_f32_16x16x32_bf16(al[m], bh[n], acc[m][n], 0, 0, 0);
            }
        __syncthreads();
        cur ^= 1;
    }

    const int r4 = ks * 4;
    #pragma unroll
    for (int m = 0; m < 4; m++) {
        #pragma unroll
        for (int n = 0; n < 2; n++) {
            #pragma unroll
            for (int j = 0; j < 4; j++) {
                int row = wr * 64 + m * 16 + r4 + j;
                int col = n0 + wc * 32 + n * 16 + fr;
                if (row < NCELL)
                    mod[(size_t)row * 2304 + col] = acc[m][n][j] * invn[col];
            }
        }
    }
}

// ---------------------------------------------------------------------------
// AdaLN: LayerNorm + per-cell (1+a)*xn + b; mod row-major [72][2304]
// ---------------------------------------------------------------------------
__global__ __launch_bounds__(256) void adaln_kernel(
    const float* __restrict__ x,
    const float* __restrict__ gamma, const float* __restrict__ beta,
    const float* __restrict__ mod_ab,
    u16* __restrict__ ohi, u16* __restrict__ olo)
{
    int p    = (blockIdx.x * blockDim.x + threadIdx.x) >> 6;
    int lane = threadIdx.x & 63;
    int b  = p / 2304;
    int hh = (p / 48) % 48;
    int ww = p % 48;
    int cell = b * 36 + (hh >> 3) * 6 + (ww >> 3);

    const float* xr = x + (size_t)p * D;
    float v[6]; float s = 0.f, ss = 0.f;
    #pragma unroll
    for (int j = 0; j < 6; j++) {
        v[j] = xr[lane + 64 * j];
        s  += v[j];
        ss += v[j] * v[j];
    }
    s = wsum(s); ss = wsum(ss);
    float mu  = s * (1.f / 384.f);
    float var = ss * (1.f / 384.f) - mu * mu;
    float rs  = 1.f / sqrtf(var + 1e-6f);

    const float* ab = mod_ab + (size_t)cell * 2304;
    #pragma unroll
    for (int j = 0; j < 6; j++) {
        int d = lane + 64 * j;
        float xn = (v[j] - mu) * rs * gamma[d] + beta[d];
        float o  = xn * (1.f + ab[d]) + ab[384 + d];
        split_bf16(o, ohi[(size_t)p * D + d], olo[(size_t)p * D + d]);
    }
}

// ---------------------------------------------------------------------------
// Fused: split-K reduce + bias + gate + residual -> x2, THEN adaln2 -> h hi/lo
// One wave per pixel.
// ---------------------------------------------------------------------------
__global__ __launch_bounds__(256) void rg_adaln_kernel(
    const float* __restrict__ part, const float* __restrict__ bias,
    const float* __restrict__ gate, const float* __restrict__ resid,
    float* __restrict__ x2out,
    const float* __restrict__ gamma, const float* __restrict__ beta,
    const float* __restrict__ mod_ab,
    u16* __restrict__ ohi, u16* __restrict__ olo)
{
    int p    = (blockIdx.x * blockDim.x + threadIdx.x) >> 6;
    int lane = threadIdx.x & 63;
    int b  = p / 2304;
    int hh = (p / 48) % 48;
    int ww = p % 48;
    int cell = b * 36 + (hh >> 3) * 6 + (ww >> 3);
    const float* gg = gate + (size_t)cell * 2304;
    const float* ab = mod_ab + (size_t)cell * 2304;

    float v[6]; float s = 0.f, ss = 0.f;
    #pragma unroll
    for (int j = 0; j < 6; j++) {
        int d = lane + 64 * j;
        size_t idx = (size_t)p * D + d;
        float pv = part[idx] + part[idx + 1769472] + part[idx + 2 * 1769472]
                 + part[idx + 3 * 1769472];
        float val = resid[idx] + (pv + bias[d]) * gg[d];
        x2out[idx] = val;
        v[j] = val; s += val; ss += val * val;
    }
    s = wsum(s); ss = wsum(ss);
    float mu  = s * (1.f / 384.f);
    float var = ss * (1.f / 384.f) - mu * mu;
    float rs  = 1.f / sqrtf(var + 1e-6f);
    #pragma unroll
    for (int j = 0; j < 6; j++) {
        int d = lane + 64 * j;
        float xn = (v[j] - mu) * rs * gamma[d] + beta[d];
        float o  = xn * (1.f + ab[d]) + ab[384 + d];
        split_bf16(o, ohi[(size_t)p * D + d], olo[(size_t)p * D + d]);
    }
}

// ---------------------------------------------------------------------------
// MFMA GEMM, split-bf16 3-term: C[4608,N] = A @ B^T
// BM=128, BN=64, BK=32, 4 waves, double-buffered, XCD swizzle.
// ---------------------------------------------------------------------------
template <int EPI, int NS>
__global__ __launch_bounds__(256) void gemm_mfma(
    const u16* __restrict__ Ah, const u16* __restrict__ Al,
    const u16* __restrict__ Bh, const u16* __restrict__ Bl,
    const float* __restrict__ bias,
    float* __restrict__ Cf, u16* __restrict__ Ch, u16* __restrict__ Cl,
    int N, int K)
{
    __shared__ u16 lds[24576];
    const int tid  = threadIdx.x;
    const int lane = tid & 63;
    const int wid  = tid >> 6;

    const int nwg = gridDim.x;
    const int q = nwg >> 3, r = nwg & 7;
    const int xcd = blockIdx.x & 7, loc = blockIdx.x >> 3;
    const int wgid = (xcd < r ? xcd * (q + 1) : r * (q + 1) + (xcd - r) * q) + loc;

    const int nx = N >> 6;
    const int per = nx * 36;
    const int bz  = wgid / per;
    const int id2 = wgid - bz * per;
    const int by  = id2 / nx;
    const int bx  = id2 - by * nx;

    const int m0 = by * 128;
    const int n0 = bx * 64;
    const int kPer = K / NS;
    const int kbeg = bz * kPer;
    const int nt = kPer >> 5;

    const int wr = wid >> 1, wc = wid & 1;

    const u16* gsrc[6];
    int loff[6];
    #pragma unroll
    for (int s = 0; s < 6; s++) {
        int c = tid + (s << 8);
        const u16* base; int ks, row;
        if (c < 512)        { ks = c >> 7;           row = c & 127; base = Ah + (size_t)(m0 + row) * K; }
        else if (c < 1024)  { int cc = c - 512;  ks = cc >> 7; row = cc & 127; base = Al + (size_t)(m0 + row) * K; }
        else if (c < 1280)  { int cc = c - 1024; ks = cc >> 6; row = cc & 63;  base = Bh + (size_t)(n0 + row) * K; }
        else                { int cc = c - 1280; ks = cc >> 6; row = cc & 63;  base = Bl + (size_t)(n0 + row) * K; }
        gsrc[s] = base + ks * 8;
        loff[s] = c * 8;
    }

    f32x4 acc[4][2] = {};
    const int ks = lane >> 4;
    const int fr = lane & 15;

    #pragma unroll
    for (int s = 0; s < 6; s++) GLOAD16(gsrc[s] + kbeg, &lds[loff[s]]);
    __syncthreads();

    int cur = 0;
    for (int kt = 0; kt < nt; kt++) {
        if (kt + 1 < nt) {
            int k0 = kbeg + ((kt + 1) << 5);
            int dbo = (cur ^ 1) * 12288;
            #pragma unroll
            for (int s = 0; s < 6; s++) GLOAD16(gsrc[s] + k0, &lds[dbo + loff[s]]);
        }
        const int b0 = cur * 12288;
        bf16x8 ah[4], al[4], bh[2], bl[2];
        #pragma unroll
        for (int m = 0; m < 4; m++) {
            int ai = b0 + (ks * 128 + wr * 64 + m * 16 + fr) * 8;
            ah[m] = *(const bf16x8*)&lds[ai];
            al[m] = *(const bf16x8*)&lds[4096 + ai];
        }
        #pragma unroll
        for (int n = 0; n < 2; n++) {
            int bi = b0 + (ks * 64 + wc * 32 + n * 16 + fr) * 8;
            bh[n] = *(const bf16x8*)&lds[8192 + bi];
            bl[n] = *(const bf16x8*)&lds[10240 + bi];
        }
        #pragma unroll
        for (int m = 0; m < 4; m++)
            #pragma unroll
            for (int n = 0; n < 2; n++) {
                acc[m][n] = __builtin_amdgcn_mfma_f32_16x16x32_bf16(ah[m], bh[n], acc[m][n], 0, 0, 0);
                acc[m][n] = __builtin_amdgcn_mfma_f32_16x16x32_bf16(ah[m], bl[n], acc[m][n], 0, 0, 0);
                acc[m][n] = __builtin_amdgcn_mfma_f32_16x16x32_bf16(al[m], bh[n], acc[m][n], 0, 0, 0);
            }
        __syncthreads();
        cur ^= 1;
    }

    const int r4 = ks * 4;
    #pragma unroll
    for (int m = 0; m < 4; m++) {
        #pragma unroll
        for (int n = 0; n < 2; n++) {
            #pragma unroll
            for (int j = 0; j < 4; j++) {
                int row = m0 + wr * 64 + m * 16 + r4 + j;
                int col = n0 + wc * 32 + n * 16 + fr;
                float v = acc[m][n][j];
                if (EPI == 0) {
                    Cf[(size_t)row * N + col] = v + bias[col];
                } else if (EPI == 1) {
                    float t = v + bias[col];
                    float c = 0.7978845608028654f * (t + 0.044715f * t * t * t);
                    float e = __expf(2.f * c);
                    float th = (e - 1.f) / (e + 1.f);
                    float g = 0.5f * t * (1.f + th);
                    size_t idx = (size_t)row * N + col;
                    split_bf16(g, Ch[idx], Cl[idx]);
                } else {
                    Cf[((size_t)bz * NPIX + row) * N + col] = v;
                }
            }
        }
    }
}

// ---------------------------------------------------------------------------
// Split-K reduce + bias + gate + residual (N=384, 4 partials) — final step
// ---------------------------------------------------------------------------
__global__ __launch_bounds__(256) void reduce_gate(
    const float* __restrict__ part, const float* __restrict__ bias,
    const float* __restrict__ gate, const float* __restrict__ resid,
    float* __restrict__ out)
{
    int i4 = blockIdx.x * 256 + threadIdx.x;
    int row = i4 / 96, c4 = i4 % 96;
    int b  = row / 2304;
    int hh = (row / 48) % 48;
    int ww = row % 48;
    int cell = b * 36 + (hh >> 3) * 6 + (ww >> 3);

    const float4* P = (const float4*)part;
    float4 p0 = P[i4], p1 = P[i4 + 442368], p2 = P[i4 + 2 * 442368], p3 = P[i4 + 3 * 442368];
    float4 bb = ((const float4*)bias)[c4];
    float4 gg = ((const float4*)(gate + (size_t)cell * 2304))[c4];
    float4 rr = ((const float4*)resid)[i4];
    float4 o;
    o.x = rr.x + (p0.x + p1.x + p2.x + p3.x + bb.x) * gg.x;
    o.y = rr.y + (p0.y + p1.y + p2.y + p3.y + bb.y) * gg.y;
    o.z = rr.z + (p0.z + p1.z + p2.z + p3.z + bb.z) * gg.z;
    o.w = rr.w + (p0.w + p1.w + p2.w + p3.w + bb.w) * gg.w;
    ((float4*)out)[i4] = o;
}

// ---------------------------------------------------------------------------
// 7x7 neighborhood attention, one wave per (pixel,head), 8x8 lane decomp.
// Bijective XCD swizzle: each XCD covers a contiguous ~12-row pixel band so
// the 49x K/V reuse hits that XCD's L2 (band+halo ~2.7MB < 4MB).
// ---------------------------------------------------------------------------
__global__ __launch_bounds__(256) void natten_kernel(
    const float* __restrict__ qkv, u16* __restrict__ ohi, u16* __restrict__ olo)
{
    // XCD swizzle (m204 bijective)
    const int nwg = gridDim.x;
    const int q8 = nwg >> 3, r8 = nwg & 7;
    const int xcd = blockIdx.x & 7, loc = blockIdx.x >> 3;
    const int bswz = (xcd < r8 ? xcd * (q8 + 1) : r8 * (q8 + 1) + (xcd - r8) * q8) + loc;

    int wid  = bswz * 4 + (threadIdx.x >> 6);
    int lane = threadIdx.x & 63;
    int head = wid % 6;
    int p    = wid / 6;
    int b  = p / 2304;
    int hh = (p / 48) % 48;
    int ww = p % 48;
    int sh = hh - 3; sh = sh < 0 ? 0 : (sh > 41 ? 41 : sh);
    int sw = ww - 3; sw = sw < 0 ? 0 : (sw > 41 ? 41 : sw);
    int pb = b * 2304;

    const int n_sub = lane >> 3;
    const int d_sub = lane & 7;
    const int dof = head * 64 + d_sub * 8;

    int npo[7];
    #pragma unroll
    for (int t = 0; t < 7; t++) {
        int n = t * 8 + n_sub;
        int nn = n > 48 ? 48 : n;
        int nr = nn / 7, nc = nn - nr * 7;
        npo[t] = pb + (sh + nr) * 48 + (sw + nc);
    }

    const float* qp = qkv + (size_t)p * C3 + dof;
    float4 q0 = *(const float4*)qp;
    float4 q1 = *(const float4*)(qp + 4);
    q0.x *= 0.125f; q0.y *= 0.125f; q0.z *= 0.125f; q0.w *= 0.125f;
    q1.x *= 0.125f; q1.y *= 0.125f; q1.z *= 0.125f; q1.w *= 0.125f;

    float4 kk0[7], kk1[7];
    #pragma unroll
    for (int t = 0; t < 7; t++) {
        const float* kp = qkv + (size_t)npo[t] * C3 + 384 + dof;
        kk0[t] = *(const float4*)kp;
        kk1[t] = *(const float4*)(kp + 4);
    }
    __builtin_amdgcn_sched_barrier(0);

    float L[7];
    #pragma unroll
    for (int t = 0; t < 7; t++) {
        float d = q0.x * kk0[t].x + q0.y * kk0[t].y + q0.z * kk0[t].z + q0.w * kk0[t].w
                + q1.x * kk1[t].x + q1.y * kk1[t].y + q1.z * kk1[t].z + q1.w * kk1[t].w;
        d += __shfl_xor(d, 1);
        d += __shfl_xor(d, 2);
        d += __shfl_xor(d, 4);
        L[t] = (t * 8 + n_sub < 49) ? d : -INFINITY;
    }

    float4 vv0[7], vv1[7];
    #pragma unroll
    for (int t = 0; t < 7; t++) {
        const float* vp = qkv + (size_t)npo[t] * C3 + 768 + dof;
        vv0[t] = *(const float4*)vp;
        vv1[t] = *(const float4*)(vp + 4);
    }
    __builtin_amdgcn_sched_barrier(0);

    float m = L[0];
    #pragma unroll
    for (int t = 1; t < 7; t++) m = fmaxf(m, L[t]);
    m = fmaxf(m, __shfl_xor(m, 8));
    m = fmaxf(m, __shfl_xor(m, 16));
    m = fmaxf(m, __shfl_xor(m, 32));

    float w[7]; float s = 0.f;
    #pragma unroll
    for (int t = 0; t < 7; t++) {
        w[t] = (L[t] == -INFINITY) ? 0.f : __expf(L[t] - m);
        s += w[t];
    }
    s += __shfl_xor(s, 8);
    s += __shfl_xor(s, 16);
    s += __shfl_xor(s, 32);
    float inv = 1.f / s;
    #pragma unroll
    for (int t = 0; t < 7; t++) w[t] *= inv;

    float a0x = 0.f, a0y = 0.f, a0z = 0.f, a0w = 0.f;
    float a1x = 0.f, a1y = 0.f, a1z = 0.f, a1w = 0.f;
    #pragma unroll
    for (int t = 0; t < 7; t++) {
        float wn = w[t];
        a0x = fmaf(wn, vv0[t].x, a0x); a0y = fmaf(wn, vv0[t].y, a0y);
        a0z = fmaf(wn, vv0[t].z, a0z); a0w = fmaf(wn, vv0[t].w, a0w);
        a1x = fmaf(wn, vv1[t].x, a1x); a1y = fmaf(wn, vv1[t].y, a1y);
        a1z = fmaf(wn, vv1[t].z, a1z); a1w = fmaf(wn, vv1[t].w, a1w);
    }
    #pragma unroll
    for (int o = 8; o <= 32; o <<= 1) {
        a0x += __shfl_xor(a0x, o); a0y += __shfl_xor(a0y, o);
        a0z += __shfl_xor(a0z, o); a0w += __shfl_xor(a0w, o);
        a1x += __shfl_xor(a1x, o); a1y += __shfl_xor(a1y, o);
        a1z += __shfl_xor(a1z, o); a1w += __shfl_xor(a1w, o);
    }

    if (lane < 8) {
        float av[8] = {a0x, a0y, a0z, a0w, a1x, a1y, a1z, a1w};
        u16 hi8[8], lo8[8];
        #pragma unroll
        for (int i = 0; i < 8; i++) split_bf16(av[i], hi8[i], lo8[i]);
        size_t oi = (size_t)p * D + head * 64 + lane * 8;
        *(uint4*)(ohi + oi) = *(uint4*)hi8;
        *(uint4*)(olo + oi) = *(uint4*)lo8;
    }
}

// ---------------------------------------------------------------------------
extern "C" void kernel_launch(void* const* d_in, const int* in_sizes, int n_in,
                              void* d_out, int out_size, void* d_ws, size_t ws_size,
                              hipStream_t stream)
{
    (void)in_sizes; (void)n_in; (void)out_size; (void)ws_size;
    const float* x      = (const float*)d_in[0];
    const float* cond   = (const float*)d_in[1];
    const float* ln1_g  = (const float*)d_in[2];
    const float* ln1_b  = (const float*)d_in[3];
    const float* ada1_v = (const float*)d_in[4];
    const float* ada1_g = (const float*)d_in[5];
    const float* ln2_g  = (const float*)d_in[6];
    const float* ln2_b  = (const float*)d_in[7];
    const float* ada2_v = (const float*)d_in[8];
    const float* ada2_g = (const float*)d_in[9];
    const float* gate1_v = (const float*)d_in[10];
    const float* gate1_g = (const float*)d_in[11];
    const float* gate2_v = (const float*)d_in[12];
    const float* gate2_g = (const float*)d_in[13];
    const float* w_qkv  = (const float*)d_in[14];
    const float* b_qkv  = (const float*)d_in[15];
    const float* w_out  = (const float*)d_in[16];
    const float* b_out  = (const float*)d_in[17];
    const float* w_mlp1 = (const float*)d_in[18];
    const float* b_mlp1 = (const float*)d_in[19];
    const float* w_mlp2 = (const float*)d_in[20];
    const float* b_mlp2 = (const float*)d_in[21];

    char* ws = (char*)d_ws;
    float* mod  = (float*)(ws + OFF_MOD);
    float* big  = (float*)(ws + OFF_BIG);
    u16* h_hi   = (u16*)(ws + OFF_HHI);
    u16* h_lo   = (u16*)(ws + OFF_HLO);
    u16* a_hi   = (u16*)(ws + OFF_AHI);
    u16* a_lo   = (u16*)(ws + OFF_ALO);
    u16* m_hi   = (u16*)(ws + OFF_MHI);
    u16* m_lo   = (u16*)(ws + OFF_MLO);
    u16* w_hi   = (u16*)(ws + OFF_WHI);
    u16* w_lo   = (u16*)(ws + OFF_WLO);
    char* bigc  = ws + OFF_BIG;
    u16* mv_hi  = (u16*)(bigc + BIGOFF_MODV_HI);
    u16* mv_lo  = (u16*)(bigc + BIGOFF_MODV_LO);
    u16* sc_hi  = (u16*)(bigc + BIGOFF_SC_HI);
    u16* sc_lo  = (u16*)(bigc + BIGOFF_SC_LO);
    float* invn = (float*)(bigc + BIGOFF_INVN);
    float* x2   = (float*)d_out;

    wconv_kernel<<<2592, 256, 0, stream>>>(
        w_qkv, w_out, w_mlp1, w_mlp2, ada1_v, ada2_v, gate1_v, gate2_v,
        w_hi, w_lo, mv_hi, mv_lo);

    modprep_kernel<<<608, 256, 0, stream>>>(
        cond, ada1_v, ada1_g, ada2_v, ada2_g, gate1_v, gate1_g, gate2_v, gate2_g,
        invn, sc_hi, sc_lo);

    modgemm_mfma<<<36, 256, 0, stream>>>(sc_hi, sc_lo, mv_hi, mv_lo, invn, mod);

    adaln_kernel<<<NPIX / 4, 256, 0, stream>>>(x, ln1_g, ln1_b, mod, h_hi, h_lo);

    gemm_mfma<0, 1><<<648, 256, 0, stream>>>(
        h_hi, h_lo, w_hi + WOFF_QKV, w_lo + WOFF_QKV, b_qkv,
        big, nullptr, nullptr, C3, D);

    natten_kernel<<<(NPIX * 6) / 4, 256, 0, stream>>>(big, a_hi, a_lo);

    gemm_mfma<2, 4><<<864, 256, 0, stream>>>(
        a_hi, a_lo, w_hi + WOFF_OUT, w_lo + WOFF_OUT, nullptr,
        big, nullptr, nullptr, D, D);

    // fused: x2 = x + (sum+b_out)*gate1, then h = adaln2(x2)
    rg_adaln_kernel<<<NPIX / 4, 256, 0, stream>>>(
        big, b_out, mod + 1536, x, x2, ln2_g, ln2_b, mod + 768, h_hi, h_lo);

    gemm_mfma<1, 1><<<864, 256, 0, stream>>>(
        h_hi, h_lo, w_hi + WOFF_M1, w_lo + WOFF_M1, b_mlp1,
        nullptr, m_hi, m_lo, DMLP, D);

    gemm_mfma<2, 4><<<864, 256, 0, stream>>>(
        m_hi, m_lo, w_hi + WOFF_M2, w_lo + WOFF_M2, nullptr,
        big, nullptr, nullptr, D, DMLP);

    reduce_gate<<<1728, 256, 0, stream>>>(big, b_mlp2, mod + 1920, x2, x2);
}

// Round 11
// 325.432 us; speedup vs baseline: 1.6703x; 1.0008x over previous
//
#include <hip/hip_runtime.h>
#include <hip/hip_bf16.h>
#include <math.h>

// Shapes fixed: B=2, H=W=48, D=384, CD=384, NH=6, hd=64, KS=7
#define NPIX 4608
#define D 384
#define CD 384
#define C3 1152
#define DMLP 1536
#define NCELL 72

typedef unsigned short u16;
typedef __attribute__((ext_vector_type(8))) short bf16x8;
typedef __attribute__((ext_vector_type(4))) float f32x4;

// ---------------- workspace layout (bytes) ----------------
#define OFF_MOD   0
#define OFF_BIG   663552
#define OFF_HHI   28975104
#define OFF_HLO   32514048
#define OFF_AHI   36052992
#define OFF_ALO   39591936
#define OFF_MHI   43130880
#define OFF_MLO   57286656
#define OFF_WHI   71442432
#define OFF_WLO   74981376
// early-phase temporaries inside BIG (dead before qkv GEMM writes big):
#define BIGOFF_MODV_HI  0
#define BIGOFF_MODV_LO  1769472
#define BIGOFF_SC_HI    3538944
#define BIGOFF_SC_LO    3637248
#define BIGOFF_INVN     3735552
// mod row-major [72][2304]: a1[0,384) b1[384,768) a2[768,1152) b2[1152,1536)
// gate1[1536,1920) gate2[1920,2304)
#define WOFF_QKV  0
#define WOFF_OUT  442368
#define WOFF_M1   589824
#define WOFF_M2   1179648

#define GLOAD16(g, l) __builtin_amdgcn_global_load_lds( \
    (const __attribute__((address_space(1))) unsigned int*)(g), \
    (__attribute__((address_space(3))) unsigned int*)(l), 16, 0, 0)

__device__ __forceinline__ float wsum(float v) {
    #pragma unroll
    for (int o = 32; o > 0; o >>= 1) v += __shfl_xor(v, o);
    return v;
}
__device__ __forceinline__ void split_bf16(float x, u16& h, u16& l) {
    __hip_bfloat16 bh = __float2bfloat16(x);
    float fh = __bfloat162float(bh);
    __hip_bfloat16 bl = __float2bfloat16(x - fh);
    h = *(u16*)&bh; l = *(u16*)&bl;
}

// ---------------------------------------------------------------------------
// Weight conversion: fp32 -> bf16 hi/lo (4 main weights + 4 modulation V)
// ---------------------------------------------------------------------------
__global__ __launch_bounds__(256) void wconv_kernel(
    const float* __restrict__ wq, const float* __restrict__ wo,
    const float* __restrict__ w1, const float* __restrict__ w2,
    const float* __restrict__ a1v, const float* __restrict__ a2v,
    const float* __restrict__ g1v, const float* __restrict__ g2v,
    u16* __restrict__ whi, u16* __restrict__ wlo,
    u16* __restrict__ mvhi, u16* __restrict__ mvlo)
{
    int i4 = blockIdx.x * 256 + threadIdx.x;   // 663552 float4s total
    const float* src; int l4; u16 *dh, *dl; int o;
    if (i4 < 442368) {
        if (i4 < 110592)        { src = wq; l4 = i4; }
        else if (i4 < 147456)   { src = wo; l4 = i4 - 110592; }
        else if (i4 < 294912)   { src = w1; l4 = i4 - 147456; }
        else                    { src = w2; l4 = i4 - 294912; }
        dh = whi; dl = wlo; o = i4 * 4;
    } else {
        int j4 = i4 - 442368;
        if (j4 < 73728)         { src = a1v; l4 = j4; }
        else if (j4 < 147456)   { src = a2v; l4 = j4 - 73728; }
        else if (j4 < 184320)   { src = g1v; l4 = j4 - 147456; }
        else                    { src = g2v; l4 = j4 - 184320; }
        dh = mvhi; dl = mvlo; o = j4 * 4;
    }
    float4 v = ((const float4*)src)[l4];
    split_bf16(v.x, dh[o+0], dl[o+0]);
    split_bf16(v.y, dh[o+1], dl[o+1]);
    split_bf16(v.z, dh[o+2], dl[o+2]);
    split_bf16(v.w, dh[o+3], dl[o+3]);
}

// ---------------------------------------------------------------------------
// modprep: wid<2304 -> inv_norm[row] = g/||v_row||; else silu(cond) -> sc
// ---------------------------------------------------------------------------
__global__ __launch_bounds__(256) void modprep_kernel(
    const float* __restrict__ cond,
    const float* __restrict__ a1v, const float* __restrict__ a1g,
    const float* __restrict__ a2v, const float* __restrict__ a2g,
    const float* __restrict__ g1v, const float* __restrict__ g1g,
    const float* __restrict__ g2v, const float* __restrict__ g2g,
    float* __restrict__ invn, u16* __restrict__ schi, u16* __restrict__ sclo)
{
    int wid  = (blockIdx.x * blockDim.x + threadIdx.x) >> 6;
    int lane = threadIdx.x & 63;
    if (wid < 2304) {
        const float* V; float g; int r;
        if (wid < 768)        { r = wid;        V = a1v; g = a1g[r]; }
        else if (wid < 1536)  { r = wid - 768;  V = a2v; g = a2g[r]; }
        else if (wid < 1920)  { r = wid - 1536; V = g1v; g = g1g[r]; }
        else                  { r = wid - 1920; V = g2v; g = g2g[r]; }
        const float* vrow = V + r * CD;
        float nrm = 0.f;
        #pragma unroll
        for (int j = 0; j < 6; j++) {
            float v = vrow[lane + 64 * j];
            nrm += v * v;
        }
        nrm = wsum(nrm);
        if (lane == 0) invn[wid] = g / sqrtf(nrm);
    } else {
        int cell = wid - 2304;
        #pragma unroll
        for (int j = 0; j < 6; j++) {
            int k = lane + 64 * j;
            float val = 0.f;
            if (cell < NCELL) {
                float c = cond[cell * CD + k];
                val = c / (1.f + __expf(-c));
            }
            split_bf16(val, schi[cell * CD + k], sclo[cell * CD + k]);
        }
    }
}

// ---------------------------------------------------------------------------
// mod GEMM: mod[72,2304] = sc[128,384] @ modV[2304,384]^T, x inv_norm[col]
// (unchanged BM=128 geometry; 36 blocks, tiny)
// ---------------------------------------------------------------------------
__global__ __launch_bounds__(256) void modgemm_mfma(
    const u16* __restrict__ Ah, const u16* __restrict__ Al,
    const u16* __restrict__ Bh, const u16* __restrict__ Bl,
    const float* __restrict__ invn, float* __restrict__ mod)
{
    __shared__ u16 lds[24576];
    const int tid  = threadIdx.x;
    const int lane = tid & 63;
    const int wid  = tid >> 6;
    const int n0 = blockIdx.x * 64;
    const int K = 384, nt = 12;
    const int wr = wid >> 1, wc = wid & 1;

    const u16* gsrc[6];
    int loff[6];
    #pragma unroll
    for (int s = 0; s < 6; s++) {
        int c = tid + (s << 8);
        const u16* base; int ks, row;
        if (c < 512)        { ks = c >> 7;           row = c & 127; base = Ah + (size_t)row * K; }
        else if (c < 1024)  { int cc = c - 512;  ks = cc >> 7; row = cc & 127; base = Al + (size_t)row * K; }
        else if (c < 1280)  { int cc = c - 1024; ks = cc >> 6; row = cc & 63;  base = Bh + (size_t)(n0 + row) * K; }
        else                { int cc = c - 1280; ks = cc >> 6; row = cc & 63;  base = Bl + (size_t)(n0 + row) * K; }
        gsrc[s] = base + ks * 8;
        loff[s] = c * 8;
    }

    f32x4 acc[4][2] = {};
    const int ks = lane >> 4;
    const int fr = lane & 15;

    #pragma unroll
    for (int s = 0; s < 6; s++) GLOAD16(gsrc[s], &lds[loff[s]]);
    __syncthreads();

    int cur = 0;
    for (int kt = 0; kt < nt; kt++) {
        if (kt + 1 < nt) {
            int k0 = (kt + 1) << 5;
            int dbo = (cur ^ 1) * 12288;
            #pragma unroll
            for (int s = 0; s < 6; s++) GLOAD16(gsrc[s] + k0, &lds[dbo + loff[s]]);
        }
        const int b0 = cur * 12288;
        bf16x8 ah[4], al[4], bh[2], bl[2];
        #pragma unroll
        for (int m = 0; m < 4; m++) {
            int ai = b0 + (ks * 128 + wr * 64 + m * 16 + fr) * 8;
            ah[m] = *(const bf16x8*)&lds[ai];
            al[m] = *(const bf16x8*)&lds[4096 + ai];
        }
        #pragma unroll
        for (int n = 0; n < 2; n++) {
            int bi = b0 + (ks * 64 + wc * 32 + n * 16 + fr) * 8;
            bh[n] = *(const bf16x8*)&lds[8192 + bi];
            bl[n] = *(const bf16x8*)&lds[10240 + bi];
        }
        #pragma unroll
        for (int m = 0; m < 4; m++)
            #pragma unroll
            for (int n = 0; n < 2; n++) {
                acc[m][n] = __builtin_amdgcn_mfma_f32_16x16x32_bf16(ah[m], bh[n], acc[m][n], 0, 0, 0);
                acc[m][n] = __builtin_amdgcn_mfma_f32_16x16x32_bf16(ah[m], bl[n], acc[m][n], 0, 0, 0);
                acc[m][n] = __builtin_amdgcn_mfma_f32_16x16x32_bf16(al[m], bh[n], acc[m][n], 0, 0, 0);
            }
        __syncthreads();
        cur ^= 1;
    }

    const int r4 = ks * 4;
    #pragma unroll
    for (int m = 0; m < 4; m++) {
        #pragma unroll
        for (int n = 0; n < 2; n++) {
            #pragma unroll
            for (int j = 0; j < 4; j++) {
                int row = wr * 64 + m * 16 + r4 + j;
                int col = n0 + wc * 32 + n * 16 + fr;
                if (row < NCELL)
                    mod[(size_t)row * 2304 + col] = acc[m][n][j] * invn[col];
            }
        }
    }
}

// ---------------------------------------------------------------------------
// AdaLN: LayerNorm + per-cell (1+a)*xn + b; mod row-major [72][2304]
// ---------------------------------------------------------------------------
__global__ __launch_bounds__(256) void adaln_kernel(
    const float* __restrict__ x,
    const float* __restrict__ gamma, const float* __restrict__ beta,
    const float* __restrict__ mod_ab,
    u16* __restrict__ ohi, u16* __restrict__ olo)
{
    int p    = (blockIdx.x * blockDim.x + threadIdx.x) >> 6;
    int lane = threadIdx.x & 63;
    int b  = p / 2304;
    int hh = (p / 48) % 48;
    int ww = p % 48;
    int cell = b * 36 + (hh >> 3) * 6 + (ww >> 3);

    const float* xr = x + (size_t)p * D;
    float v[6]; float s = 0.f, ss = 0.f;
    #pragma unroll
    for (int j = 0; j < 6; j++) {
        v[j] = xr[lane + 64 * j];
        s  += v[j];
        ss += v[j] * v[j];
    }
    s = wsum(s); ss = wsum(ss);
    float mu  = s * (1.f / 384.f);
    float var = ss * (1.f / 384.f) - mu * mu;
    float rs  = 1.f / sqrtf(var + 1e-6f);

    const float* ab = mod_ab + (size_t)cell * 2304;
    #pragma unroll
    for (int j = 0; j < 6; j++) {
        int d = lane + 64 * j;
        float xn = (v[j] - mu) * rs * gamma[d] + beta[d];
        float o  = xn * (1.f + ab[d]) + ab[384 + d];
        split_bf16(o, ohi[(size_t)p * D + d], olo[(size_t)p * D + d]);
    }
}

// ---------------------------------------------------------------------------
// MFMA GEMM, split-bf16 3-term: C[4608,N] = A @ B^T
// BM=64, BN=64, BK=32, 4 waves (2x2, 32x32 each), double-buffered (32 KB),
// bijective XCD swizzle. No split-K.
// EPI 0: +bias -> f32
// EPI 1: +bias, gelu -> bf16 hi/lo
// EPI 3: resid + (acc+bias)*gate[cell] -> f32 (fused gate+residual)
// ---------------------------------------------------------------------------
template <int EPI>
__global__ __launch_bounds__(256) void gemm_mfma(
    const u16* __restrict__ Ah, const u16* __restrict__ Al,
    const u16* __restrict__ Bh, const u16* __restrict__ Bl,
    const float* __restrict__ bias,
    float* __restrict__ Cf, u16* __restrict__ Ch, u16* __restrict__ Cl,
    const float* __restrict__ gate, const float* __restrict__ resid,
    int N, int K)
{
    __shared__ u16 lds[16384];   // 2 x 8192 u16 = 32 KB
    const int tid  = threadIdx.x;
    const int lane = tid & 63;
    const int wid  = tid >> 6;

    // bijective XCD swizzle (m204); all grids divisible by 8
    const int nwg = gridDim.x;
    const int q = nwg >> 3, r = nwg & 7;
    const int xcd = blockIdx.x & 7, loc = blockIdx.x >> 3;
    const int wgid = (xcd < r ? xcd * (q + 1) : r * (q + 1) + (xcd - r) * q) + loc;

    const int nx = N >> 6;
    const int by = wgid / nx;
    const int bx = wgid - by * nx;
    const int m0 = by * 64;
    const int n0 = bx * 64;
    const int nt = K >> 5;

    const int wr = wid >> 1, wc = wid & 1;

    // staging: 4 chunks of 16B per thread; chunk c = tid + 256*s
    // regions (u16): Ahi[0,2048) Alo[2048,4096) Bhi[4096,6144) Blo[6144,8192)
    const u16* gsrc[4];
    int loff[4];
    #pragma unroll
    for (int s = 0; s < 4; s++) {
        int c = tid + (s << 8);
        int ks = (c & 255) >> 6;
        int row = c & 63;
        const u16* base;
        if (c < 256)       base = Ah + (size_t)(m0 + row) * K;
        else if (c < 512)  base = Al + (size_t)(m0 + row) * K;
        else if (c < 768)  base = Bh + (size_t)(n0 + row) * K;
        else               base = Bl + (size_t)(n0 + row) * K;
        gsrc[s] = base + ks * 8;
        loff[s] = c * 8;
    }

    f32x4 acc[2][2] = {};
    const int ks = lane >> 4;
    const int fr = lane & 15;

    #pragma unroll
    for (int s = 0; s < 4; s++) GLOAD16(gsrc[s], &lds[loff[s]]);
    __syncthreads();

    int cur = 0;
    for (int kt = 0; kt < nt; kt++) {
        if (kt + 1 < nt) {
            int k0 = (kt + 1) << 5;
            int dbo = (cur ^ 1) * 8192;
            #pragma unroll
            for (int s = 0; s < 4; s++) GLOAD16(gsrc[s] + k0, &lds[dbo + loff[s]]);
        }
        const int b0 = cur * 8192;
        bf16x8 ah[2], al[2], bh[2], bl[2];
        #pragma unroll
        for (int m = 0; m < 2; m++) {
            int ai = b0 + (ks * 64 + wr * 32 + m * 16 + fr) * 8;
            ah[m] = *(const bf16x8*)&lds[ai];
            al[m] = *(const bf16x8*)&lds[2048 + ai];
        }
        #pragma unroll
        for (int n = 0; n < 2; n++) {
            int bi = b0 + (ks * 64 + wc * 32 + n * 16 + fr) * 8;
            bh[n] = *(const bf16x8*)&lds[4096 + bi];
            bl[n] = *(const bf16x8*)&lds[6144 + bi];
        }
        #pragma unroll
        for (int m = 0; m < 2; m++)
            #pragma unroll
            for (int n = 0; n < 2; n++) {
                acc[m][n] = __builtin_amdgcn_mfma_f32_16x16x32_bf16(ah[m], bh[n], acc[m][n], 0, 0, 0);
                acc[m][n] = __builtin_amdgcn_mfma_f32_16x16x32_bf16(ah[m], bl[n], acc[m][n], 0, 0, 0);
                acc[m][n] = __builtin_amdgcn_mfma_f32_16x16x32_bf16(al[m], bh[n], acc[m][n], 0, 0, 0);
            }
        __syncthreads();
        cur ^= 1;
    }

    // epilogue: C/D layout col=lane&15, row=(lane>>4)*4+j (m89-verified)
    const int r4 = ks * 4;
    #pragma unroll
    for (int m = 0; m < 2; m++) {
        #pragma unroll
        for (int n = 0; n < 2; n++) {
            #pragma unroll
            for (int j = 0; j < 4; j++) {
                int row = m0 + wr * 32 + m * 16 + r4 + j;
                int col = n0 + wc * 32 + n * 16 + fr;
                float v = acc[m][n][j];
                if (EPI == 0) {
                    Cf[(size_t)row * N + col] = v + bias[col];
                } else if (EPI == 1) {
                    float t = v + bias[col];
                    float c = 0.7978845608028654f * (t + 0.044715f * t * t * t);
                    float e = __expf(2.f * c);
                    float th = (e - 1.f) / (e + 1.f);
                    float g = 0.5f * t * (1.f + th);
                    size_t idx = (size_t)row * N + col;
                    split_bf16(g, Ch[idx], Cl[idx]);
                } else {   // EPI == 3: fused gate + residual (N must be 384)
                    int b  = row / 2304;
                    int hh = (row / 48) % 48;
                    int ww = row % 48;
                    int cell = b * 36 + (hh >> 3) * 6 + (ww >> 3);
                    size_t idx = (size_t)row * N + col;
                    Cf[idx] = resid[idx] + (v + bias[col]) * gate[(size_t)cell * 2304 + col];
                }
            }
        }
    }
}

// ---------------------------------------------------------------------------
// 7x7 neighborhood attention, one wave per (pixel,head), 8x8 lane decomp.
// Bijective XCD swizzle: each XCD covers a contiguous ~12-row pixel band so
// the 49x K/V reuse hits that XCD's L2 (band+halo ~2.7MB < 4MB).
// ---------------------------------------------------------------------------
__global__ __launch_bounds__(256) void natten_kernel(
    const float* __restrict__ qkv, u16* __restrict__ ohi, u16* __restrict__ olo)
{
    const int nwg = gridDim.x;
    const int q8 = nwg >> 3, r8 = nwg & 7;
    const int xcd = blockIdx.x & 7, loc = blockIdx.x >> 3;
    const int bswz = (xcd < r8 ? xcd * (q8 + 1) : r8 * (q8 + 1) + (xcd - r8) * q8) + loc;

    int wid  = bswz * 4 + (threadIdx.x >> 6);
    int lane = threadIdx.x & 63;
    int head = wid % 6;
    int p    = wid / 6;
    int b  = p / 2304;
    int hh = (p / 48) % 48;
    int ww = p % 48;
    int sh = hh - 3; sh = sh < 0 ? 0 : (sh > 41 ? 41 : sh);
    int sw = ww - 3; sw = sw < 0 ? 0 : (sw > 41 ? 41 : sw);
    int pb = b * 2304;

    const int n_sub = lane >> 3;
    const int d_sub = lane & 7;
    const int dof = head * 64 + d_sub * 8;

    int npo[7];
    #pragma unroll
    for (int t = 0; t < 7; t++) {
        int n = t * 8 + n_sub;
        int nn = n > 48 ? 48 : n;
        int nr = nn / 7, nc = nn - nr * 7;
        npo[t] = pb + (sh + nr) * 48 + (sw + nc);
    }

    const float* qp = qkv + (size_t)p * C3 + dof;
    float4 q0 = *(const float4*)qp;
    float4 q1 = *(const float4*)(qp + 4);
    q0.x *= 0.125f; q0.y *= 0.125f; q0.z *= 0.125f; q0.w *= 0.125f;
    q1.x *= 0.125f; q1.y *= 0.125f; q1.z *= 0.125f; q1.w *= 0.125f;

    float4 kk0[7], kk1[7];
    #pragma unroll
    for (int t = 0; t < 7; t++) {
        const float* kp = qkv + (size_t)npo[t] * C3 + 384 + dof;
        kk0[t] = *(const float4*)kp;
        kk1[t] = *(const float4*)(kp + 4);
    }
    __builtin_amdgcn_sched_barrier(0);

    float L[7];
    #pragma unroll
    for (int t = 0; t < 7; t++) {
        float d = q0.x * kk0[t].x + q0.y * kk0[t].y + q0.z * kk0[t].z + q0.w * kk0[t].w
                + q1.x * kk1[t].x + q1.y * kk1[t].y + q1.z * kk1[t].z + q1.w * kk1[t].w;
        d += __shfl_xor(d, 1);
        d += __shfl_xor(d, 2);
        d += __shfl_xor(d, 4);
        L[t] = (t * 8 + n_sub < 49) ? d : -INFINITY;
    }

    float4 vv0[7], vv1[7];
    #pragma unroll
    for (int t = 0; t < 7; t++) {
        const float* vp = qkv + (size_t)npo[t] * C3 + 768 + dof;
        vv0[t] = *(const float4*)vp;
        vv1[t] = *(const float4*)(vp + 4);
    }
    __builtin_amdgcn_sched_barrier(0);

    float m = L[0];
    #pragma unroll
    for (int t = 1; t < 7; t++) m = fmaxf(m, L[t]);
    m = fmaxf(m, __shfl_xor(m, 8));
    m = fmaxf(m, __shfl_xor(m, 16));
    m = fmaxf(m, __shfl_xor(m, 32));

    float w[7]; float s = 0.f;
    #pragma unroll
    for (int t = 0; t < 7; t++) {
        w[t] = (L[t] == -INFINITY) ? 0.f : __expf(L[t] - m);
        s += w[t];
    }
    s += __shfl_xor(s, 8);
    s += __shfl_xor(s, 16);
    s += __shfl_xor(s, 32);
    float inv = 1.f / s;
    #pragma unroll
    for (int t = 0; t < 7; t++) w[t] *= inv;

    float a0x = 0.f, a0y = 0.f, a0z = 0.f, a0w = 0.f;
    float a1x = 0.f, a1y = 0.f, a1z = 0.f, a1w = 0.f;
    #pragma unroll
    for (int t = 0; t < 7; t++) {
        float wn = w[t];
        a0x = fmaf(wn, vv0[t].x, a0x); a0y = fmaf(wn, vv0[t].y, a0y);
        a0z = fmaf(wn, vv0[t].z, a0z); a0w = fmaf(wn, vv0[t].w, a0w);
        a1x = fmaf(wn, vv1[t].x, a1x); a1y = fmaf(wn, vv1[t].y, a1y);
        a1z = fmaf(wn, vv1[t].z, a1z); a1w = fmaf(wn, vv1[t].w, a1w);
    }
    #pragma unroll
    for (int o = 8; o <= 32; o <<= 1) {
        a0x += __shfl_xor(a0x, o); a0y += __shfl_xor(a0y, o);
        a0z += __shfl_xor(a0z, o); a0w += __shfl_xor(a0w, o);
        a1x += __shfl_xor(a1x, o); a1y += __shfl_xor(a1y, o);
        a1z += __shfl_xor(a1z, o); a1w += __shfl_xor(a1w, o);
    }

    if (lane < 8) {
        float av[8] = {a0x, a0y, a0z, a0w, a1x, a1y, a1z, a1w};
        u16 hi8[8], lo8[8];
        #pragma unroll
        for (int i = 0; i < 8; i++) split_bf16(av[i], hi8[i], lo8[i]);
        size_t oi = (size_t)p * D + head * 64 + lane * 8;
        *(uint4*)(ohi + oi) = *(uint4*)hi8;
        *(uint4*)(olo + oi) = *(uint4*)lo8;
    }
}

// ---------------------------------------------------------------------------
extern "C" void kernel_launch(void* const* d_in, const int* in_sizes, int n_in,
                              void* d_out, int out_size, void* d_ws, size_t ws_size,
                              hipStream_t stream)
{
    (void)in_sizes; (void)n_in; (void)out_size; (void)ws_size;
    const float* x      = (const float*)d_in[0];
    const float* cond   = (const float*)d_in[1];
    const float* ln1_g  = (const float*)d_in[2];
    const float* ln1_b  = (const float*)d_in[3];
    const float* ada1_v = (const float*)d_in[4];
    const float* ada1_g = (const float*)d_in[5];
    const float* ln2_g  = (const float*)d_in[6];
    const float* ln2_b  = (const float*)d_in[7];
    const float* ada2_v = (const float*)d_in[8];
    const float* ada2_g = (const float*)d_in[9];
    const float* gate1_v = (const float*)d_in[10];
    const float* gate1_g = (const float*)d_in[11];
    const float* gate2_v = (const float*)d_in[12];
    const float* gate2_g = (const float*)d_in[13];
    const float* w_qkv  = (const float*)d_in[14];
    const float* b_qkv  = (const float*)d_in[15];
    const float* w_out  = (const float*)d_in[16];
    const float* b_out  = (const float*)d_in[17];
    const float* w_mlp1 = (const float*)d_in[18];
    const float* b_mlp1 = (const float*)d_in[19];
    const float* w_mlp2 = (const float*)d_in[20];
    const float* b_mlp2 = (const float*)d_in[21];

    char* ws = (char*)d_ws;
    float* mod  = (float*)(ws + OFF_MOD);
    float* big  = (float*)(ws + OFF_BIG);
    u16* h_hi   = (u16*)(ws + OFF_HHI);
    u16* h_lo   = (u16*)(ws + OFF_HLO);
    u16* a_hi   = (u16*)(ws + OFF_AHI);
    u16* a_lo   = (u16*)(ws + OFF_ALO);
    u16* m_hi   = (u16*)(ws + OFF_MHI);
    u16* m_lo   = (u16*)(ws + OFF_MLO);
    u16* w_hi   = (u16*)(ws + OFF_WHI);
    u16* w_lo   = (u16*)(ws + OFF_WLO);
    char* bigc  = ws + OFF_BIG;
    u16* mv_hi  = (u16*)(bigc + BIGOFF_MODV_HI);
    u16* mv_lo  = (u16*)(bigc + BIGOFF_MODV_LO);
    u16* sc_hi  = (u16*)(bigc + BIGOFF_SC_HI);
    u16* sc_lo  = (u16*)(bigc + BIGOFF_SC_LO);
    float* invn = (float*)(bigc + BIGOFF_INVN);
    float* x2   = (float*)d_out;

    wconv_kernel<<<2592, 256, 0, stream>>>(
        w_qkv, w_out, w_mlp1, w_mlp2, ada1_v, ada2_v, gate1_v, gate2_v,
        w_hi, w_lo, mv_hi, mv_lo);

    modprep_kernel<<<608, 256, 0, stream>>>(
        cond, ada1_v, ada1_g, ada2_v, ada2_g, gate1_v, gate1_g, gate2_v, gate2_g,
        invn, sc_hi, sc_lo);

    modgemm_mfma<<<36, 256, 0, stream>>>(sc_hi, sc_lo, mv_hi, mv_lo, invn, mod);

    adaln_kernel<<<NPIX / 4, 256, 0, stream>>>(x, ln1_g, ln1_b, mod, h_hi, h_lo);

    // qkv: 18 x 72 = 1296 blocks
    gemm_mfma<0><<<1296, 256, 0, stream>>>(
        h_hi, h_lo, w_hi + WOFF_QKV, w_lo + WOFF_QKV, b_qkv,
        big, nullptr, nullptr, nullptr, nullptr, C3, D);

    natten_kernel<<<(NPIX * 6) / 4, 256, 0, stream>>>(big, a_hi, a_lo);

    // out-proj fused gate1+residual: 6 x 72 = 432 blocks -> x2 (d_out)
    gemm_mfma<3><<<432, 256, 0, stream>>>(
        a_hi, a_lo, w_hi + WOFF_OUT, w_lo + WOFF_OUT, b_out,
        x2, nullptr, nullptr, mod + 1536, x, D, D);

    // adaln2 on x2
    adaln_kernel<<<NPIX / 4, 256, 0, stream>>>(x2, ln2_g, ln2_b, mod + 768, h_hi, h_lo);

    // mlp1: 24 x 72 = 1728 blocks
    gemm_mfma<1><<<1728, 256, 0, stream>>>(
        h_hi, h_lo, w_hi + WOFF_M1, w_lo + WOFF_M1, b_mlp1,
        nullptr, m_hi, m_lo, nullptr, nullptr, DMLP, D);

    // mlp2 fused gate2+residual (K=1536, nt=48): 432 blocks -> d_out in place
    gemm_mfma<3><<<432, 256, 0, stream>>>(
        m_hi, m_lo, w_hi + WOFF_M2, w_lo + WOFF_M2, b_mlp2,
        x2, nullptr, nullptr, mod + 1920, x2, D, DMLP);
}

// Round 12
// 323.909 us; speedup vs baseline: 1.6781x; 1.0047x over previous
//
#include <hip/hip_runtime.h>
#include <hip/hip_bf16.h>
#include <math.h>

// Shapes fixed: B=2, H=W=48, D=384, CD=384, NH=6, hd=64, KS=7
#define NPIX 4608
#define D 384
#define CD 384
#define C3 1152
#define DMLP 1536
#define NCELL 72

typedef unsigned short u16;
typedef __attribute__((ext_vector_type(8))) short bf16x8;
typedef __attribute__((ext_vector_type(4))) float f32x4;

// ---------------- workspace layout (bytes) ----------------
#define OFF_MOD   0
#define OFF_BIG   663552
#define OFF_HHI   28975104
#define OFF_HLO   32514048
#define OFF_AHI   36052992
#define OFF_ALO   39591936
#define OFF_MHI   43130880
#define OFF_MLO   57286656
#define OFF_WHI   71442432
#define OFF_WLO   74981376
// early-phase temporaries inside BIG (dead before qkv GEMM writes big):
#define BIGOFF_MODV_HI  0
#define BIGOFF_MODV_LO  1769472
#define BIGOFF_SC_HI    3538944
#define BIGOFF_SC_LO    3637248
#define BIGOFF_INVN     3735552
// mod row-major [72][2304]: a1[0,384) b1[384,768) a2[768,1152) b2[1152,1536)
// gate1[1536,1920) gate2[1920,2304)
#define WOFF_QKV  0
#define WOFF_OUT  442368
#define WOFF_M1   589824
#define WOFF_M2   1179648

#define GLOAD16(g, l) __builtin_amdgcn_global_load_lds( \
    (const __attribute__((address_space(1))) unsigned int*)(g), \
    (__attribute__((address_space(3))) unsigned int*)(l), 16, 0, 0)

__device__ __forceinline__ float wsum(float v) {
    #pragma unroll
    for (int o = 32; o > 0; o >>= 1) v += __shfl_xor(v, o);
    return v;
}
__device__ __forceinline__ void split_bf16(float x, u16& h, u16& l) {
    __hip_bfloat16 bh = __float2bfloat16(x);
    float fh = __bfloat162float(bh);
    __hip_bfloat16 bl = __float2bfloat16(x - fh);
    h = *(u16*)&bh; l = *(u16*)&bl;
}

// ---------------------------------------------------------------------------
// Weight conversion: fp32 -> bf16 hi/lo (4 main weights + 4 modulation V)
// ---------------------------------------------------------------------------
__global__ __launch_bounds__(256) void wconv_kernel(
    const float* __restrict__ wq, const float* __restrict__ wo,
    const float* __restrict__ w1, const float* __restrict__ w2,
    const float* __restrict__ a1v, const float* __restrict__ a2v,
    const float* __restrict__ g1v, const float* __restrict__ g2v,
    u16* __restrict__ whi, u16* __restrict__ wlo,
    u16* __restrict__ mvhi, u16* __restrict__ mvlo)
{
    int i4 = blockIdx.x * 256 + threadIdx.x;   // 663552 float4s total
    const float* src; int l4; u16 *dh, *dl; int o;
    if (i4 < 442368) {
        if (i4 < 110592)        { src = wq; l4 = i4; }
        else if (i4 < 147456)   { src = wo; l4 = i4 - 110592; }
        else if (i4 < 294912)   { src = w1; l4 = i4 - 147456; }
        else                    { src = w2; l4 = i4 - 294912; }
        dh = whi; dl = wlo; o = i4 * 4;
    } else {
        int j4 = i4 - 442368;
        if (j4 < 73728)         { src = a1v; l4 = j4; }
        else if (j4 < 147456)   { src = a2v; l4 = j4 - 73728; }
        else if (j4 < 184320)   { src = g1v; l4 = j4 - 147456; }
        else                    { src = g2v; l4 = j4 - 184320; }
        dh = mvhi; dl = mvlo; o = j4 * 4;
    }
    float4 v = ((const float4*)src)[l4];
    split_bf16(v.x, dh[o+0], dl[o+0]);
    split_bf16(v.y, dh[o+1], dl[o+1]);
    split_bf16(v.z, dh[o+2], dl[o+2]);
    split_bf16(v.w, dh[o+3], dl[o+3]);
}

// ---------------------------------------------------------------------------
// modprep: wid<2304 -> inv_norm[row] = g/||v_row||; else silu(cond) -> sc
// ---------------------------------------------------------------------------
__global__ __launch_bounds__(256) void modprep_kernel(
    const float* __restrict__ cond,
    const float* __restrict__ a1v, const float* __restrict__ a1g,
    const float* __restrict__ a2v, const float* __restrict__ a2g,
    const float* __restrict__ g1v, const float* __restrict__ g1g,
    const float* __restrict__ g2v, const float* __restrict__ g2g,
    float* __restrict__ invn, u16* __restrict__ schi, u16* __restrict__ sclo)
{
    int wid  = (blockIdx.x * blockDim.x + threadIdx.x) >> 6;
    int lane = threadIdx.x & 63;
    if (wid < 2304) {
        const float* V; float g; int r;
        if (wid < 768)        { r = wid;        V = a1v; g = a1g[r]; }
        else if (wid < 1536)  { r = wid - 768;  V = a2v; g = a2g[r]; }
        else if (wid < 1920)  { r = wid - 1536; V = g1v; g = g1g[r]; }
        else                  { r = wid - 1920; V = g2v; g = g2g[r]; }
        const float* vrow = V + r * CD;
        float nrm = 0.f;
        #pragma unroll
        for (int j = 0; j < 6; j++) {
            float v = vrow[lane + 64 * j];
            nrm += v * v;
        }
        nrm = wsum(nrm);
        if (lane == 0) invn[wid] = g / sqrtf(nrm);
    } else {
        int cell = wid - 2304;
        #pragma unroll
        for (int j = 0; j < 6; j++) {
            int k = lane + 64 * j;
            float val = 0.f;
            if (cell < NCELL) {
                float c = cond[cell * CD + k];
                val = c / (1.f + __expf(-c));
            }
            split_bf16(val, schi[cell * CD + k], sclo[cell * CD + k]);
        }
    }
}

// ---------------------------------------------------------------------------
// mod GEMM: mod[72,2304] = sc[128,384] @ modV[2304,384]^T, x inv_norm[col]
// (BM=128 geometry; 36 blocks; simple 2-buffer __syncthreads version)
// ---------------------------------------------------------------------------
__global__ __launch_bounds__(256) void modgemm_mfma(
    const u16* __restrict__ Ah, const u16* __restrict__ Al,
    const u16* __restrict__ Bh, const u16* __restrict__ Bl,
    const float* __restrict__ invn, float* __restrict__ mod)
{
    __shared__ u16 lds[24576];
    const int tid  = threadIdx.x;
    const int lane = tid & 63;
    const int wid  = tid >> 6;
    const int n0 = blockIdx.x * 64;
    const int K = 384, nt = 12;
    const int wr = wid >> 1, wc = wid & 1;

    const u16* gsrc[6];
    int loff[6];
    #pragma unroll
    for (int s = 0; s < 6; s++) {
        int c = tid + (s << 8);
        const u16* base; int ks, row;
        if (c < 512)        { ks = c >> 7;           row = c & 127; base = Ah + (size_t)row * K; }
        else if (c < 1024)  { int cc = c - 512;  ks = cc >> 7; row = cc & 127; base = Al + (size_t)row * K; }
        else if (c < 1280)  { int cc = c - 1024; ks = cc >> 6; row = cc & 63;  base = Bh + (size_t)(n0 + row) * K; }
        else                { int cc = c - 1280; ks = cc >> 6; row = cc & 63;  base = Bl + (size_t)(n0 + row) * K; }
        gsrc[s] = base + ks * 8;
        loff[s] = c * 8;
    }

    f32x4 acc[4][2] = {};
    const int ks = lane >> 4;
    const int fr = lane & 15;

    #pragma unroll
    for (int s = 0; s < 6; s++) GLOAD16(gsrc[s], &lds[loff[s]]);
    __syncthreads();

    int cur = 0;
    for (int kt = 0; kt < nt; kt++) {
        if (kt + 1 < nt) {
            int k0 = (kt + 1) << 5;
            int dbo = (cur ^ 1) * 12288;
            #pragma unroll
            for (int s = 0; s < 6; s++) GLOAD16(gsrc[s] + k0, &lds[dbo + loff[s]]);
        }
        const int b0 = cur * 12288;
        bf16x8 ah[4], al[4], bh[2], bl[2];
        #pragma unroll
        for (int m = 0; m < 4; m++) {
            int ai = b0 + (ks * 128 + wr * 64 + m * 16 + fr) * 8;
            ah[m] = *(const bf16x8*)&lds[ai];
            al[m] = *(const bf16x8*)&lds[4096 + ai];
        }
        #pragma unroll
        for (int n = 0; n < 2; n++) {
            int bi = b0 + (ks * 64 + wc * 32 + n * 16 + fr) * 8;
            bh[n] = *(const bf16x8*)&lds[8192 + bi];
            bl[n] = *(const bf16x8*)&lds[10240 + bi];
        }
        #pragma unroll
        for (int m = 0; m < 4; m++)
            #pragma unroll
            for (int n = 0; n < 2; n++) {
                acc[m][n] = __builtin_amdgcn_mfma_f32_16x16x32_bf16(ah[m], bh[n], acc[m][n], 0, 0, 0);
                acc[m][n] = __builtin_amdgcn_mfma_f32_16x16x32_bf16(ah[m], bl[n], acc[m][n], 0, 0, 0);
                acc[m][n] = __builtin_amdgcn_mfma_f32_16x16x32_bf16(al[m], bh[n], acc[m][n], 0, 0, 0);
            }
        __syncthreads();
        cur ^= 1;
    }

    const int r4 = ks * 4;
    #pragma unroll
    for (int m = 0; m < 4; m++) {
        #pragma unroll
        for (int n = 0; n < 2; n++) {
            #pragma unroll
            for (int j = 0; j < 4; j++) {
                int row = wr * 64 + m * 16 + r4 + j;
                int col = n0 + wc * 32 + n * 16 + fr;
                if (row < NCELL)
                    mod[(size_t)row * 2304 + col] = acc[m][n][j] * invn[col];
            }
        }
    }
}

// ---------------------------------------------------------------------------
// AdaLN: LayerNorm + per-cell (1+a)*xn + b; mod row-major [72][2304]
// ---------------------------------------------------------------------------
__global__ __launch_bounds__(256) void adaln_kernel(
    const float* __restrict__ x,
    const float* __restrict__ gamma, const float* __restrict__ beta,
    const float* __restrict__ mod_ab,
    u16* __restrict__ ohi, u16* __restrict__ olo)
{
    int p    = (blockIdx.x * blockDim.x + threadIdx.x) >> 6;
    int lane = threadIdx.x & 63;
    int b  = p / 2304;
    int hh = (p / 48) % 48;
    int ww = p % 48;
    int cell = b * 36 + (hh >> 3) * 6 + (ww >> 3);

    const float* xr = x + (size_t)p * D;
    float v[6]; float s = 0.f, ss = 0.f;
    #pragma unroll
    for (int j = 0; j < 6; j++) {
        v[j] = xr[lane + 64 * j];
        s  += v[j];
        ss += v[j] * v[j];
    }
    s = wsum(s); ss = wsum(ss);
    float mu  = s * (1.f / 384.f);
    float var = ss * (1.f / 384.f) - mu * mu;
    float rs  = 1.f / sqrtf(var + 1e-6f);

    const float* ab = mod_ab + (size_t)cell * 2304;
    #pragma unroll
    for (int j = 0; j < 6; j++) {
        int d = lane + 64 * j;
        float xn = (v[j] - mu) * rs * gamma[d] + beta[d];
        float o  = xn * (1.f + ab[d]) + ab[384 + d];
        split_bf16(o, ohi[(size_t)p * D + d], olo[(size_t)p * D + d]);
    }
}

// ---------------------------------------------------------------------------
// MFMA GEMM, split-bf16 3-term: C[4608,N] = A @ B^T
// BM=64, BN=64, BK=32, 4 waves (2x2, 32x32 each).
// 3-deep LDS ring (48 KB) + counted vmcnt (T4): tile t+2 issued while tile t
// computes; vmcnt(8) waits only the oldest tile's 4 loads -> loads stay in
// flight across barriers (no vmcnt(0) drain in steady state).
// Raw s_barrier x2 per iter: #1 after vmcnt (tile-t DMA landed, all waves),
// #2 after ds_read+lgkmcnt(0) (buffer safe to overwrite).
// EPI 0: +bias -> f32
// EPI 1: +bias, gelu -> bf16 hi/lo
// EPI 3: resid + (acc+bias)*gate[cell] -> f32 (fused gate+residual)
// ---------------------------------------------------------------------------
template <int EPI>
__global__ __launch_bounds__(256) void gemm_mfma(
    const u16* __restrict__ Ah, const u16* __restrict__ Al,
    const u16* __restrict__ Bh, const u16* __restrict__ Bl,
    const float* __restrict__ bias,
    float* __restrict__ Cf, u16* __restrict__ Ch, u16* __restrict__ Cl,
    const float* __restrict__ gate, const float* __restrict__ resid,
    int N, int K)
{
    __shared__ u16 lds[24576];   // 3 x 8192 u16 = 48 KB ring
    const int tid  = threadIdx.x;
    const int lane = tid & 63;
    const int wid  = tid >> 6;

    // bijective XCD swizzle (m204); all grids divisible by 8
    const int nwg = gridDim.x;
    const int q = nwg >> 3, r = nwg & 7;
    const int xcd = blockIdx.x & 7, loc = blockIdx.x >> 3;
    const int wgid = (xcd < r ? xcd * (q + 1) : r * (q + 1) + (xcd - r) * q) + loc;

    const int nx = N >> 6;
    const int by = wgid / nx;
    const int bx = wgid - by * nx;
    const int m0 = by * 64;
    const int n0 = bx * 64;
    const int nt = K >> 5;

    const int wr = wid >> 1, wc = wid & 1;

    // staging: 4 chunks of 16B per thread; chunk c = tid + 256*s
    // regions (u16): Ahi[0,2048) Alo[2048,4096) Bhi[4096,6144) Blo[6144,8192)
    const u16* gsrc[4];
    int loff[4];
    #pragma unroll
    for (int s = 0; s < 4; s++) {
        int c = tid + (s << 8);
        int ks = (c & 255) >> 6;
        int row = c & 63;
        const u16* base;
        if (c < 256)       base = Ah + (size_t)(m0 + row) * K;
        else if (c < 512)  base = Al + (size_t)(m0 + row) * K;
        else if (c < 768)  base = Bh + (size_t)(n0 + row) * K;
        else               base = Bl + (size_t)(n0 + row) * K;
        gsrc[s] = base + ks * 8;
        loff[s] = c * 8;
    }

    f32x4 acc[2][2] = {};
    const int ks = lane >> 4;
    const int fr = lane & 15;

    // prologue: stage tiles 0 and 1 (nt >= 2 always here)
    #pragma unroll
    for (int s = 0; s < 4; s++) GLOAD16(gsrc[s], &lds[loff[s]]);
    #pragma unroll
    for (int s = 0; s < 4; s++) GLOAD16(gsrc[s] + 32, &lds[8192 + loff[s]]);

    for (int kt = 0; kt < nt; kt++) {
        if (kt + 2 < nt) {
            int k0 = (kt + 2) << 5;
            int dbo = ((kt + 2) % 3) * 8192;
            #pragma unroll
            for (int s = 0; s < 4; s++) GLOAD16(gsrc[s] + k0, &lds[dbo + loff[s]]);
        }
        // wait until tile kt's 4 loads (oldest) are complete; younger tiles stay in flight
        int rem = nt - 1 - kt;
        if (rem >= 2)      asm volatile("s_waitcnt vmcnt(8)" ::: "memory");
        else if (rem == 1) asm volatile("s_waitcnt vmcnt(4)" ::: "memory");
        else               asm volatile("s_waitcnt vmcnt(0)" ::: "memory");
        __builtin_amdgcn_s_barrier();

        const int b0 = (kt % 3) * 8192;
        bf16x8 ah[2], al[2], bh[2], bl[2];
        #pragma unroll
        for (int m = 0; m < 2; m++) {
            int ai = b0 + (ks * 64 + wr * 32 + m * 16 + fr) * 8;
            ah[m] = *(const bf16x8*)&lds[ai];
            al[m] = *(const bf16x8*)&lds[2048 + ai];
        }
        #pragma unroll
        for (int n = 0; n < 2; n++) {
            int bi = b0 + (ks * 64 + wc * 32 + n * 16 + fr) * 8;
            bh[n] = *(const bf16x8*)&lds[4096 + bi];
            bl[n] = *(const bf16x8*)&lds[6144 + bi];
        }
        asm volatile("s_waitcnt lgkmcnt(0)" ::: "memory");
        __builtin_amdgcn_sched_barrier(0);
        __builtin_amdgcn_s_barrier();

        #pragma unroll
        for (int m = 0; m < 2; m++)
            #pragma unroll
            for (int n = 0; n < 2; n++) {
                acc[m][n] = __builtin_amdgcn_mfma_f32_16x16x32_bf16(ah[m], bh[n], acc[m][n], 0, 0, 0);
                acc[m][n] = __builtin_amdgcn_mfma_f32_16x16x32_bf16(ah[m], bl[n], acc[m][n], 0, 0, 0);
                acc[m][n] = __builtin_amdgcn_mfma_f32_16x16x32_bf16(al[m], bh[n], acc[m][n], 0, 0, 0);
            }
    }

    // epilogue: C/D layout col=lane&15, row=(lane>>4)*4+j (m89-verified)
    const int r4 = ks * 4;
    #pragma unroll
    for (int m = 0; m < 2; m++) {
        #pragma unroll
        for (int n = 0; n < 2; n++) {
            #pragma unroll
            for (int j = 0; j < 4; j++) {
                int row = m0 + wr * 32 + m * 16 + r4 + j;
                int col = n0 + wc * 32 + n * 16 + fr;
                float v = acc[m][n][j];
                if (EPI == 0) {
                    Cf[(size_t)row * N + col] = v + bias[col];
                } else if (EPI == 1) {
                    float t = v + bias[col];
                    float c = 0.7978845608028654f * (t + 0.044715f * t * t * t);
                    float e = __expf(2.f * c);
                    float th = (e - 1.f) / (e + 1.f);
                    float g = 0.5f * t * (1.f + th);
                    size_t idx = (size_t)row * N + col;
                    split_bf16(g, Ch[idx], Cl[idx]);
                } else {   // EPI == 3: fused gate + residual (N must be 384)
                    int b  = row / 2304;
                    int hh = (row / 48) % 48;
                    int ww = row % 48;
                    int cell = b * 36 + (hh >> 3) * 6 + (ww >> 3);
                    size_t idx = (size_t)row * N + col;
                    Cf[idx] = resid[idx] + (v + bias[col]) * gate[(size_t)cell * 2304 + col];
                }
            }
        }
    }
}

// ---------------------------------------------------------------------------
// 7x7 neighborhood attention, one wave per (pixel,head), 8x8 lane decomp.
// Bijective XCD swizzle: each XCD covers a contiguous ~12-row pixel band so
// the 49x K/V reuse hits that XCD's L2 (band+halo ~2.7MB < 4MB).
// ---------------------------------------------------------------------------
__global__ __launch_bounds__(256) void natten_kernel(
    const float* __restrict__ qkv, u16* __restrict__ ohi, u16* __restrict__ olo)
{
    const int nwg = gridDim.x;
    const int q8 = nwg >> 3, r8 = nwg & 7;
    const int xcd = blockIdx.x & 7, loc = blockIdx.x >> 3;
    const int bswz = (xcd < r8 ? xcd * (q8 + 1) : r8 * (q8 + 1) + (xcd - r8) * q8) + loc;

    int wid  = bswz * 4 + (threadIdx.x >> 6);
    int lane = threadIdx.x & 63;
    int head = wid % 6;
    int p    = wid / 6;
    int b  = p / 2304;
    int hh = (p / 48) % 48;
    int ww = p % 48;
    int sh = hh - 3; sh = sh < 0 ? 0 : (sh > 41 ? 41 : sh);
    int sw = ww - 3; sw = sw < 0 ? 0 : (sw > 41 ? 41 : sw);
    int pb = b * 2304;

    const int n_sub = lane >> 3;
    const int d_sub = lane & 7;
    const int dof = head * 64 + d_sub * 8;

    int npo[7];
    #pragma unroll
    for (int t = 0; t < 7; t++) {
        int n = t * 8 + n_sub;
        int nn = n > 48 ? 48 : n;
        int nr = nn / 7, nc = nn - nr * 7;
        npo[t] = pb + (sh + nr) * 48 + (sw + nc);
    }

    const float* qp = qkv + (size_t)p * C3 + dof;
    float4 q0 = *(const float4*)qp;
    float4 q1 = *(const float4*)(qp + 4);
    q0.x *= 0.125f; q0.y *= 0.125f; q0.z *= 0.125f; q0.w *= 0.125f;
    q1.x *= 0.125f; q1.y *= 0.125f; q1.z *= 0.125f; q1.w *= 0.125f;

    float4 kk0[7], kk1[7];
    #pragma unroll
    for (int t = 0; t < 7; t++) {
        const float* kp = qkv + (size_t)npo[t] * C3 + 384 + dof;
        kk0[t] = *(const float4*)kp;
        kk1[t] = *(const float4*)(kp + 4);
    }
    __builtin_amdgcn_sched_barrier(0);

    float L[7];
    #pragma unroll
    for (int t = 0; t < 7; t++) {
        float d = q0.x * kk0[t].x + q0.y * kk0[t].y + q0.z * kk0[t].z + q0.w * kk0[t].w
                + q1.x * kk1[t].x + q1.y * kk1[t].y + q1.z * kk1[t].z + q1.w * kk1[t].w;
        d += __shfl_xor(d, 1);
        d += __shfl_xor(d, 2);
        d += __shfl_xor(d, 4);
        L[t] = (t * 8 + n_sub < 49) ? d : -INFINITY;
    }

    float4 vv0[7], vv1[7];
    #pragma unroll
    for (int t = 0; t < 7; t++) {
        const float* vp = qkv + (size_t)npo[t] * C3 + 768 + dof;
        vv0[t] = *(const float4*)vp;
        vv1[t] = *(const float4*)(vp + 4);
    }
    __builtin_amdgcn_sched_barrier(0);

    float m = L[0];
    #pragma unroll
    for (int t = 1; t < 7; t++) m = fmaxf(m, L[t]);
    m = fmaxf(m, __shfl_xor(m, 8));
    m = fmaxf(m, __shfl_xor(m, 16));
    m = fmaxf(m, __shfl_xor(m, 32));

    float w[7]; float s = 0.f;
    #pragma unroll
    for (int t = 0; t < 7; t++) {
        w[t] = (L[t] == -INFINITY) ? 0.f : __expf(L[t] - m);
        s += w[t];
    }
    s += __shfl_xor(s, 8);
    s += __shfl_xor(s, 16);
    s += __shfl_xor(s, 32);
    float inv = 1.f / s;
    #pragma unroll
    for (int t = 0; t < 7; t++) w[t] *= inv;

    float a0x = 0.f, a0y = 0.f, a0z = 0.f, a0w = 0.f;
    float a1x = 0.f, a1y = 0.f, a1z = 0.f, a1w = 0.f;
    #pragma unroll
    for (int t = 0; t < 7; t++) {
        float wn = w[t];
        a0x = fmaf(wn, vv0[t].x, a0x); a0y = fmaf(wn, vv0[t].y, a0y);
        a0z = fmaf(wn, vv0[t].z, a0z); a0w = fmaf(wn, vv0[t].w, a0w);
        a1x = fmaf(wn, vv1[t].x, a1x); a1y = fmaf(wn, vv1[t].y, a1y);
        a1z = fmaf(wn, vv1[t].z, a1z); a1w = fmaf(wn, vv1[t].w, a1w);
    }
    #pragma unroll
    for (int o = 8; o <= 32; o <<= 1) {
        a0x += __shfl_xor(a0x, o); a0y += __shfl_xor(a0y, o);
        a0z += __shfl_xor(a0z, o); a0w += __shfl_xor(a0w, o);
        a1x += __shfl_xor(a1x, o); a1y += __shfl_xor(a1y, o);
        a1z += __shfl_xor(a1z, o); a1w += __shfl_xor(a1w, o);
    }

    if (lane < 8) {
        float av[8] = {a0x, a0y, a0z, a0w, a1x, a1y, a1z, a1w};
        u16 hi8[8], lo8[8];
        #pragma unroll
        for (int i = 0; i < 8; i++) split_bf16(av[i], hi8[i], lo8[i]);
        size_t oi = (size_t)p * D + head * 64 + lane * 8;
        *(uint4*)(ohi + oi) = *(uint4*)hi8;
        *(uint4*)(olo + oi) = *(uint4*)lo8;
    }
}

// ---------------------------------------------------------------------------
extern "C" void kernel_launch(void* const* d_in, const int* in_sizes, int n_in,
                              void* d_out, int out_size, void* d_ws, size_t ws_size,
                              hipStream_t stream)
{
    (void)in_sizes; (void)n_in; (void)out_size; (void)ws_size;
    const float* x      = (const float*)d_in[0];
    const float* cond   = (const float*)d_in[1];
    const float* ln1_g  = (const float*)d_in[2];
    const float* ln1_b  = (const float*)d_in[3];
    const float* ada1_v = (const float*)d_in[4];
    const float* ada1_g = (const float*)d_in[5];
    const float* ln2_g  = (const float*)d_in[6];
    const float* ln2_b  = (const float*)d_in[7];
    const float* ada2_v = (const float*)d_in[8];
    const float* ada2_g = (const float*)d_in[9];
    const float* gate1_v = (const float*)d_in[10];
    const float* gate1_g = (const float*)d_in[11];
    const float* gate2_v = (const float*)d_in[12];
    const float* gate2_g = (const float*)d_in[13];
    const float* w_qkv  = (const float*)d_in[14];
    const float* b_qkv  = (const float*)d_in[15];
    const float* w_out  = (const float*)d_in[16];
    const float* b_out  = (const float*)d_in[17];
    const float* w_mlp1 = (const float*)d_in[18];
    const float* b_mlp1 = (const float*)d_in[19];
    const float* w_mlp2 = (const float*)d_in[20];
    const float* b_mlp2 = (const float*)d_in[21];

    char* ws = (char*)d_ws;
    float* mod  = (float*)(ws + OFF_MOD);
    float* big  = (float*)(ws + OFF_BIG);
    u16* h_hi   = (u16*)(ws + OFF_HHI);
    u16* h_lo   = (u16*)(ws + OFF_HLO);
    u16* a_hi   = (u16*)(ws + OFF_AHI);
    u16* a_lo   = (u16*)(ws + OFF_ALO);
    u16* m_hi   = (u16*)(ws + OFF_MHI);
    u16* m_lo   = (u16*)(ws + OFF_MLO);
    u16* w_hi   = (u16*)(ws + OFF_WHI);
    u16* w_lo   = (u16*)(ws + OFF_WLO);
    char* bigc  = ws + OFF_BIG;
    u16* mv_hi  = (u16*)(bigc + BIGOFF_MODV_HI);
    u16* mv_lo  = (u16*)(bigc + BIGOFF_MODV_LO);
    u16* sc_hi  = (u16*)(bigc + BIGOFF_SC_HI);
    u16* sc_lo  = (u16*)(bigc + BIGOFF_SC_LO);
    float* invn = (float*)(bigc + BIGOFF_INVN);
    float* x2   = (float*)d_out;

    wconv_kernel<<<2592, 256, 0, stream>>>(
        w_qkv, w_out, w_mlp1, w_mlp2, ada1_v, ada2_v, gate1_v, gate2_v,
        w_hi, w_lo, mv_hi, mv_lo);

    modprep_kernel<<<608, 256, 0, stream>>>(
        cond, ada1_v, ada1_g, ada2_v, ada2_g, gate1_v, gate1_g, gate2_v, gate2_g,
        invn, sc_hi, sc_lo);

    modgemm_mfma<<<36, 256, 0, stream>>>(sc_hi, sc_lo, mv_hi, mv_lo, invn, mod);

    adaln_kernel<<<NPIX / 4, 256, 0, stream>>>(x, ln1_g, ln1_b, mod, h_hi, h_lo);

    // qkv: 18 x 72 = 1296 blocks
    gemm_mfma<0><<<1296, 256, 0, stream>>>(
        h_hi, h_lo, w_hi + WOFF_QKV, w_lo + WOFF_QKV, b_qkv,
        big, nullptr, nullptr, nullptr, nullptr, C3, D);

    natten_kernel<<<(NPIX * 6) / 4, 256, 0, stream>>>(big, a_hi, a_lo);

    // out-proj fused gate1+residual: 432 blocks -> x2 (d_out)
    gemm_mfma<3><<<432, 256, 0, stream>>>(
        a_hi, a_lo, w_hi + WOFF_OUT, w_lo + WOFF_OUT, b_out,
        x2, nullptr, nullptr, mod + 1536, x, D, D);

    // adaln2 on x2
    adaln_kernel<<<NPIX / 4, 256, 0, stream>>>(x2, ln2_g, ln2_b, mod + 768, h_hi, h_lo);

    // mlp1: 1728 blocks
    gemm_mfma<1><<<1728, 256, 0, stream>>>(
        h_hi, h_lo, w_hi + WOFF_M1, w_lo + WOFF_M1, b_mlp1,
        nullptr, m_hi, m_lo, nullptr, nullptr, DMLP, D);

    // mlp2 fused gate2+residual (K=1536, nt=48): 432 blocks -> d_out in place
    gemm_mfma<3><<<432, 256, 0, stream>>>(
        m_hi, m_lo, w_hi + WOFF_M2, w_lo + WOFF_M2, b_mlp2,
        x2, nullptr, nullptr, mod + 1920, x2, D, DMLP);
}

// Round 13
// 319.725 us; speedup vs baseline: 1.7001x; 1.0131x over previous
//
#include <hip/hip_runtime.h>
#include <hip/hip_bf16.h>
#include <math.h>

// Shapes fixed: B=2, H=W=48, D=384, CD=384, NH=6, hd=64, KS=7
#define NPIX 4608
#define D 384
#define CD 384
#define C3 1152
#define DMLP 1536
#define NCELL 72

typedef unsigned short u16;
typedef __attribute__((ext_vector_type(8))) short bf16x8;
typedef __attribute__((ext_vector_type(4))) float f32x4;

// ---------------- workspace layout (bytes) ----------------
#define OFF_MOD   0
#define OFF_BIG   663552
#define OFF_HHI   28975104
#define OFF_HLO   32514048
#define OFF_AHI   36052992
#define OFF_ALO   39591936
#define OFF_MHI   43130880
#define OFF_MLO   57286656
#define OFF_WHI   71442432
#define OFF_WLO   74981376
// early-phase temporaries inside BIG (dead before qkv GEMM writes big):
#define BIGOFF_MODV_HI  0
#define BIGOFF_MODV_LO  1769472
#define BIGOFF_SC_HI    3538944
#define BIGOFF_SC_LO    3637248
#define BIGOFF_INVN     3735552
// mod row-major [72][2304]: a1[0,384) b1[384,768) a2[768,1152) b2[1152,1536)
// gate1[1536,1920) gate2[1920,2304)
#define WOFF_QKV  0
#define WOFF_OUT  442368
#define WOFF_M1   589824
#define WOFF_M2   1179648

#define GLOAD16(g, l) __builtin_amdgcn_global_load_lds( \
    (const __attribute__((address_space(1))) unsigned int*)(g), \
    (__attribute__((address_space(3))) unsigned int*)(l), 16, 0, 0)

__device__ __forceinline__ float wsum(float v) {
    #pragma unroll
    for (int o = 32; o > 0; o >>= 1) v += __shfl_xor(v, o);
    return v;
}
__device__ __forceinline__ void split_bf16(float x, u16& h, u16& l) {
    __hip_bfloat16 bh = __float2bfloat16(x);
    float fh = __bfloat162float(bh);
    __hip_bfloat16 bl = __float2bfloat16(x - fh);
    h = *(u16*)&bh; l = *(u16*)&bl;
}

// ---------------------------------------------------------------------------
// Weight conversion: fp32 -> bf16 hi/lo (4 main weights + 4 modulation V)
// ---------------------------------------------------------------------------
__global__ __launch_bounds__(256) void wconv_kernel(
    const float* __restrict__ wq, const float* __restrict__ wo,
    const float* __restrict__ w1, const float* __restrict__ w2,
    const float* __restrict__ a1v, const float* __restrict__ a2v,
    const float* __restrict__ g1v, const float* __restrict__ g2v,
    u16* __restrict__ whi, u16* __restrict__ wlo,
    u16* __restrict__ mvhi, u16* __restrict__ mvlo)
{
    int i4 = blockIdx.x * 256 + threadIdx.x;   // 663552 float4s total
    const float* src; int l4; u16 *dh, *dl; int o;
    if (i4 < 442368) {
        if (i4 < 110592)        { src = wq; l4 = i4; }
        else if (i4 < 147456)   { src = wo; l4 = i4 - 110592; }
        else if (i4 < 294912)   { src = w1; l4 = i4 - 147456; }
        else                    { src = w2; l4 = i4 - 294912; }
        dh = whi; dl = wlo; o = i4 * 4;
    } else {
        int j4 = i4 - 442368;
        if (j4 < 73728)         { src = a1v; l4 = j4; }
        else if (j4 < 147456)   { src = a2v; l4 = j4 - 73728; }
        else if (j4 < 184320)   { src = g1v; l4 = j4 - 147456; }
        else                    { src = g2v; l4 = j4 - 184320; }
        dh = mvhi; dl = mvlo; o = j4 * 4;
    }
    float4 v = ((const float4*)src)[l4];
    split_bf16(v.x, dh[o+0], dl[o+0]);
    split_bf16(v.y, dh[o+1], dl[o+1]);
    split_bf16(v.z, dh[o+2], dl[o+2]);
    split_bf16(v.w, dh[o+3], dl[o+3]);
}

// ---------------------------------------------------------------------------
// modprep: wid<2304 -> inv_norm[row] = g/||v_row||; else silu(cond) -> sc
// ---------------------------------------------------------------------------
__global__ __launch_bounds__(256) void modprep_kernel(
    const float* __restrict__ cond,
    const float* __restrict__ a1v, const float* __restrict__ a1g,
    const float* __restrict__ a2v, const float* __restrict__ a2g,
    const float* __restrict__ g1v, const float* __restrict__ g1g,
    const float* __restrict__ g2v, const float* __restrict__ g2g,
    float* __restrict__ invn, u16* __restrict__ schi, u16* __restrict__ sclo)
{
    int wid  = (blockIdx.x * blockDim.x + threadIdx.x) >> 6;
    int lane = threadIdx.x & 63;
    if (wid < 2304) {
        const float* V; float g; int r;
        if (wid < 768)        { r = wid;        V = a1v; g = a1g[r]; }
        else if (wid < 1536)  { r = wid - 768;  V = a2v; g = a2g[r]; }
        else if (wid < 1920)  { r = wid - 1536; V = g1v; g = g1g[r]; }
        else                  { r = wid - 1920; V = g2v; g = g2g[r]; }
        const float* vrow = V + r * CD;
        float nrm = 0.f;
        #pragma unroll
        for (int j = 0; j < 6; j++) {
            float v = vrow[lane + 64 * j];
            nrm += v * v;
        }
        nrm = wsum(nrm);
        if (lane == 0) invn[wid] = g / sqrtf(nrm);
    } else {
        int cell = wid - 2304;
        #pragma unroll
        for (int j = 0; j < 6; j++) {
            int k = lane + 64 * j;
            float val = 0.f;
            if (cell < NCELL) {
                float c = cond[cell * CD + k];
                val = c / (1.f + __expf(-c));
            }
            split_bf16(val, schi[cell * CD + k], sclo[cell * CD + k]);
        }
    }
}

// ---------------------------------------------------------------------------
// mod GEMM: mod[72,2304] = sc[128,384] @ modV[2304,384]^T, x inv_norm[col]
// (BM=128 geometry; 36 blocks; simple 2-buffer __syncthreads version)
// ---------------------------------------------------------------------------
__global__ __launch_bounds__(256) void modgemm_mfma(
    const u16* __restrict__ Ah, const u16* __restrict__ Al,
    const u16* __restrict__ Bh, const u16* __restrict__ Bl,
    const float* __restrict__ invn, float* __restrict__ mod)
{
    __shared__ u16 lds[24576];
    const int tid  = threadIdx.x;
    const int lane = tid & 63;
    const int wid  = tid >> 6;
    const int n0 = blockIdx.x * 64;
    const int K = 384, nt = 12;
    const int wr = wid >> 1, wc = wid & 1;

    const u16* gsrc[6];
    int loff[6];
    #pragma unroll
    for (int s = 0; s < 6; s++) {
        int c = tid + (s << 8);
        const u16* base; int ks, row;
        if (c < 512)        { ks = c >> 7;           row = c & 127; base = Ah + (size_t)row * K; }
        else if (c < 1024)  { int cc = c - 512;  ks = cc >> 7; row = cc & 127; base = Al + (size_t)row * K; }
        else if (c < 1280)  { int cc = c - 1024; ks = cc >> 6; row = cc & 63;  base = Bh + (size_t)(n0 + row) * K; }
        else                { int cc = c - 1280; ks = cc >> 6; row = cc & 63;  base = Bl + (size_t)(n0 + row) * K; }
        gsrc[s] = base + ks * 8;
        loff[s] = c * 8;
    }

    f32x4 acc[4][2] = {};
    const int ks = lane >> 4;
    const int fr = lane & 15;

    #pragma unroll
    for (int s = 0; s < 6; s++) GLOAD16(gsrc[s], &lds[loff[s]]);
    __syncthreads();

    int cur = 0;
    for (int kt = 0; kt < nt; kt++) {
        if (kt + 1 < nt) {
            int k0 = (kt + 1) << 5;
            int dbo = (cur ^ 1) * 12288;
            #pragma unroll
            for (int s = 0; s < 6; s++) GLOAD16(gsrc[s] + k0, &lds[dbo + loff[s]]);
        }
        const int b0 = cur * 12288;
        bf16x8 ah[4], al[4], bh[2], bl[2];
        #pragma unroll
        for (int m = 0; m < 4; m++) {
            int ai = b0 + (ks * 128 + wr * 64 + m * 16 + fr) * 8;
            ah[m] = *(const bf16x8*)&lds[ai];
            al[m] = *(const bf16x8*)&lds[4096 + ai];
        }
        #pragma unroll
        for (int n = 0; n < 2; n++) {
            int bi = b0 + (ks * 64 + wc * 32 + n * 16 + fr) * 8;
            bh[n] = *(const bf16x8*)&lds[8192 + bi];
            bl[n] = *(const bf16x8*)&lds[10240 + bi];
        }
        #pragma unroll
        for (int m = 0; m < 4; m++)
            #pragma unroll
            for (int n = 0; n < 2; n++) {
                acc[m][n] = __builtin_amdgcn_mfma_f32_16x16x32_bf16(ah[m], bh[n], acc[m][n], 0, 0, 0);
                acc[m][n] = __builtin_amdgcn_mfma_f32_16x16x32_bf16(ah[m], bl[n], acc[m][n], 0, 0, 0);
                acc[m][n] = __builtin_amdgcn_mfma_f32_16x16x32_bf16(al[m], bh[n], acc[m][n], 0, 0, 0);
            }
        __syncthreads();
        cur ^= 1;
    }

    const int r4 = ks * 4;
    #pragma unroll
    for (int m = 0; m < 4; m++) {
        #pragma unroll
        for (int n = 0; n < 2; n++) {
            #pragma unroll
            for (int j = 0; j < 4; j++) {
                int row = wr * 64 + m * 16 + r4 + j;
                int col = n0 + wc * 32 + n * 16 + fr;
                if (row < NCELL)
                    mod[(size_t)row * 2304 + col] = acc[m][n][j] * invn[col];
            }
        }
    }
}

// ---------------------------------------------------------------------------
// AdaLN: LayerNorm + per-cell (1+a)*xn + b; mod row-major [72][2304]
// ---------------------------------------------------------------------------
__global__ __launch_bounds__(256) void adaln_kernel(
    const float* __restrict__ x,
    const float* __restrict__ gamma, const float* __restrict__ beta,
    const float* __restrict__ mod_ab,
    u16* __restrict__ ohi, u16* __restrict__ olo)
{
    int p    = (blockIdx.x * blockDim.x + threadIdx.x) >> 6;
    int lane = threadIdx.x & 63;
    int b  = p / 2304;
    int hh = (p / 48) % 48;
    int ww = p % 48;
    int cell = b * 36 + (hh >> 3) * 6 + (ww >> 3);

    const float* xr = x + (size_t)p * D;
    float v[6]; float s = 0.f, ss = 0.f;
    #pragma unroll
    for (int j = 0; j < 6; j++) {
        v[j] = xr[lane + 64 * j];
        s  += v[j];
        ss += v[j] * v[j];
    }
    s = wsum(s); ss = wsum(ss);
    float mu  = s * (1.f / 384.f);
    float var = ss * (1.f / 384.f) - mu * mu;
    float rs  = 1.f / sqrtf(var + 1e-6f);

    const float* ab = mod_ab + (size_t)cell * 2304;
    #pragma unroll
    for (int j = 0; j < 6; j++) {
        int d = lane + 64 * j;
        float xn = (v[j] - mu) * rs * gamma[d] + beta[d];
        float o  = xn * (1.f + ab[d]) + ab[384 + d];
        split_bf16(o, ohi[(size_t)p * D + d], olo[(size_t)p * D + d]);
    }
}

// ---------------------------------------------------------------------------
// MFMA GEMM, split-bf16 3-term: C[4608,N] = A @ B^T
// BM=64, BN=64, BK=32, 512 threads = 8 waves (4x2 grid, 16x32 per wave).
// 4-deep LDS ring (64 KB) + counted vmcnt: tile t+3 issued while tile t
// computes (prefetch horizon 3 iters >= HBM latency). Per-wave loads/tile = 2
// -> steady-state wait is vmcnt(6). Raw s_barrier x2 per iter (ring safety
// proof: writer of buf[(t+3)&3]=buf[(t-1)&3] issues after barrier#2(t-1),
// whose readers drained via lgkmcnt(0)+sched_barrier before that barrier).
// EPI 0: +bias -> f32
// EPI 1: +bias, gelu -> bf16 hi/lo
// EPI 3: resid + (acc+bias)*gate[cell] -> f32 (fused gate+residual)
// ---------------------------------------------------------------------------
template <int EPI>
__global__ __launch_bounds__(512) void gemm_mfma(
    const u16* __restrict__ Ah, const u16* __restrict__ Al,
    const u16* __restrict__ Bh, const u16* __restrict__ Bl,
    const float* __restrict__ bias,
    float* __restrict__ Cf, u16* __restrict__ Ch, u16* __restrict__ Cl,
    const float* __restrict__ gate, const float* __restrict__ resid,
    int N, int K)
{
    __shared__ u16 lds[32768];   // 4 x 8192 u16 = 64 KB ring
    const int tid  = threadIdx.x;
    const int lane = tid & 63;
    const int wid  = tid >> 6;       // 0..7

    // bijective XCD swizzle (m204); all grids divisible by 8
    const int nwg = gridDim.x;
    const int q = nwg >> 3, r = nwg & 7;
    const int xcd = blockIdx.x & 7, loc = blockIdx.x >> 3;
    const int wgid = (xcd < r ? xcd * (q + 1) : r * (q + 1) + (xcd - r) * q) + loc;

    const int nx = N >> 6;
    const int by = wgid / nx;
    const int bx = wgid - by * nx;
    const int m0 = by * 64;
    const int n0 = bx * 64;
    const int nt = K >> 5;           // 12 or 48, always >= 4

    const int wr = wid >> 1;         // 0..3: row quarter (16 rows)
    const int wc = wid & 1;          // 0..1: col half (32 cols)

    // staging: 2 chunks of 16B per thread; chunk c = tid + 512*s, c in 0..1023
    // tile regions (u16): Ahi[0,2048) Alo[2048,4096) Bhi[4096,6144) Blo[6144,8192)
    // each wave's 64 chunks stay inside ONE region (wave-uniform base).
    const u16* gsrc[2];
    int loff[2];
    #pragma unroll
    for (int s = 0; s < 2; s++) {
        int c = tid + (s << 9);
        int ks = (c & 255) >> 6;
        int row = c & 63;
        const u16* base;
        if (c < 256)       base = Ah + (size_t)(m0 + row) * K;
        else if (c < 512)  base = Al + (size_t)(m0 + row) * K;
        else if (c < 768)  base = Bh + (size_t)(n0 + row) * K;
        else               base = Bl + (size_t)(n0 + row) * K;
        gsrc[s] = base + ks * 8;
        loff[s] = c * 8;
    }

    f32x4 acc[2] = {};
    const int ks = lane >> 4;
    const int fr = lane & 15;

    // prologue: stage tiles 0,1,2 into ring slots 0,1,2
    #pragma unroll
    for (int s = 0; s < 2; s++) GLOAD16(gsrc[s],      &lds[loff[s]]);
    #pragma unroll
    for (int s = 0; s < 2; s++) GLOAD16(gsrc[s] + 32, &lds[8192 + loff[s]]);
    #pragma unroll
    for (int s = 0; s < 2; s++) GLOAD16(gsrc[s] + 64, &lds[16384 + loff[s]]);

    for (int kt = 0; kt < nt; kt++) {
        if (kt + 3 < nt) {
            int k0 = (kt + 3) << 5;
            int dbo = ((kt + 3) & 3) * 8192;
            #pragma unroll
            for (int s = 0; s < 2; s++) GLOAD16(gsrc[s] + k0, &lds[dbo + loff[s]]);
        }
        // wait only for tile kt's 2 loads (oldest); younger tiles stay in flight
        int rem = nt - 1 - kt;
        if (rem >= 3)      asm volatile("s_waitcnt vmcnt(6)" ::: "memory");
        else if (rem == 2) asm volatile("s_waitcnt vmcnt(4)" ::: "memory");
        else if (rem == 1) asm volatile("s_waitcnt vmcnt(2)" ::: "memory");
        else               asm volatile("s_waitcnt vmcnt(0)" ::: "memory");
        __builtin_amdgcn_s_barrier();

        const int b0 = (kt & 3) * 8192;
        bf16x8 ah, al, bh[2], bl[2];
        {
            int ai = b0 + (ks * 64 + wr * 16 + fr) * 8;
            ah = *(const bf16x8*)&lds[ai];
            al = *(const bf16x8*)&lds[2048 + ai];
        }
        #pragma unroll
        for (int n = 0; n < 2; n++) {
            int bi = b0 + 4096 + (ks * 64 + wc * 32 + n * 16 + fr) * 8;
            bh[n] = *(const bf16x8*)&lds[bi];
            bl[n] = *(const bf16x8*)&lds[2048 + bi];
        }
        asm volatile("s_waitcnt lgkmcnt(0)" ::: "memory");
        __builtin_amdgcn_sched_barrier(0);
        __builtin_amdgcn_s_barrier();

        #pragma unroll
        for (int n = 0; n < 2; n++) {
            acc[n] = __builtin_amdgcn_mfma_f32_16x16x32_bf16(ah, bh[n], acc[n], 0, 0, 0);
            acc[n] = __builtin_amdgcn_mfma_f32_16x16x32_bf16(ah, bl[n], acc[n], 0, 0, 0);
            acc[n] = __builtin_amdgcn_mfma_f32_16x16x32_bf16(al, bh[n], acc[n], 0, 0, 0);
        }
    }

    // epilogue: C/D layout col=lane&15, row=(lane>>4)*4+j (m89-verified)
    const int r4 = ks * 4;
    #pragma unroll
    for (int n = 0; n < 2; n++) {
        #pragma unroll
        for (int j = 0; j < 4; j++) {
            int row = m0 + wr * 16 + r4 + j;
            int col = n0 + wc * 32 + n * 16 + fr;
            float v = acc[n][j];
            if (EPI == 0) {
                Cf[(size_t)row * N + col] = v + bias[col];
            } else if (EPI == 1) {
                float t = v + bias[col];
                float c = 0.7978845608028654f * (t + 0.044715f * t * t * t);
                float e = __expf(2.f * c);
                float th = (e - 1.f) / (e + 1.f);
                float g = 0.5f * t * (1.f + th);
                size_t idx = (size_t)row * N + col;
                split_bf16(g, Ch[idx], Cl[idx]);
            } else {   // EPI == 3: fused gate + residual (N must be 384)
                int b  = row / 2304;
                int hh = (row / 48) % 48;
                int ww = row % 48;
                int cell = b * 36 + (hh >> 3) * 6 + (ww >> 3);
                size_t idx = (size_t)row * N + col;
                Cf[idx] = resid[idx] + (v + bias[col]) * gate[(size_t)cell * 2304 + col];
            }
        }
    }
}

// ---------------------------------------------------------------------------
// 7x7 neighborhood attention, one wave per (pixel,head), 8x8 lane decomp.
// Bijective XCD swizzle: contiguous pixel band per XCD -> K/V reuse in L2.
// ---------------------------------------------------------------------------
__global__ __launch_bounds__(256) void natten_kernel(
    const float* __restrict__ qkv, u16* __restrict__ ohi, u16* __restrict__ olo)
{
    const int nwg = gridDim.x;
    const int q8 = nwg >> 3, r8 = nwg & 7;
    const int xcd = blockIdx.x & 7, loc = blockIdx.x >> 3;
    const int bswz = (xcd < r8 ? xcd * (q8 + 1) : r8 * (q8 + 1) + (xcd - r8) * q8) + loc;

    int wid  = bswz * 4 + (threadIdx.x >> 6);
    int lane = threadIdx.x & 63;
    int head = wid % 6;
    int p    = wid / 6;
    int b  = p / 2304;
    int hh = (p / 48) % 48;
    int ww = p % 48;
    int sh = hh - 3; sh = sh < 0 ? 0 : (sh > 41 ? 41 : sh);
    int sw = ww - 3; sw = sw < 0 ? 0 : (sw > 41 ? 41 : sw);
    int pb = b * 2304;

    const int n_sub = lane >> 3;
    const int d_sub = lane & 7;
    const int dof = head * 64 + d_sub * 8;

    int npo[7];
    #pragma unroll
    for (int t = 0; t < 7; t++) {
        int n = t * 8 + n_sub;
        int nn = n > 48 ? 48 : n;
        int nr = nn / 7, nc = nn - nr * 7;
        npo[t] = pb + (sh + nr) * 48 + (sw + nc);
    }

    const float* qp = qkv + (size_t)p * C3 + dof;
    float4 q0 = *(const float4*)qp;
    float4 q1 = *(const float4*)(qp + 4);
    q0.x *= 0.125f; q0.y *= 0.125f; q0.z *= 0.125f; q0.w *= 0.125f;
    q1.x *= 0.125f; q1.y *= 0.125f; q1.z *= 0.125f; q1.w *= 0.125f;

    float4 kk0[7], kk1[7];
    #pragma unroll
    for (int t = 0; t < 7; t++) {
        const float* kp = qkv + (size_t)npo[t] * C3 + 384 + dof;
        kk0[t] = *(const float4*)kp;
        kk1[t] = *(const float4*)(kp + 4);
    }
    __builtin_amdgcn_sched_barrier(0);

    float L[7];
    #pragma unroll
    for (int t = 0; t < 7; t++) {
        float d = q0.x * kk0[t].x + q0.y * kk0[t].y + q0.z * kk0[t].z + q0.w * kk0[t].w
                + q1.x * kk1[t].x + q1.y * kk1[t].y + q1.z * kk1[t].z + q1.w * kk1[t].w;
        d += __shfl_xor(d, 1);
        d += __shfl_xor(d, 2);
        d += __shfl_xor(d, 4);
        L[t] = (t * 8 + n_sub < 49) ? d : -INFINITY;
    }

    float4 vv0[7], vv1[7];
    #pragma unroll
    for (int t = 0; t < 7; t++) {
        const float* vp = qkv + (size_t)npo[t] * C3 + 768 + dof;
        vv0[t] = *(const float4*)vp;
        vv1[t] = *(const float4*)(vp + 4);
    }
    __builtin_amdgcn_sched_barrier(0);

    float m = L[0];
    #pragma unroll
    for (int t = 1; t < 7; t++) m = fmaxf(m, L[t]);
    m = fmaxf(m, __shfl_xor(m, 8));
    m = fmaxf(m, __shfl_xor(m, 16));
    m = fmaxf(m, __shfl_xor(m, 32));

    float w[7]; float s = 0.f;
    #pragma unroll
    for (int t = 0; t < 7; t++) {
        w[t] = (L[t] == -INFINITY) ? 0.f : __expf(L[t] - m);
        s += w[t];
    }
    s += __shfl_xor(s, 8);
    s += __shfl_xor(s, 16);
    s += __shfl_xor(s, 32);
    float inv = 1.f / s;
    #pragma unroll
    for (int t = 0; t < 7; t++) w[t] *= inv;

    float a0x = 0.f, a0y = 0.f, a0z = 0.f, a0w = 0.f;
    float a1x = 0.f, a1y = 0.f, a1z = 0.f, a1w = 0.f;
    #pragma unroll
    for (int t = 0; t < 7; t++) {
        float wn = w[t];
        a0x = fmaf(wn, vv0[t].x, a0x); a0y = fmaf(wn, vv0[t].y, a0y);
        a0z = fmaf(wn, vv0[t].z, a0z); a0w = fmaf(wn, vv0[t].w, a0w);
        a1x = fmaf(wn, vv1[t].x, a1x); a1y = fmaf(wn, vv1[t].y, a1y);
        a1z = fmaf(wn, vv1[t].z, a1z); a1w = fmaf(wn, vv1[t].w, a1w);
    }
    #pragma unroll
    for (int o = 8; o <= 32; o <<= 1) {
        a0x += __shfl_xor(a0x, o); a0y += __shfl_xor(a0y, o);
        a0z += __shfl_xor(a0z, o); a0w += __shfl_xor(a0w, o);
        a1x += __shfl_xor(a1x, o); a1y += __shfl_xor(a1y, o);
        a1z += __shfl_xor(a1z, o); a1w += __shfl_xor(a1w, o);
    }

    if (lane < 8) {
        float av[8] = {a0x, a0y, a0z, a0w, a1x, a1y, a1z, a1w};
        u16 hi8[8], lo8[8];
        #pragma unroll
        for (int i = 0; i < 8; i++) split_bf16(av[i], hi8[i], lo8[i]);
        size_t oi = (size_t)p * D + head * 64 + lane * 8;
        *(uint4*)(ohi + oi) = *(uint4*)hi8;
        *(uint4*)(olo + oi) = *(uint4*)lo8;
    }
}

// ---------------------------------------------------------------------------
extern "C" void kernel_launch(void* const* d_in, const int* in_sizes, int n_in,
                              void* d_out, int out_size, void* d_ws, size_t ws_size,
                              hipStream_t stream)
{
    (void)in_sizes; (void)n_in; (void)out_size; (void)ws_size;
    const float* x      = (const float*)d_in[0];
    const float* cond   = (const float*)d_in[1];
    const float* ln1_g  = (const float*)d_in[2];
    const float* ln1_b  = (const float*)d_in[3];
    const float* ada1_v = (const float*)d_in[4];
    const float* ada1_g = (const float*)d_in[5];
    const float* ln2_g  = (const float*)d_in[6];
    const float* ln2_b  = (const float*)d_in[7];
    const float* ada2_v = (const float*)d_in[8];
    const float* ada2_g = (const float*)d_in[9];
    const float* gate1_v = (const float*)d_in[10];
    const float* gate1_g = (const float*)d_in[11];
    const float* gate2_v = (const float*)d_in[12];
    const float* gate2_g = (const float*)d_in[13];
    const float* w_qkv  = (const float*)d_in[14];
    const float* b_qkv  = (const float*)d_in[15];
    const float* w_out  = (const float*)d_in[16];
    const float* b_out  = (const float*)d_in[17];
    const float* w_mlp1 = (const float*)d_in[18];
    const float* b_mlp1 = (const float*)d_in[19];
    const float* w_mlp2 = (const float*)d_in[20];
    const float* b_mlp2 = (const float*)d_in[21];

    char* ws = (char*)d_ws;
    float* mod  = (float*)(ws + OFF_MOD);
    float* big  = (float*)(ws + OFF_BIG);
    u16* h_hi   = (u16*)(ws + OFF_HHI);
    u16* h_lo   = (u16*)(ws + OFF_HLO);
    u16* a_hi   = (u16*)(ws + OFF_AHI);
    u16* a_lo   = (u16*)(ws + OFF_ALO);
    u16* m_hi   = (u16*)(ws + OFF_MHI);
    u16* m_lo   = (u16*)(ws + OFF_MLO);
    u16* w_hi   = (u16*)(ws + OFF_WHI);
    u16* w_lo   = (u16*)(ws + OFF_WLO);
    char* bigc  = ws + OFF_BIG;
    u16* mv_hi  = (u16*)(bigc + BIGOFF_MODV_HI);
    u16* mv_lo  = (u16*)(bigc + BIGOFF_MODV_LO);
    u16* sc_hi  = (u16*)(bigc + BIGOFF_SC_HI);
    u16* sc_lo  = (u16*)(bigc + BIGOFF_SC_LO);
    float* invn = (float*)(bigc + BIGOFF_INVN);
    float* x2   = (float*)d_out;

    wconv_kernel<<<2592, 256, 0, stream>>>(
        w_qkv, w_out, w_mlp1, w_mlp2, ada1_v, ada2_v, gate1_v, gate2_v,
        w_hi, w_lo, mv_hi, mv_lo);

    modprep_kernel<<<608, 256, 0, stream>>>(
        cond, ada1_v, ada1_g, ada2_v, ada2_g, gate1_v, gate1_g, gate2_v, gate2_g,
        invn, sc_hi, sc_lo);

    modgemm_mfma<<<36, 256, 0, stream>>>(sc_hi, sc_lo, mv_hi, mv_lo, invn, mod);

    adaln_kernel<<<NPIX / 4, 256, 0, stream>>>(x, ln1_g, ln1_b, mod, h_hi, h_lo);

    // qkv: 18 x 72 = 1296 blocks (512 thr)
    gemm_mfma<0><<<1296, 512, 0, stream>>>(
        h_hi, h_lo, w_hi + WOFF_QKV, w_lo + WOFF_QKV, b_qkv,
        big, nullptr, nullptr, nullptr, nullptr, C3, D);

    natten_kernel<<<(NPIX * 6) / 4, 256, 0, stream>>>(big, a_hi, a_lo);

    // out-proj fused gate1+residual: 432 blocks -> x2 (d_out)
    gemm_mfma<3><<<432, 512, 0, stream>>>(
        a_hi, a_lo, w_hi + WOFF_OUT, w_lo + WOFF_OUT, b_out,
        x2, nullptr, nullptr, mod + 1536, x, D, D);

    // adaln2 on x2
    adaln_kernel<<<NPIX / 4, 256, 0, stream>>>(x2, ln2_g, ln2_b, mod + 768, h_hi, h_lo);

    // mlp1: 1728 blocks
    gemm_mfma<1><<<1728, 512, 0, stream>>>(
        h_hi, h_lo, w_hi + WOFF_M1, w_lo + WOFF_M1, b_mlp1,
        nullptr, m_hi, m_lo, nullptr, nullptr, DMLP, D);

    // mlp2 fused gate2+residual (K=1536, nt=48): 432 blocks -> d_out in place
    gemm_mfma<3><<<432, 512, 0, stream>>>(
        m_hi, m_lo, w_hi + WOFF_M2, w_lo + WOFF_M2, b_mlp2,
        x2, nullptr, nullptr, mod + 1920, x2, D, DMLP);
}